// Round 1
// baseline (2659.064 us; speedup 1.0000x reference)
//
#include <hip/hip_runtime.h>

#define N_NODES 50000
#define N_EDGES 800000
#define NUM_GRAPHS 128
#define EPS 1e-5f

// ---------------- degree / norm ----------------

__global__ void init_deg_kernel(float* deg, int n) {
    int i = blockIdx.x * blockDim.x + threadIdx.x;
    if (i < n) deg[i] = 1.0f;  // self-loop
}

__global__ void count_deg_kernel(const int* __restrict__ dst, float* deg, int E) {
    int i = blockIdx.x * blockDim.x + threadIdx.x;
    int stride = gridDim.x * blockDim.x;
    for (; i < E; i += stride) atomicAdd(&deg[dst[i]], 1.0f);
}

__global__ void rsqrt_kernel(float* deg, int n) {
    int i = blockIdx.x * blockDim.x + threadIdx.x;
    if (i < n) deg[i] = rsqrtf(deg[i]);
}

// ---------------- GEMM: H[N,M] = X[N,K] @ W[K,M] ----------------
// 64x64 tile, BK=16, 16x16 threads, 4x4 per thread. f32 vector ALU.

#define BM 64
#define BN 64
#define BK 16

__global__ __launch_bounds__(256) void gemm_f32_kernel(
        const float* __restrict__ X, const float* __restrict__ W,
        float* __restrict__ H, int N, int K, int M) {
    __shared__ float As[BK][BM + 1];
    __shared__ float Bs[BK][BN];
    int bm = blockIdx.x * BM;
    int bn = blockIdx.y * BN;
    int tid = threadIdx.x;
    int tr = tid / 16, tc = tid % 16;
    float acc[4][4] = {};
    for (int k0 = 0; k0 < K; k0 += BK) {
        for (int i = tid; i < BM * BK; i += 256) {
            int m = i / BK, k = i % BK;
            int row = bm + m;
            As[k][m] = (row < N) ? X[(size_t)row * K + k0 + k] : 0.0f;
        }
        for (int i = tid; i < BK * BN; i += 256) {
            int k = i / BN, n = i % BN;
            Bs[k][n] = W[(size_t)(k0 + k) * M + bn + n];
        }
        __syncthreads();
#pragma unroll
        for (int k = 0; k < BK; ++k) {
            float a[4], b[4];
#pragma unroll
            for (int i = 0; i < 4; ++i) a[i] = As[k][tr * 4 + i];
#pragma unroll
            for (int j = 0; j < 4; ++j) b[j] = Bs[k][tc * 4 + j];
#pragma unroll
            for (int i = 0; i < 4; ++i)
#pragma unroll
                for (int j = 0; j < 4; ++j) acc[i][j] += a[i] * b[j];
        }
        __syncthreads();
    }
    for (int i = 0; i < 4; ++i) {
        int row = bm + tr * 4 + i;
        if (row < N) {
            float* o = H + (size_t)row * M + bn + tc * 4;
#pragma unroll
            for (int j = 0; j < 4; ++j) o[j] = acc[i][j];
        }
    }
}

// ---------------- aggregation ----------------

// AGG[i][c] = b[c] + H[i][c]*dinv[i]^2   (bias + self-loop term)
__global__ void agg_init_kernel(const float* __restrict__ H, const float* __restrict__ dinv,
                                const float* __restrict__ b, float* __restrict__ AGG,
                                int n, int C) {
    size_t idx = (size_t)blockIdx.x * blockDim.x + threadIdx.x;
    size_t total = (size_t)n * C;
    if (idx >= total) return;
    int i = (int)(idx / C);
    int c = (int)(idx % C);
    float dv = dinv[i];
    AGG[idx] = b[c] + H[idx] * dv * dv;
}

// AGG[dst] += H[src] * dinv[src]*dinv[dst]; one block per edge, thread per channel
__global__ void edge_agg_kernel(const int* __restrict__ src, const int* __restrict__ dst,
                                const float* __restrict__ dinv, const float* __restrict__ H,
                                float* __restrict__ AGG, int E, int C) {
    for (int e = blockIdx.x; e < E; e += gridDim.x) {
        int s = src[e], d = dst[e];
        float nw = dinv[s] * dinv[d];
        const float* hrow = H + (size_t)s * C;
        float* orow = AGG + (size_t)d * C;
        for (int c = threadIdx.x; c < C; c += blockDim.x)
            atomicAdd(&orow[c], hrow[c] * nw);
    }
}

// ---------------- batch norm ----------------

__global__ void zero_kernel(float* p, int n) {
    int i = blockIdx.x * blockDim.x + threadIdx.x;
    if (i < n) p[i] = 0.0f;
}

__global__ void bn_stats_kernel(const float* __restrict__ A, float* __restrict__ sums,
                                float* __restrict__ sumsq, int n, int C) {
    int c = threadIdx.x;  // blockDim.x == C
    int rpb = (n + gridDim.x - 1) / gridDim.x;
    int r0 = blockIdx.x * rpb;
    int r1 = min(n, r0 + rpb);
    float s = 0.0f, s2 = 0.0f;
    for (int r = r0; r < r1; ++r) {
        float v = A[(size_t)r * C + c];
        s += v;
        s2 += v * v;
    }
    atomicAdd(&sums[c], s);
    atomicAdd(&sumsq[c], s2);
}

__global__ void bn_finalize_kernel(const float* __restrict__ sums, const float* __restrict__ sumsq,
                                   const float* __restrict__ gamma, const float* __restrict__ beta,
                                   float* __restrict__ scale, float* __restrict__ shift,
                                   int n, int C) {
    int c = threadIdx.x;
    if (c >= C) return;
    float inv_n = 1.0f / (float)n;
    float mu = sums[c] * inv_n;
    float var = sumsq[c] * inv_n - mu * mu;
    float rs = rsqrtf(var + EPS);
    float sc = gamma[c] * rs;
    scale[c] = sc;
    shift[c] = beta[c] - mu * sc;
}

__global__ void bn_apply_relu_kernel(float* __restrict__ A, const float* __restrict__ scale,
                                     const float* __restrict__ shift, int n, int C) {
    size_t idx = (size_t)blockIdx.x * blockDim.x + threadIdx.x;
    if (idx >= (size_t)n * C) return;
    int c = (int)(idx % C);
    float v = A[idx] * scale[c] + shift[c];
    A[idx] = v > 0.0f ? v : 0.0f;
}

// ---------------- pooling ----------------

__global__ void pool_kernel(const float* __restrict__ H, const int* __restrict__ batch,
                            float* __restrict__ out, float* __restrict__ counts, int n, int C) {
    size_t idx = (size_t)blockIdx.x * blockDim.x + threadIdx.x;
    if (idx >= (size_t)n * C) return;
    int i = (int)(idx / C);
    int c = (int)(idx % C);
    int g = batch[i];
    atomicAdd(&out[(size_t)g * C + c], H[idx]);
    if (c == 0) atomicAdd(&counts[g], 1.0f);
}

__global__ void pool_div_kernel(float* out, const float* __restrict__ counts, int G, int C) {
    int idx = blockIdx.x * blockDim.x + threadIdx.x;
    if (idx >= G * C) return;
    int g = idx / C;
    out[idx] /= fmaxf(counts[g], 1.0f);
}

// ---------------- host driver ----------------

static void run_layer(hipStream_t stream, const float* X, const float* W, const float* b,
                      const float* gamma, const float* beta, int Cin, int Cout,
                      const int* src, const int* dst, const float* dinv,
                      float* H, float* AGG, float* sums, float* sumsq,
                      float* scale, float* shift) {
    dim3 gg((N_NODES + BM - 1) / BM, Cout / BN);
    hipLaunchKernelGGL(gemm_f32_kernel, gg, dim3(256), 0, stream, X, W, H, N_NODES, Cin, Cout);

    size_t total = (size_t)N_NODES * Cout;
    int blocks = (int)((total + 255) / 256);
    hipLaunchKernelGGL(agg_init_kernel, dim3(blocks), dim3(256), 0, stream, H, dinv, b, AGG,
                       N_NODES, Cout);
    hipLaunchKernelGGL(edge_agg_kernel, dim3(N_EDGES), dim3(Cout), 0, stream, src, dst, dinv, H,
                       AGG, N_EDGES, Cout);

    hipLaunchKernelGGL(zero_kernel, dim3(2), dim3(256), 0, stream, sums, 512);  // sums+sumsq
    hipLaunchKernelGGL(bn_stats_kernel, dim3(256), dim3(Cout), 0, stream, AGG, sums, sumsq,
                       N_NODES, Cout);
    hipLaunchKernelGGL(bn_finalize_kernel, dim3(1), dim3(Cout), 0, stream, sums, sumsq, gamma,
                       beta, scale, shift, N_NODES, Cout);
    hipLaunchKernelGGL(bn_apply_relu_kernel, dim3(blocks), dim3(256), 0, stream, AGG, scale,
                       shift, N_NODES, Cout);
}

extern "C" void kernel_launch(void* const* d_in, const int* in_sizes, int n_in,
                              void* d_out, int out_size, void* d_ws, size_t ws_size,
                              hipStream_t stream) {
    const float* x     = (const float*)d_in[0];
    const int*   ei    = (const int*)d_in[1];
    const int*   batch = (const int*)d_in[2];
    const float* W1 = (const float*)d_in[3];
    const float* b1 = (const float*)d_in[4];
    const float* W2 = (const float*)d_in[5];
    const float* b2 = (const float*)d_in[6];
    const float* W3 = (const float*)d_in[7];
    const float* b3 = (const float*)d_in[8];
    const float* g1 = (const float*)d_in[9];
    const float* be1 = (const float*)d_in[10];
    const float* g2 = (const float*)d_in[11];
    const float* be2 = (const float*)d_in[12];
    const float* g3 = (const float*)d_in[13];
    const float* be3 = (const float*)d_in[14];
    float* out = (float*)d_out;

    const int* src = ei;             // edge_index[0]
    const int* dstv = ei + N_EDGES;  // edge_index[1]

    // workspace carve-up (256B aligned)
    size_t off = 0;
    auto alloc = [&](size_t nfloats) {
        float* p = (float*)((char*)d_ws + off);
        off += nfloats * sizeof(float);
        off = (off + 255) & ~(size_t)255;
        return p;
    };
    float* deg    = alloc(N_NODES);      // becomes dinv in-place
    float* sums   = alloc(512);          // sums[256] + sumsq[256] contiguous
    float* sumsq  = sums + 256;
    float* scale  = alloc(256);
    float* shift  = alloc(256);
    float* counts = alloc(NUM_GRAPHS);
    float* bufA   = alloc((size_t)N_NODES * 256);
    float* bufB   = alloc((size_t)N_NODES * 256);
    (void)ws_size; (void)n_in; (void)in_sizes; (void)out_size;

    // degree + dinv
    hipLaunchKernelGGL(init_deg_kernel, dim3((N_NODES + 255) / 256), dim3(256), 0, stream, deg,
                       N_NODES);
    hipLaunchKernelGGL(count_deg_kernel, dim3(2048), dim3(256), 0, stream, dstv, deg, N_EDGES);
    hipLaunchKernelGGL(rsqrt_kernel, dim3((N_NODES + 255) / 256), dim3(256), 0, stream, deg,
                       N_NODES);

    // layer 1: 128 -> 256   (X = input x; H = bufA; AGG = bufB)
    run_layer(stream, x, W1, b1, g1, be1, 128, 256, src, dstv, deg, bufA, bufB, sums, sumsq,
              scale, shift);
    // layer 2: 256 -> 256   (X = bufB; H = bufA; AGG = bufB — X dead after GEMM)
    run_layer(stream, bufB, W2, b2, g2, be2, 256, 256, src, dstv, deg, bufA, bufB, sums, sumsq,
              scale, shift);
    // layer 3: 256 -> 128
    run_layer(stream, bufB, W3, b3, g3, be3, 256, 128, src, dstv, deg, bufA, bufB, sums, sumsq,
              scale, shift);

    // global mean pool (bufB holds [N,128])
    hipLaunchKernelGGL(zero_kernel, dim3((NUM_GRAPHS * 128 + 255) / 256), dim3(256), 0, stream,
                       out, NUM_GRAPHS * 128);
    hipLaunchKernelGGL(zero_kernel, dim3(1), dim3(NUM_GRAPHS), 0, stream, counts, NUM_GRAPHS);
    int pblocks = (int)(((size_t)N_NODES * 128 + 255) / 256);
    hipLaunchKernelGGL(pool_kernel, dim3(pblocks), dim3(256), 0, stream, bufB, batch, out, counts,
                       N_NODES, 128);
    hipLaunchKernelGGL(pool_div_kernel, dim3((NUM_GRAPHS * 128 + 255) / 256), dim3(256), 0,
                       stream, out, counts, NUM_GRAPHS, 128);
}

// Round 2
// 1291.583 us; speedup vs baseline: 2.0588x; 2.0588x over previous
//
#include <hip/hip_runtime.h>

#define N_NODES 50000
#define N_EDGES 800000
#define NUM_GRAPHS 128
#define EPS 1e-5f

// ---------------- degree / CSR build ----------------

__global__ void zero_int_kernel(int* p, int n) {
    int i = blockIdx.x * blockDim.x + threadIdx.x;
    if (i < n) p[i] = 0;
}

__global__ void count_deg_kernel(const int* __restrict__ dst, int* deg, int E) {
    int i = blockIdx.x * blockDim.x + threadIdx.x;
    int stride = gridDim.x * blockDim.x;
    for (; i < E; i += stride) atomicAdd(&deg[dst[i]], 1);
}

// dinv[i] = rsqrt(deg_edges[i] + 1)   (self-loop)
__global__ void dinv_kernel(const int* __restrict__ deg, float* dinv, int n) {
    int i = blockIdx.x * blockDim.x + threadIdx.x;
    if (i < n) dinv[i] = rsqrtf((float)(deg[i] + 1));
}

// one-block exclusive scan of deg -> row_start[0..n], row_start[n] = E
__global__ __launch_bounds__(1024) void scan_kernel(const int* __restrict__ deg,
                                                    int* __restrict__ row_start, int n) {
    __shared__ int lsum[1024];
    int tid = threadIdx.x;
    int chunk = (n + 1023) / 1024;
    int i0 = tid * chunk, i1 = min(n, i0 + chunk);
    int s = 0;
    for (int i = i0; i < i1; ++i) s += deg[i];
    lsum[tid] = s;
    __syncthreads();
    // Hillis-Steele inclusive scan
    for (int off = 1; off < 1024; off <<= 1) {
        int v = (tid >= off) ? lsum[tid - off] : 0;
        __syncthreads();
        lsum[tid] += v;
        __syncthreads();
    }
    int base = (tid == 0) ? 0 : lsum[tid - 1];
    for (int i = i0; i < i1; ++i) {
        row_start[i] = base;
        base += deg[i];
    }
    if (tid == 1023) row_start[n] = base;
}

__global__ void copy_int_kernel(const int* __restrict__ a, int* b, int n) {
    int i = blockIdx.x * blockDim.x + threadIdx.x;
    if (i < n) b[i] = a[i];
}

__global__ void fill_csr_kernel(const int* __restrict__ src, const int* __restrict__ dst,
                                int* __restrict__ cursor, int* __restrict__ csr_src, int E) {
    int i = blockIdx.x * blockDim.x + threadIdx.x;
    int stride = gridDim.x * blockDim.x;
    for (; i < E; i += stride) {
        int p = atomicAdd(&cursor[dst[i]], 1);
        csr_src[p] = src[i];
    }
}

// ---------------- GEMM: H[N,M] = X[N,K] @ W[K,M] (+ optional bias) ----------------

#define BM 64
#define BN 64
#define BK 16

__global__ __launch_bounds__(256) void gemm_f32_kernel(
        const float* __restrict__ X, const float* __restrict__ W,
        const float* __restrict__ bias, float* __restrict__ H, int N, int K, int M) {
    __shared__ float As[BK][BM + 1];
    __shared__ float Bs[BK][BN];
    int bm = blockIdx.x * BM;
    int bn = blockIdx.y * BN;
    int tid = threadIdx.x;
    int tr = tid / 16, tc = tid % 16;
    float acc[4][4] = {};
    for (int k0 = 0; k0 < K; k0 += BK) {
        for (int i = tid; i < BM * BK; i += 256) {
            int m = i / BK, k = i % BK;
            int row = bm + m;
            As[k][m] = (row < N) ? X[(size_t)row * K + k0 + k] : 0.0f;
        }
        for (int i = tid; i < BK * BN; i += 256) {
            int k = i / BN, n = i % BN;
            Bs[k][n] = W[(size_t)(k0 + k) * M + bn + n];
        }
        __syncthreads();
#pragma unroll
        for (int k = 0; k < BK; ++k) {
            float a[4], b[4];
#pragma unroll
            for (int i = 0; i < 4; ++i) a[i] = As[k][tr * 4 + i];
#pragma unroll
            for (int j = 0; j < 4; ++j) b[j] = Bs[k][tc * 4 + j];
#pragma unroll
            for (int i = 0; i < 4; ++i)
#pragma unroll
                for (int j = 0; j < 4; ++j) acc[i][j] += a[i] * b[j];
        }
        __syncthreads();
    }
    for (int i = 0; i < 4; ++i) {
        int row = bm + tr * 4 + i;
        if (row < N) {
            float* o = H + (size_t)row * M + bn + tc * 4;
#pragma unroll
            for (int j = 0; j < 4; ++j) {
                float v = acc[i][j];
                if (bias) v += bias[bn + tc * 4 + j];
                o[j] = v;
            }
        }
    }
}

// ---------------- gather aggregation (CSR by dst) ----------------
// One wave (64 threads) per node. AGG[i] = bias + H[i]*dinv[i]^2
//                                        + sum_{s in N(i)} H[s]*dinv[s]*dinv[i]
// C == 256: each lane owns float4 at c = lane*4; C == 128: float2 at c = lane*2.

template <int C>
__global__ __launch_bounds__(64) void gather_agg_kernel(
        const float* __restrict__ H, const float* __restrict__ dinv,
        const float* __restrict__ bias, const int* __restrict__ row_start,
        const int* __restrict__ csr_src, float* __restrict__ AGG, int n) {
    constexpr int V = C / 64;  // floats per lane
    int i = blockIdx.x;
    if (i >= n) return;
    int lane = threadIdx.x;
    float di = dinv[i];
    float acc[V];
    const float* hrow = H + (size_t)i * C + lane * V;
#pragma unroll
    for (int v = 0; v < V; ++v) acc[v] = (bias ? bias[lane * V + v] : 0.0f) + hrow[v] * di * di;
    int e0 = row_start[i], e1 = row_start[i + 1];
    for (int e = e0; e < e1; ++e) {
        int s = csr_src[e];
        float w = dinv[s] * di;
        const float* srow = H + (size_t)s * C + lane * V;
#pragma unroll
        for (int v = 0; v < V; ++v) acc[v] += srow[v] * w;
    }
    float* orow = AGG + (size_t)i * C + lane * V;
#pragma unroll
    for (int v = 0; v < V; ++v) orow[v] = acc[v];
}

// ---------------- batch norm ----------------

__global__ void zero_kernel(float* p, int n) {
    int i = blockIdx.x * blockDim.x + threadIdx.x;
    if (i < n) p[i] = 0.0f;
}

__global__ void bn_stats_kernel(const float* __restrict__ A, float* __restrict__ sums,
                                float* __restrict__ sumsq, int n, int C) {
    int c = threadIdx.x;  // blockDim.x == C
    int rpb = (n + gridDim.x - 1) / gridDim.x;
    int r0 = blockIdx.x * rpb;
    int r1 = min(n, r0 + rpb);
    float s = 0.0f, s2 = 0.0f;
    for (int r = r0; r < r1; ++r) {
        float v = A[(size_t)r * C + c];
        s += v;
        s2 += v * v;
    }
    atomicAdd(&sums[c], s);
    atomicAdd(&sumsq[c], s2);
}

__global__ void bn_finalize_kernel(const float* __restrict__ sums, const float* __restrict__ sumsq,
                                   const float* __restrict__ gamma, const float* __restrict__ beta,
                                   float* __restrict__ scale, float* __restrict__ shift,
                                   int n, int C) {
    int c = threadIdx.x;
    if (c >= C) return;
    float inv_n = 1.0f / (float)n;
    float mu = sums[c] * inv_n;
    float var = sumsq[c] * inv_n - mu * mu;
    float rs = rsqrtf(var + EPS);
    float sc = gamma[c] * rs;
    scale[c] = sc;
    shift[c] = beta[c] - mu * sc;
}

__global__ void bn_apply_relu_kernel(float* __restrict__ A, const float* __restrict__ scale,
                                     const float* __restrict__ shift, int n, int C) {
    size_t idx = (size_t)blockIdx.x * blockDim.x + threadIdx.x;
    if (idx >= (size_t)n * C) return;
    int c = (int)(idx % C);
    float v = A[idx] * scale[c] + shift[c];
    A[idx] = v > 0.0f ? v : 0.0f;
}

// ---------------- pooling ----------------

__global__ void pool_kernel(const float* __restrict__ H, const int* __restrict__ batch,
                            float* __restrict__ out, float* __restrict__ counts, int n, int C) {
    size_t idx = (size_t)blockIdx.x * blockDim.x + threadIdx.x;
    if (idx >= (size_t)n * C) return;
    int i = (int)(idx / C);
    int c = (int)(idx % C);
    int g = batch[i];
    atomicAdd(&out[(size_t)g * C + c], H[idx]);
    if (c == 0) atomicAdd(&counts[g], 1.0f);
}

__global__ void pool_div_kernel(float* out, const float* __restrict__ counts, int G, int C) {
    int idx = blockIdx.x * blockDim.x + threadIdx.x;
    if (idx >= G * C) return;
    int g = idx / C;
    out[idx] /= fmaxf(counts[g], 1.0f);
}

// ---------------- host-side helpers ----------------

static void run_bn(hipStream_t stream, float* A, const float* gamma, const float* beta, int Cout,
                   float* sums, float* sumsq, float* scale, float* shift) {
    size_t total = (size_t)N_NODES * Cout;
    int blocks = (int)((total + 255) / 256);
    hipLaunchKernelGGL(zero_kernel, dim3(2), dim3(256), 0, stream, sums, 512);
    hipLaunchKernelGGL(bn_stats_kernel, dim3(256), dim3(Cout), 0, stream, A, sums, sumsq,
                       N_NODES, Cout);
    hipLaunchKernelGGL(bn_finalize_kernel, dim3(1), dim3(Cout), 0, stream, sums, sumsq, gamma,
                       beta, scale, shift, N_NODES, Cout);
    hipLaunchKernelGGL(bn_apply_relu_kernel, dim3(blocks), dim3(256), 0, stream, A, scale,
                       shift, N_NODES, Cout);
}

extern "C" void kernel_launch(void* const* d_in, const int* in_sizes, int n_in,
                              void* d_out, int out_size, void* d_ws, size_t ws_size,
                              hipStream_t stream) {
    const float* x     = (const float*)d_in[0];
    const int*   ei    = (const int*)d_in[1];
    const int*   batch = (const int*)d_in[2];
    const float* W1 = (const float*)d_in[3];
    const float* b1 = (const float*)d_in[4];
    const float* W2 = (const float*)d_in[5];
    const float* b2 = (const float*)d_in[6];
    const float* W3 = (const float*)d_in[7];
    const float* b3 = (const float*)d_in[8];
    const float* g1 = (const float*)d_in[9];
    const float* be1 = (const float*)d_in[10];
    const float* g2 = (const float*)d_in[11];
    const float* be2 = (const float*)d_in[12];
    const float* g3 = (const float*)d_in[13];
    const float* be3 = (const float*)d_in[14];
    float* out = (float*)d_out;

    const int* src = ei;             // edge_index[0]
    const int* dstv = ei + N_EDGES;  // edge_index[1]

    // workspace carve-up (256B aligned)
    size_t off = 0;
    auto allocb = [&](size_t nbytes) {
        char* p = (char*)d_ws + off;
        off += (nbytes + 255) & ~(size_t)255;
        return p;
    };
    int*   deg_int   = (int*)allocb(N_NODES * 4);
    int*   row_start = (int*)allocb((N_NODES + 1) * 4);
    int*   cursor    = (int*)allocb(N_NODES * 4);
    int*   csr_src   = (int*)allocb(N_EDGES * 4);
    float* dinv      = (float*)allocb(N_NODES * 4);
    float* sums      = (float*)allocb(512 * 4);  // sums[256] + sumsq[256]
    float* sumsq     = sums + 256;
    float* scale     = (float*)allocb(256 * 4);
    float* shift     = (float*)allocb(256 * 4);
    float* counts    = (float*)allocb(NUM_GRAPHS * 4);
    float* bufA      = (float*)allocb((size_t)N_NODES * 256 * 4);
    float* bufB      = (float*)allocb((size_t)N_NODES * 256 * 4);
    (void)ws_size; (void)n_in; (void)in_sizes; (void)out_size;

    int nb = (N_NODES + 255) / 256;

    // ---- degree, dinv, CSR (by dst) ----
    hipLaunchKernelGGL(zero_int_kernel, dim3(nb), dim3(256), 0, stream, deg_int, N_NODES);
    hipLaunchKernelGGL(count_deg_kernel, dim3(2048), dim3(256), 0, stream, dstv, deg_int, N_EDGES);
    hipLaunchKernelGGL(dinv_kernel, dim3(nb), dim3(256), 0, stream, deg_int, dinv, N_NODES);
    hipLaunchKernelGGL(scan_kernel, dim3(1), dim3(1024), 0, stream, deg_int, row_start, N_NODES);
    hipLaunchKernelGGL(copy_int_kernel, dim3(nb), dim3(256), 0, stream, row_start, cursor, N_NODES);
    hipLaunchKernelGGL(fill_csr_kernel, dim3(2048), dim3(256), 0, stream, src, dstv, cursor,
                       csr_src, N_EDGES);

    // ---- layer 1: aggregate x (128ch) first, then GEMM 128->256 (+b1) ----
    hipLaunchKernelGGL((gather_agg_kernel<128>), dim3(N_NODES), dim3(64), 0, stream, x, dinv,
                       (const float*)nullptr, row_start, csr_src, bufA, N_NODES);
    hipLaunchKernelGGL(gemm_f32_kernel, dim3((N_NODES + BM - 1) / BM, 256 / BN), dim3(256), 0,
                       stream, bufA, W1, b1, bufB, N_NODES, 128, 256);
    run_bn(stream, bufB, g1, be1, 256, sums, sumsq, scale, shift);

    // ---- layer 2: GEMM 256->256, then aggregate (256ch, +b2) ----
    hipLaunchKernelGGL(gemm_f32_kernel, dim3((N_NODES + BM - 1) / BM, 256 / BN), dim3(256), 0,
                       stream, bufB, W2, (const float*)nullptr, bufA, N_NODES, 256, 256);
    hipLaunchKernelGGL((gather_agg_kernel<256>), dim3(N_NODES), dim3(64), 0, stream, bufA, dinv,
                       b2, row_start, csr_src, bufB, N_NODES);
    run_bn(stream, bufB, g2, be2, 256, sums, sumsq, scale, shift);

    // ---- layer 3: GEMM 256->128, then aggregate (128ch, +b3) ----
    hipLaunchKernelGGL(gemm_f32_kernel, dim3((N_NODES + BM - 1) / BM, 128 / BN), dim3(256), 0,
                       stream, bufB, W3, (const float*)nullptr, bufA, N_NODES, 256, 128);
    hipLaunchKernelGGL((gather_agg_kernel<128>), dim3(N_NODES), dim3(64), 0, stream, bufA, dinv,
                       b3, row_start, csr_src, bufB, N_NODES);
    run_bn(stream, bufB, g3, be3, 128, sums, sumsq, scale, shift);

    // ---- global mean pool (bufB holds [N,128]) ----
    hipLaunchKernelGGL(zero_kernel, dim3((NUM_GRAPHS * 128 + 255) / 256), dim3(256), 0, stream,
                       out, NUM_GRAPHS * 128);
    hipLaunchKernelGGL(zero_kernel, dim3(1), dim3(NUM_GRAPHS), 0, stream, counts, NUM_GRAPHS);
    int pblocks = (int)(((size_t)N_NODES * 128 + 255) / 256);
    hipLaunchKernelGGL(pool_kernel, dim3(pblocks), dim3(256), 0, stream, bufB, batch, out, counts,
                       N_NODES, 128);
    hipLaunchKernelGGL(pool_div_kernel, dim3((NUM_GRAPHS * 128 + 255) / 256), dim3(256), 0,
                       stream, out, counts, NUM_GRAPHS, 128);
}

// Round 3
// 995.932 us; speedup vs baseline: 2.6699x; 1.2969x over previous
//
#include <hip/hip_runtime.h>

#define N_NODES 50000
#define N_EDGES 800000
#define NUM_GRAPHS 128
#define EPS 1e-5f

// ---------------- degree / CSR build ----------------

__global__ void zero_int_kernel(int* p, int n) {
    int i = blockIdx.x * blockDim.x + threadIdx.x;
    if (i < n) p[i] = 0;
}

__global__ void count_deg_kernel(const int* __restrict__ dst, int* deg, int E) {
    int i = blockIdx.x * blockDim.x + threadIdx.x;
    int stride = gridDim.x * blockDim.x;
    for (; i < E; i += stride) atomicAdd(&deg[dst[i]], 1);
}

// dinv[i] = rsqrt(deg_edges[i] + 1)   (self-loop)
__global__ void dinv_kernel(const int* __restrict__ deg, float* dinv, int n) {
    int i = blockIdx.x * blockDim.x + threadIdx.x;
    if (i < n) dinv[i] = rsqrtf((float)(deg[i] + 1));
}

// one-block exclusive scan of deg -> row_start[0..n], row_start[n] = E
__global__ __launch_bounds__(1024) void scan_kernel(const int* __restrict__ deg,
                                                    int* __restrict__ row_start, int n) {
    __shared__ int lsum[1024];
    int tid = threadIdx.x;
    int chunk = (n + 1023) / 1024;
    int i0 = tid * chunk, i1 = min(n, i0 + chunk);
    int s = 0;
    for (int i = i0; i < i1; ++i) s += deg[i];
    lsum[tid] = s;
    __syncthreads();
    for (int off = 1; off < 1024; off <<= 1) {
        int v = (tid >= off) ? lsum[tid - off] : 0;
        __syncthreads();
        lsum[tid] += v;
        __syncthreads();
    }
    int base = (tid == 0) ? 0 : lsum[tid - 1];
    for (int i = i0; i < i1; ++i) {
        row_start[i] = base;
        base += deg[i];
    }
    if (tid == 1023) row_start[n] = base;
}

__global__ void copy_int_kernel(const int* __restrict__ a, int* b, int n) {
    int i = blockIdx.x * blockDim.x + threadIdx.x;
    if (i < n) b[i] = a[i];
}

__global__ void fill_csr_kernel(const int* __restrict__ src, const int* __restrict__ dst,
                                int* __restrict__ cursor, int* __restrict__ csr_src, int E) {
    int i = blockIdx.x * blockDim.x + threadIdx.x;
    int stride = gridDim.x * blockDim.x;
    for (; i < E; i += stride) {
        int p = atomicAdd(&cursor[dst[i]], 1);
        csr_src[p] = src[i];
    }
}

// ---------------- GEMM: H[N,M] = relu_bn(X)[N,K] @ W[K,M] (+ optional bias) -------
// If in_scale != nullptr, A-tile elements are relu(x*in_scale[k] + in_shift[k]).

#define BM 64
#define BN 64
#define BK 16

__global__ __launch_bounds__(256) void gemm_f32_kernel(
        const float* __restrict__ X, const float* __restrict__ W,
        const float* __restrict__ bias, const float* __restrict__ in_scale,
        const float* __restrict__ in_shift, float* __restrict__ H, int N, int K, int M) {
    __shared__ float As[BK][BM + 1];
    __shared__ float Bs[BK][BN];
    int bm = blockIdx.x * BM;
    int bn = blockIdx.y * BN;
    int tid = threadIdx.x;
    int tr = tid / 16, tc = tid % 16;
    float acc[4][4] = {};
    for (int k0 = 0; k0 < K; k0 += BK) {
        for (int i = tid; i < BM * BK; i += 256) {
            int m = i / BK, k = i % BK;
            int row = bm + m;
            float v = (row < N) ? X[(size_t)row * K + k0 + k] : 0.0f;
            if (in_scale) v = fmaxf(v * in_scale[k0 + k] + in_shift[k0 + k], 0.0f);
            As[k][m] = v;
        }
        for (int i = tid; i < BK * BN; i += 256) {
            int k = i / BN, n = i % BN;
            Bs[k][n] = W[(size_t)(k0 + k) * M + bn + n];
        }
        __syncthreads();
#pragma unroll
        for (int k = 0; k < BK; ++k) {
            float a[4], b[4];
#pragma unroll
            for (int i = 0; i < 4; ++i) a[i] = As[k][tr * 4 + i];
#pragma unroll
            for (int j = 0; j < 4; ++j) b[j] = Bs[k][tc * 4 + j];
#pragma unroll
            for (int i = 0; i < 4; ++i)
#pragma unroll
                for (int j = 0; j < 4; ++j) acc[i][j] += a[i] * b[j];
        }
        __syncthreads();
    }
    for (int i = 0; i < 4; ++i) {
        int row = bm + tr * 4 + i;
        if (row < N) {
            float* o = H + (size_t)row * M + bn + tc * 4;
#pragma unroll
            for (int j = 0; j < 4; ++j) {
                float v = acc[i][j];
                if (bias) v += bias[bn + tc * 4 + j];
                o[j] = v;
            }
        }
    }
}

// ---------------- gather aggregation (CSR by dst) ----------------

template <int C>
__global__ __launch_bounds__(64) void gather_agg_kernel(
        const float* __restrict__ H, const float* __restrict__ dinv,
        const float* __restrict__ bias, const int* __restrict__ row_start,
        const int* __restrict__ csr_src, float* __restrict__ AGG, int n) {
    constexpr int V = C / 64;  // floats per lane
    int i = blockIdx.x;
    if (i >= n) return;
    int lane = threadIdx.x;
    float di = dinv[i];
    float acc[V];
    const float* hrow = H + (size_t)i * C + lane * V;
#pragma unroll
    for (int v = 0; v < V; ++v) acc[v] = (bias ? bias[lane * V + v] : 0.0f) + hrow[v] * di * di;
    int e0 = row_start[i], e1 = row_start[i + 1];
    for (int e = e0; e < e1; ++e) {
        int s = csr_src[e];
        float w = dinv[s] * di;
        const float* srow = H + (size_t)s * C + lane * V;
#pragma unroll
        for (int v = 0; v < V; ++v) acc[v] += srow[v] * w;
    }
    float* orow = AGG + (size_t)i * C + lane * V;
#pragma unroll
    for (int v = 0; v < V; ++v) orow[v] = acc[v];
}

// ---------------- batch norm stats ----------------

__global__ void zero_kernel(float* p, int n) {
    int i = blockIdx.x * blockDim.x + threadIdx.x;
    if (i < n) p[i] = 0.0f;
}

__global__ void bn_stats_kernel(const float* __restrict__ A, float* __restrict__ sums,
                                float* __restrict__ sumsq, int n, int C) {
    int c = threadIdx.x;  // blockDim.x == C
    int rpb = (n + gridDim.x - 1) / gridDim.x;
    int r0 = blockIdx.x * rpb;
    int r1 = min(n, r0 + rpb);
    float s = 0.0f, s2 = 0.0f;
    for (int r = r0; r < r1; ++r) {
        float v = A[(size_t)r * C + c];
        s += v;
        s2 += v * v;
    }
    atomicAdd(&sums[c], s);
    atomicAdd(&sumsq[c], s2);
}

__global__ void bn_finalize_kernel(const float* __restrict__ sums, const float* __restrict__ sumsq,
                                   const float* __restrict__ gamma, const float* __restrict__ beta,
                                   float* __restrict__ scale, float* __restrict__ shift,
                                   int n, int C) {
    int c = threadIdx.x;
    if (c >= C) return;
    float inv_n = 1.0f / (float)n;
    float mu = sums[c] * inv_n;
    float var = sumsq[c] * inv_n - mu * mu;
    float rs = rsqrtf(var + EPS);
    float sc = gamma[c] * rs;
    scale[c] = sc;
    shift[c] = beta[c] - mu * sc;
}

// ---------------- pooling (sorted-segment, no atomics) ----------------

// gstart[g] = first node index with batch >= g; gstart[G] = n
__global__ void graph_bounds_kernel(const int* __restrict__ batch, int* __restrict__ gstart,
                                    int n, int G) {
    int g = blockIdx.x * blockDim.x + threadIdx.x;
    if (g > G) return;
    int lo = 0, hi = n;
    while (lo < hi) {
        int mid = (lo + hi) >> 1;
        if (batch[mid] < g) lo = mid + 1; else hi = mid;
    }
    gstart[g] = lo;
}

// one block per graph; applies layer-3 BN scale/shift + relu inline; C == 128
__global__ __launch_bounds__(256) void pool_seg_kernel(
        const float* __restrict__ A, const float* __restrict__ scale,
        const float* __restrict__ shift, const int* __restrict__ gstart,
        float* __restrict__ out) {
    __shared__ float partial[256];
    int g = blockIdx.x;
    int tid = threadIdx.x;
    int c = tid & 127;
    int part = tid >> 7;  // 0..1
    int r0 = gstart[g], r1 = gstart[g + 1];
    float sc = scale[c], sh = shift[c];
    float s = 0.0f;
    for (int r = r0 + part; r < r1; r += 2) {
        float v = A[(size_t)r * 128 + c];
        s += fmaxf(v * sc + sh, 0.0f);
    }
    partial[tid] = s;
    __syncthreads();
    if (part == 0) {
        float tot = s + partial[c + 128];
        float cnt = (float)(r1 - r0);
        out[g * 128 + c] = tot / fmaxf(cnt, 1.0f);
    }
}

// ---------------- host-side helpers ----------------

static void run_bn_stats(hipStream_t stream, const float* A, const float* gamma,
                         const float* beta, int Cout, float* sums, float* sumsq,
                         float* scale, float* shift) {
    hipLaunchKernelGGL(zero_kernel, dim3(2), dim3(256), 0, stream, sums, 512);
    hipLaunchKernelGGL(bn_stats_kernel, dim3(256), dim3(Cout), 0, stream, A, sums, sumsq,
                       N_NODES, Cout);
    hipLaunchKernelGGL(bn_finalize_kernel, dim3(1), dim3(Cout), 0, stream, sums, sumsq, gamma,
                       beta, scale, shift, N_NODES, Cout);
}

extern "C" void kernel_launch(void* const* d_in, const int* in_sizes, int n_in,
                              void* d_out, int out_size, void* d_ws, size_t ws_size,
                              hipStream_t stream) {
    const float* x     = (const float*)d_in[0];
    const int*   ei    = (const int*)d_in[1];
    const int*   batch = (const int*)d_in[2];
    const float* W1 = (const float*)d_in[3];
    const float* b1 = (const float*)d_in[4];
    const float* W2 = (const float*)d_in[5];
    const float* b2 = (const float*)d_in[6];
    const float* W3 = (const float*)d_in[7];
    const float* b3 = (const float*)d_in[8];
    const float* g1 = (const float*)d_in[9];
    const float* be1 = (const float*)d_in[10];
    const float* g2 = (const float*)d_in[11];
    const float* be2 = (const float*)d_in[12];
    const float* g3 = (const float*)d_in[13];
    const float* be3 = (const float*)d_in[14];
    float* out = (float*)d_out;

    const int* src = ei;             // edge_index[0]
    const int* dstv = ei + N_EDGES;  // edge_index[1]

    size_t off = 0;
    auto allocb = [&](size_t nbytes) {
        char* p = (char*)d_ws + off;
        off += (nbytes + 255) & ~(size_t)255;
        return p;
    };
    int*   deg_int   = (int*)allocb(N_NODES * 4);
    int*   row_start = (int*)allocb((N_NODES + 1) * 4);
    int*   cursor    = (int*)allocb(N_NODES * 4);
    int*   csr_src   = (int*)allocb(N_EDGES * 4);
    int*   gstart    = (int*)allocb((NUM_GRAPHS + 1) * 4);
    float* dinv      = (float*)allocb(N_NODES * 4);
    float* sums      = (float*)allocb(512 * 4);  // sums[256] + sumsq[256]
    float* sumsq     = sums + 256;
    float* scale     = (float*)allocb(256 * 4);
    float* shift     = (float*)allocb(256 * 4);
    float* bufA      = (float*)allocb((size_t)N_NODES * 256 * 4);
    float* bufB      = (float*)allocb((size_t)N_NODES * 256 * 4);
    (void)ws_size; (void)n_in; (void)in_sizes; (void)out_size;

    int nb = (N_NODES + 255) / 256;

    // ---- degree, dinv, CSR (by dst), graph bounds ----
    hipLaunchKernelGGL(zero_int_kernel, dim3(nb), dim3(256), 0, stream, deg_int, N_NODES);
    hipLaunchKernelGGL(count_deg_kernel, dim3(2048), dim3(256), 0, stream, dstv, deg_int, N_EDGES);
    hipLaunchKernelGGL(dinv_kernel, dim3(nb), dim3(256), 0, stream, deg_int, dinv, N_NODES);
    hipLaunchKernelGGL(scan_kernel, dim3(1), dim3(1024), 0, stream, deg_int, row_start, N_NODES);
    hipLaunchKernelGGL(copy_int_kernel, dim3(nb), dim3(256), 0, stream, row_start, cursor, N_NODES);
    hipLaunchKernelGGL(fill_csr_kernel, dim3(2048), dim3(256), 0, stream, src, dstv, cursor,
                       csr_src, N_EDGES);
    hipLaunchKernelGGL(graph_bounds_kernel, dim3(1), dim3(NUM_GRAPHS + 1), 0, stream, batch,
                       gstart, N_NODES, NUM_GRAPHS);

    // ---- layer 1: aggregate x (128ch), GEMM 128->256 (+b1), BN stats ----
    hipLaunchKernelGGL((gather_agg_kernel<128>), dim3(N_NODES), dim3(64), 0, stream, x, dinv,
                       (const float*)nullptr, row_start, csr_src, bufA, N_NODES);
    hipLaunchKernelGGL(gemm_f32_kernel, dim3((N_NODES + BM - 1) / BM, 256 / BN), dim3(256), 0,
                       stream, bufA, W1, b1, (const float*)nullptr, (const float*)nullptr, bufB,
                       N_NODES, 128, 256);
    run_bn_stats(stream, bufB, g1, be1, 256, sums, sumsq, scale, shift);

    // ---- layer 2: GEMM 256->256 (BN1 apply+relu fused on input), aggregate (+b2), stats ----
    hipLaunchKernelGGL(gemm_f32_kernel, dim3((N_NODES + BM - 1) / BM, 256 / BN), dim3(256), 0,
                       stream, bufB, W2, (const float*)nullptr, scale, shift, bufA,
                       N_NODES, 256, 256);
    hipLaunchKernelGGL((gather_agg_kernel<256>), dim3(N_NODES), dim3(64), 0, stream, bufA, dinv,
                       b2, row_start, csr_src, bufB, N_NODES);
    run_bn_stats(stream, bufB, g2, be2, 256, sums, sumsq, scale, shift);

    // ---- layer 3: GEMM 256->128 (BN2 apply+relu fused), aggregate (+b3), stats ----
    hipLaunchKernelGGL(gemm_f32_kernel, dim3((N_NODES + BM - 1) / BM, 128 / BN), dim3(256), 0,
                       stream, bufB, W3, (const float*)nullptr, scale, shift, bufA,
                       N_NODES, 256, 128);
    hipLaunchKernelGGL((gather_agg_kernel<128>), dim3(N_NODES), dim3(64), 0, stream, bufA, dinv,
                       b3, row_start, csr_src, bufB, N_NODES);
    run_bn_stats(stream, bufB, g3, be3, 128, sums, sumsq, scale, shift);

    // ---- pool: segmented mean with BN3 apply+relu fused (bufB = [N,128] raw AGG) ----
    hipLaunchKernelGGL(pool_seg_kernel, dim3(NUM_GRAPHS), dim3(256), 0, stream, bufB, scale,
                       shift, gstart, out);
}

// Round 4
// 867.571 us; speedup vs baseline: 3.0650x; 1.1480x over previous
//
#include <hip/hip_runtime.h>

#define N_NODES 50000
#define N_EDGES 800000
#define NUM_GRAPHS 128
#define EPS 1e-5f
#define NT_ROWS (N_NODES / 16)  // 3125 row tiles (exact)

typedef __attribute__((ext_vector_type(8))) short short8;
typedef __attribute__((ext_vector_type(4))) float floatx4;

__device__ __forceinline__ unsigned short f2bf_rne(float f) {
    unsigned int u = __float_as_uint(f);
    u += 0x7FFF + ((u >> 16) & 1);
    return (unsigned short)(u >> 16);
}
__device__ __forceinline__ float bf2f(unsigned short h) {
    return __uint_as_float(((unsigned int)h) << 16);
}

// ---------------- degree / CSR build ----------------

__global__ void zero_int_kernel(int* p, int n) {
    int i = blockIdx.x * blockDim.x + threadIdx.x;
    if (i < n) p[i] = 0;
}

__global__ void count_deg_kernel(const int* __restrict__ dst, int* deg, int E) {
    int i = blockIdx.x * blockDim.x + threadIdx.x;
    int stride = gridDim.x * blockDim.x;
    for (; i < E; i += stride) atomicAdd(&deg[dst[i]], 1);
}

__global__ void dinv_kernel(const int* __restrict__ deg, float* dinv, int n) {
    int i = blockIdx.x * blockDim.x + threadIdx.x;
    if (i < n) dinv[i] = rsqrtf((float)(deg[i] + 1));
}

__global__ __launch_bounds__(1024) void scan_kernel(const int* __restrict__ deg,
                                                    int* __restrict__ row_start, int n) {
    __shared__ int lsum[1024];
    int tid = threadIdx.x;
    int chunk = (n + 1023) / 1024;
    int i0 = tid * chunk, i1 = min(n, i0 + chunk);
    int s = 0;
    for (int i = i0; i < i1; ++i) s += deg[i];
    lsum[tid] = s;
    __syncthreads();
    for (int off = 1; off < 1024; off <<= 1) {
        int v = (tid >= off) ? lsum[tid - off] : 0;
        __syncthreads();
        lsum[tid] += v;
        __syncthreads();
    }
    int base = (tid == 0) ? 0 : lsum[tid - 1];
    for (int i = i0; i < i1; ++i) {
        row_start[i] = base;
        base += deg[i];
    }
    if (tid == 1023) row_start[n] = base;
}

__global__ void copy_int_kernel(const int* __restrict__ a, int* b, int n) {
    int i = blockIdx.x * blockDim.x + threadIdx.x;
    if (i < n) b[i] = a[i];
}

__global__ void fill_csr_kernel(const int* __restrict__ src, const int* __restrict__ dst,
                                int* __restrict__ cursor, int* __restrict__ csr_src, int E) {
    int i = blockIdx.x * blockDim.x + threadIdx.x;
    int stride = gridDim.x * blockDim.x;
    for (; i < E; i += stride) {
        int p = atomicAdd(&cursor[dst[i]], 1);
        csr_src[p] = src[i];
    }
}

// ---------------- operand packing (f32 -> bf16 hi/lo, MFMA fragment order) -------

// W[K][M] f32 -> Wf[kt][nt][lane][8hi|8lo]  (lane: q=lane>>4, m=lane&15;
//   element j: k = kt*32 + q*8 + j, n = nt*16 + m)
__global__ void wpack_kernel(const float* __restrict__ W, short* __restrict__ Wf,
                             int K, int M) {
    int t = blockIdx.x * blockDim.x + threadIdx.x;
    int KT = K >> 5, MT = M >> 4;
    if (t >= KT * MT * 64) return;
    int lane = t & 63, chunk = t >> 6;
    int kt = chunk / MT, nt = chunk % MT;
    int q = lane >> 4, m = lane & 15;
    int n = nt * 16 + m;
    short* op = Wf + (size_t)t * 16;
#pragma unroll
    for (int j = 0; j < 8; ++j) {
        float w = W[(size_t)(kt * 32 + q * 8 + j) * M + n];
        unsigned short hi = f2bf_rne(w);
        unsigned short lo = f2bf_rne(w - bf2f(hi));
        op[j] = (short)hi;
        op[8 + j] = (short)lo;
    }
}

// A[N][K] f32 -> Af[rt][kt][lane][8hi|8lo]; optional fused BN apply + relu.
// one wave per (rt,kt) tile; N_NODES % 16 == 0.
__global__ __launch_bounds__(256) void apack_kernel(
        const float* __restrict__ A, const float* __restrict__ scale,
        const float* __restrict__ shift, short* __restrict__ Af, int K) {
    int KT = K >> 5;
    int gw = blockIdx.x * 4 + (threadIdx.x >> 6);
    if (gw >= NT_ROWS * KT) return;
    int lane = threadIdx.x & 63;
    int rt = gw / KT, kt = gw % KT;
    int m = lane & 15, q = lane >> 4;
    int row = rt * 16 + m;
    int k0 = kt * 32 + q * 8;
    const float* ap = A + (size_t)row * K + k0;
    float v[8];
    *(float4*)(v) = *(const float4*)(ap);
    *(float4*)(v + 4) = *(const float4*)(ap + 4);
    if (scale) {
        float sc[8], sh[8];
        *(float4*)(sc) = *(const float4*)(scale + k0);
        *(float4*)(sc + 4) = *(const float4*)(scale + k0 + 4);
        *(float4*)(sh) = *(const float4*)(shift + k0);
        *(float4*)(sh + 4) = *(const float4*)(shift + k0 + 4);
#pragma unroll
        for (int j = 0; j < 8; ++j) v[j] = fmaxf(v[j] * sc[j] + sh[j], 0.0f);
    }
    short hi[8], lo[8];
#pragma unroll
    for (int j = 0; j < 8; ++j) {
        unsigned short h = f2bf_rne(v[j]);
        hi[j] = (short)h;
        lo[j] = (short)f2bf_rne(v[j] - bf2f(h));
    }
    short* op = Af + ((size_t)gw * 64 + lane) * 16;
    *(short8*)op = *(short8*)hi;
    *(short8*)(op + 8) = *(short8*)lo;
}

// ---------------- MFMA GEMM: H[N,M] = A[N,K] @ W[K,M] (+ optional bias) ----------
// block = 4 waves in 2x2, block tile 128x128, wave tile 64x64, no LDS.

template <int KT>
__global__ __launch_bounds__(256) void gemm_mfma_kernel(
        const short* __restrict__ Af, const short* __restrict__ Wf,
        const float* __restrict__ bias, float* __restrict__ H, int N, int M) {
    const int MT = M >> 4;
    int wave = threadIdx.x >> 6, lane = threadIdx.x & 63;
    int wr = wave >> 1, wc = wave & 1;
    int bm = blockIdx.x * 128 + wr * 64;
    int bn = blockIdx.y * 128 + wc * 64;
    int q = lane >> 4, l16 = lane & 15;
    int rtbase = bm >> 4;
    int ntbase = bn >> 4;
    floatx4 acc[4][4] = {};
    for (int kt = 0; kt < KT; ++kt) {
        short8 ahi[4], alo[4];
#pragma unroll
        for (int mt = 0; mt < 4; ++mt) {
            int rt = rtbase + mt;
            if (rt > NT_ROWS - 1) rt = NT_ROWS - 1;  // clamp; rows guarded at store
            const short* ap = Af + (((size_t)rt * KT + kt) * 64 + lane) * 16;
            ahi[mt] = *(const short8*)ap;
            alo[mt] = *(const short8*)(ap + 8);
        }
#pragma unroll
        for (int nt = 0; nt < 4; ++nt) {
            const short* wp = Wf + (((size_t)kt * MT + ntbase + nt) * 64 + lane) * 16;
            short8 bhi = *(const short8*)wp;
            short8 blo = *(const short8*)(wp + 8);
#pragma unroll
            for (int mt = 0; mt < 4; ++mt) {
                acc[mt][nt] = __builtin_amdgcn_mfma_f32_16x16x32_bf16(ahi[mt], bhi,
                                                                      acc[mt][nt], 0, 0, 0);
                acc[mt][nt] = __builtin_amdgcn_mfma_f32_16x16x32_bf16(ahi[mt], blo,
                                                                      acc[mt][nt], 0, 0, 0);
                acc[mt][nt] = __builtin_amdgcn_mfma_f32_16x16x32_bf16(alo[mt], bhi,
                                                                      acc[mt][nt], 0, 0, 0);
            }
        }
    }
#pragma unroll
    for (int nt = 0; nt < 4; ++nt) {
        int col = bn + nt * 16 + l16;
        float bv = bias ? bias[col] : 0.0f;
#pragma unroll
        for (int mt = 0; mt < 4; ++mt) {
#pragma unroll
            for (int r = 0; r < 4; ++r) {
                int row = bm + mt * 16 + q * 4 + r;
                if (row < N) H[(size_t)row * M + col] = acc[mt][nt][r] + bv;
            }
        }
    }
}

// ---------------- gather aggregation (CSR by dst) ----------------

template <int C>
__global__ __launch_bounds__(64) void gather_agg_kernel(
        const float* __restrict__ H, const float* __restrict__ dinv,
        const float* __restrict__ bias, const int* __restrict__ row_start,
        const int* __restrict__ csr_src, float* __restrict__ AGG, int n) {
    constexpr int V = C / 64;
    int i = blockIdx.x;
    if (i >= n) return;
    int lane = threadIdx.x;
    float di = dinv[i];
    float acc[V];
    const float* hrow = H + (size_t)i * C + lane * V;
#pragma unroll
    for (int v = 0; v < V; ++v) acc[v] = (bias ? bias[lane * V + v] : 0.0f) + hrow[v] * di * di;
    int e0 = row_start[i], e1 = row_start[i + 1];
    for (int e = e0; e < e1; ++e) {
        int s = csr_src[e];
        float w = dinv[s] * di;
        const float* srow = H + (size_t)s * C + lane * V;
#pragma unroll
        for (int v = 0; v < V; ++v) acc[v] += srow[v] * w;
    }
    float* orow = AGG + (size_t)i * C + lane * V;
#pragma unroll
    for (int v = 0; v < V; ++v) orow[v] = acc[v];
}

// ---------------- batch norm stats ----------------

__global__ void zero_kernel(float* p, int n) {
    int i = blockIdx.x * blockDim.x + threadIdx.x;
    if (i < n) p[i] = 0.0f;
}

__global__ void bn_stats_kernel(const float* __restrict__ A, float* __restrict__ sums,
                                float* __restrict__ sumsq, int n, int C) {
    int c = threadIdx.x;
    int rpb = (n + gridDim.x - 1) / gridDim.x;
    int r0 = blockIdx.x * rpb;
    int r1 = min(n, r0 + rpb);
    float s = 0.0f, s2 = 0.0f;
    for (int r = r0; r < r1; ++r) {
        float v = A[(size_t)r * C + c];
        s += v;
        s2 += v * v;
    }
    atomicAdd(&sums[c], s);
    atomicAdd(&sumsq[c], s2);
}

__global__ void bn_finalize_kernel(const float* __restrict__ sums, const float* __restrict__ sumsq,
                                   const float* __restrict__ gamma, const float* __restrict__ beta,
                                   float* __restrict__ scale, float* __restrict__ shift,
                                   int n, int C) {
    int c = threadIdx.x;
    if (c >= C) return;
    float inv_n = 1.0f / (float)n;
    float mu = sums[c] * inv_n;
    float var = sumsq[c] * inv_n - mu * mu;
    float rs = rsqrtf(var + EPS);
    float sc = gamma[c] * rs;
    scale[c] = sc;
    shift[c] = beta[c] - mu * sc;
}

// ---------------- pooling (sorted-segment, no atomics) ----------------

__global__ void graph_bounds_kernel(const int* __restrict__ batch, int* __restrict__ gstart,
                                    int n, int G) {
    int g = blockIdx.x * blockDim.x + threadIdx.x;
    if (g > G) return;
    int lo = 0, hi = n;
    while (lo < hi) {
        int mid = (lo + hi) >> 1;
        if (batch[mid] < g) lo = mid + 1; else hi = mid;
    }
    gstart[g] = lo;
}

__global__ __launch_bounds__(256) void pool_seg_kernel(
        const float* __restrict__ A, const float* __restrict__ scale,
        const float* __restrict__ shift, const int* __restrict__ gstart,
        float* __restrict__ out) {
    __shared__ float partial[256];
    int g = blockIdx.x;
    int tid = threadIdx.x;
    int c = tid & 127;
    int part = tid >> 7;
    int r0 = gstart[g], r1 = gstart[g + 1];
    float sc = scale[c], sh = shift[c];
    float s = 0.0f;
    for (int r = r0 + part; r < r1; r += 2) {
        float v = A[(size_t)r * 128 + c];
        s += fmaxf(v * sc + sh, 0.0f);
    }
    partial[tid] = s;
    __syncthreads();
    if (part == 0) {
        float tot = s + partial[c + 128];
        float cnt = (float)(r1 - r0);
        out[g * 128 + c] = tot / fmaxf(cnt, 1.0f);
    }
}

// ---------------- host-side helpers ----------------

static void run_bn_stats(hipStream_t stream, const float* A, const float* gamma,
                         const float* beta, int Cout, float* sums, float* sumsq,
                         float* scale, float* shift) {
    hipLaunchKernelGGL(zero_kernel, dim3(2), dim3(256), 0, stream, sums, 512);
    hipLaunchKernelGGL(bn_stats_kernel, dim3(256), dim3(Cout), 0, stream, A, sums, sumsq,
                       N_NODES, Cout);
    hipLaunchKernelGGL(bn_finalize_kernel, dim3(1), dim3(Cout), 0, stream, sums, sumsq, gamma,
                       beta, scale, shift, N_NODES, Cout);
}

extern "C" void kernel_launch(void* const* d_in, const int* in_sizes, int n_in,
                              void* d_out, int out_size, void* d_ws, size_t ws_size,
                              hipStream_t stream) {
    const float* x     = (const float*)d_in[0];
    const int*   ei    = (const int*)d_in[1];
    const int*   batch = (const int*)d_in[2];
    const float* W1 = (const float*)d_in[3];
    const float* b1 = (const float*)d_in[4];
    const float* W2 = (const float*)d_in[5];
    const float* b2 = (const float*)d_in[6];
    const float* W3 = (const float*)d_in[7];
    const float* b3 = (const float*)d_in[8];
    const float* g1 = (const float*)d_in[9];
    const float* be1 = (const float*)d_in[10];
    const float* g2 = (const float*)d_in[11];
    const float* be2 = (const float*)d_in[12];
    const float* g3 = (const float*)d_in[13];
    const float* be3 = (const float*)d_in[14];
    float* out = (float*)d_out;

    const int* src = ei;
    const int* dstv = ei + N_EDGES;

    size_t off = 0;
    auto allocb = [&](size_t nbytes) {
        char* p = (char*)d_ws + off;
        off += (nbytes + 255) & ~(size_t)255;
        return p;
    };
    int*   deg_int   = (int*)allocb(N_NODES * 4);
    int*   row_start = (int*)allocb((N_NODES + 1) * 4);
    int*   cursor    = (int*)allocb(N_NODES * 4);
    int*   csr_src   = (int*)allocb(N_EDGES * 4);
    int*   gstart    = (int*)allocb((NUM_GRAPHS + 1) * 4);
    float* dinv      = (float*)allocb(N_NODES * 4);
    float* sums      = (float*)allocb(512 * 4);
    float* sumsq     = sums + 256;
    float* scale     = (float*)allocb(256 * 4);
    float* shift     = (float*)allocb(256 * 4);
    short* W1f       = (short*)allocb((size_t)128 * 256 * 4);  // [kt][nt][64][16]
    short* W2f       = (short*)allocb((size_t)256 * 256 * 4);
    short* W3f       = (short*)allocb((size_t)256 * 128 * 4);
    float* bufA      = (float*)allocb((size_t)N_NODES * 256 * 4);
    float* bufB      = (float*)allocb((size_t)N_NODES * 256 * 4);
    (void)ws_size; (void)n_in; (void)in_sizes; (void)out_size;

    int nb = (N_NODES + 255) / 256;

    // ---- degree, dinv, CSR (by dst), graph bounds, W packing ----
    hipLaunchKernelGGL(zero_int_kernel, dim3(nb), dim3(256), 0, stream, deg_int, N_NODES);
    hipLaunchKernelGGL(count_deg_kernel, dim3(2048), dim3(256), 0, stream, dstv, deg_int, N_EDGES);
    hipLaunchKernelGGL(dinv_kernel, dim3(nb), dim3(256), 0, stream, deg_int, dinv, N_NODES);
    hipLaunchKernelGGL(scan_kernel, dim3(1), dim3(1024), 0, stream, deg_int, row_start, N_NODES);
    hipLaunchKernelGGL(copy_int_kernel, dim3(nb), dim3(256), 0, stream, row_start, cursor, N_NODES);
    hipLaunchKernelGGL(fill_csr_kernel, dim3(2048), dim3(256), 0, stream, src, dstv, cursor,
                       csr_src, N_EDGES);
    hipLaunchKernelGGL(graph_bounds_kernel, dim3(1), dim3(NUM_GRAPHS + 1), 0, stream, batch,
                       gstart, N_NODES, NUM_GRAPHS);
    hipLaunchKernelGGL(wpack_kernel, dim3(16), dim3(256), 0, stream, W1, W1f, 128, 256);
    hipLaunchKernelGGL(wpack_kernel, dim3(32), dim3(256), 0, stream, W2, W2f, 256, 256);
    hipLaunchKernelGGL(wpack_kernel, dim3(16), dim3(256), 0, stream, W3, W3f, 256, 128);

    int gx = (N_NODES + 127) / 128;  // 391

    // ---- layer 1: gather(x) -> bufA; pack -> bufB; gemm(+b1) -> bufA; stats ----
    hipLaunchKernelGGL((gather_agg_kernel<128>), dim3(N_NODES), dim3(64), 0, stream, x, dinv,
                       (const float*)nullptr, row_start, csr_src, bufA, N_NODES);
    hipLaunchKernelGGL(apack_kernel, dim3(NT_ROWS * 4 / 4), dim3(256), 0, stream, bufA,
                       (const float*)nullptr, (const float*)nullptr, (short*)bufB, 128);
    hipLaunchKernelGGL((gemm_mfma_kernel<4>), dim3(gx, 2), dim3(256), 0, stream, (short*)bufB,
                       W1f, b1, bufA, N_NODES, 256);
    run_bn_stats(stream, bufA, g1, be1, 256, sums, sumsq, scale, shift);

    // ---- layer 2: pack(BN1+relu) -> bufB; gemm -> bufA; gather(+b2) -> bufB; stats ----
    hipLaunchKernelGGL(apack_kernel, dim3(NT_ROWS * 8 / 4), dim3(256), 0, stream, bufA, scale,
                       shift, (short*)bufB, 256);
    hipLaunchKernelGGL((gemm_mfma_kernel<8>), dim3(gx, 2), dim3(256), 0, stream, (short*)bufB,
                       W2f, (const float*)nullptr, bufA, N_NODES, 256);
    hipLaunchKernelGGL((gather_agg_kernel<256>), dim3(N_NODES), dim3(64), 0, stream, bufA, dinv,
                       b2, row_start, csr_src, bufB, N_NODES);
    run_bn_stats(stream, bufB, g2, be2, 256, sums, sumsq, scale, shift);

    // ---- layer 3: pack(BN2+relu) -> bufA; gemm -> bufB; gather(+b3) -> bufA; stats ----
    hipLaunchKernelGGL(apack_kernel, dim3(NT_ROWS * 8 / 4), dim3(256), 0, stream, bufB, scale,
                       shift, (short*)bufA, 256);
    hipLaunchKernelGGL((gemm_mfma_kernel<8>), dim3(gx, 1), dim3(256), 0, stream, (short*)bufA,
                       W3f, (const float*)nullptr, bufB, N_NODES, 128);
    hipLaunchKernelGGL((gather_agg_kernel<128>), dim3(N_NODES), dim3(64), 0, stream, bufB, dinv,
                       b3, row_start, csr_src, bufA, N_NODES);
    run_bn_stats(stream, bufA, g3, be3, 128, sums, sumsq, scale, shift);

    // ---- pool: segmented mean with BN3 apply+relu fused ----
    hipLaunchKernelGGL(pool_seg_kernel, dim3(NUM_GRAPHS), dim3(256), 0, stream, bufA, scale,
                       shift, gstart, out);
}

// Round 5
// 811.673 us; speedup vs baseline: 3.2760x; 1.0689x over previous
//
#include <hip/hip_runtime.h>

#define N_NODES 50000
#define N_EDGES 800000
#define NUM_GRAPHS 128
#define EPS 1e-5f
#define NT_ROWS (N_NODES / 16)  // 3125 row tiles (exact)

typedef __attribute__((ext_vector_type(8))) short short8;
typedef __attribute__((ext_vector_type(4))) float floatx4;
typedef __attribute__((ext_vector_type(4))) unsigned short ushort4v;

__device__ __forceinline__ unsigned short f2bf_rne(float f) {
    unsigned int u = __float_as_uint(f);
    u += 0x7FFF + ((u >> 16) & 1);
    return (unsigned short)(u >> 16);
}
__device__ __forceinline__ float bf2f(unsigned short h) {
    return __uint_as_float(((unsigned int)h) << 16);
}

// ---------------- degree / CSR build ----------------

__global__ void zero_int_kernel(int* p, int n) {
    int i = blockIdx.x * blockDim.x + threadIdx.x;
    if (i < n) p[i] = 0;
}

__global__ void count_deg_kernel(const int* __restrict__ dst, int* deg, int E) {
    int i = blockIdx.x * blockDim.x + threadIdx.x;
    int stride = gridDim.x * blockDim.x;
    for (; i < E; i += stride) atomicAdd(&deg[dst[i]], 1);
}

__global__ void dinv_kernel(const int* __restrict__ deg, float* dinv, int n) {
    int i = blockIdx.x * blockDim.x + threadIdx.x;
    if (i < n) dinv[i] = rsqrtf((float)(deg[i] + 1));
}

__global__ __launch_bounds__(1024) void scan_kernel(const int* __restrict__ deg,
                                                    int* __restrict__ row_start, int n) {
    __shared__ int lsum[1024];
    int tid = threadIdx.x;
    int chunk = (n + 1023) / 1024;
    int i0 = tid * chunk, i1 = min(n, i0 + chunk);
    int s = 0;
    for (int i = i0; i < i1; ++i) s += deg[i];
    lsum[tid] = s;
    __syncthreads();
    for (int off = 1; off < 1024; off <<= 1) {
        int v = (tid >= off) ? lsum[tid - off] : 0;
        __syncthreads();
        lsum[tid] += v;
        __syncthreads();
    }
    int base = (tid == 0) ? 0 : lsum[tid - 1];
    for (int i = i0; i < i1; ++i) {
        row_start[i] = base;
        base += deg[i];
    }
    if (tid == 1023) row_start[n] = base;
}

__global__ void copy_int_kernel(const int* __restrict__ a, int* b, int n) {
    int i = blockIdx.x * blockDim.x + threadIdx.x;
    if (i < n) b[i] = a[i];
}

__global__ void fill_csr_kernel(const int* __restrict__ src, const int* __restrict__ dst,
                                int* __restrict__ cursor, int* __restrict__ csr_src, int E) {
    int i = blockIdx.x * blockDim.x + threadIdx.x;
    int stride = gridDim.x * blockDim.x;
    for (; i < E; i += stride) {
        int p = atomicAdd(&cursor[dst[i]], 1);
        csr_src[p] = src[i];
    }
}

// ---------------- f32 -> bf16 bulk convert (4 elems/thread) ----------------

__global__ void f2bf4_kernel(const float* __restrict__ in, unsigned short* __restrict__ out,
                             int n4) {
    int i = blockIdx.x * blockDim.x + threadIdx.x;
    if (i >= n4) return;
    float4 v = ((const float4*)in)[i];
    ushort4v o = {f2bf_rne(v.x), f2bf_rne(v.y), f2bf_rne(v.z), f2bf_rne(v.w)};
    ((ushort4v*)out)[i] = o;
}

// ---------------- operand packing (f32 -> bf16 hi/lo, MFMA fragment order) -------

__global__ void wpack_kernel(const float* __restrict__ W, short* __restrict__ Wf,
                             int K, int M) {
    int t = blockIdx.x * blockDim.x + threadIdx.x;
    int KT = K >> 5, MT = M >> 4;
    if (t >= KT * MT * 64) return;
    int lane = t & 63, chunk = t >> 6;
    int kt = chunk / MT, nt = chunk % MT;
    int q = lane >> 4, m = lane & 15;
    int n = nt * 16 + m;
    short* op = Wf + (size_t)t * 16;
#pragma unroll
    for (int j = 0; j < 8; ++j) {
        float w = W[(size_t)(kt * 32 + q * 8 + j) * M + n];
        unsigned short hi = f2bf_rne(w);
        unsigned short lo = f2bf_rne(w - bf2f(hi));
        op[j] = (short)hi;
        op[8 + j] = (short)lo;
    }
}

// A[N][K] f32 -> Af[rt][kt][lane][8hi|8lo]; optional fused BN apply + relu.
__global__ __launch_bounds__(256) void apack_kernel(
        const float* __restrict__ A, const float* __restrict__ scale,
        const float* __restrict__ shift, short* __restrict__ Af, int K) {
    int KT = K >> 5;
    int gw = blockIdx.x * 4 + (threadIdx.x >> 6);
    if (gw >= NT_ROWS * KT) return;
    int lane = threadIdx.x & 63;
    int rt = gw / KT, kt = gw % KT;
    int m = lane & 15, q = lane >> 4;
    int row = rt * 16 + m;
    int k0 = kt * 32 + q * 8;
    const float* ap = A + (size_t)row * K + k0;
    float v[8];
    *(float4*)(v) = *(const float4*)(ap);
    *(float4*)(v + 4) = *(const float4*)(ap + 4);
    if (scale) {
        float sc[8], sh[8];
        *(float4*)(sc) = *(const float4*)(scale + k0);
        *(float4*)(sc + 4) = *(const float4*)(scale + k0 + 4);
        *(float4*)(sh) = *(const float4*)(shift + k0);
        *(float4*)(sh + 4) = *(const float4*)(shift + k0 + 4);
#pragma unroll
        for (int j = 0; j < 8; ++j) v[j] = fmaxf(v[j] * sc[j] + sh[j], 0.0f);
    }
    short hi[8], lo[8];
#pragma unroll
    for (int j = 0; j < 8; ++j) {
        unsigned short h = f2bf_rne(v[j]);
        hi[j] = (short)h;
        lo[j] = (short)f2bf_rne(v[j] - bf2f(h));
    }
    short* op = Af + ((size_t)gw * 64 + lane) * 16;
    *(short8*)op = *(short8*)hi;
    *(short8*)(op + 8) = *(short8*)lo;
}

// ---------------- MFMA GEMM: H[N,M] = A[N,K] @ W[K,M] (+ optional bias) ----------
// block = 4 waves in 2x2, block tile 128x128, wave tile 64x64, no LDS.
// BF16OUT: epilogue rounds to bf16 (consumed by the bf16 gather).

template <int KT, bool BF16OUT>
__global__ __launch_bounds__(256) void gemm_mfma_kernel(
        const short* __restrict__ Af, const short* __restrict__ Wf,
        const float* __restrict__ bias, void* __restrict__ Hout, int N, int M) {
    const int MT = M >> 4;
    int wave = threadIdx.x >> 6, lane = threadIdx.x & 63;
    int wr = wave >> 1, wc = wave & 1;
    int bm = blockIdx.x * 128 + wr * 64;
    int bn = blockIdx.y * 128 + wc * 64;
    int q = lane >> 4, l16 = lane & 15;
    int rtbase = bm >> 4;
    int ntbase = bn >> 4;
    floatx4 acc[4][4] = {};
    for (int kt = 0; kt < KT; ++kt) {
        short8 ahi[4], alo[4];
#pragma unroll
        for (int mt = 0; mt < 4; ++mt) {
            int rt = rtbase + mt;
            if (rt > NT_ROWS - 1) rt = NT_ROWS - 1;
            const short* ap = Af + (((size_t)rt * KT + kt) * 64 + lane) * 16;
            ahi[mt] = *(const short8*)ap;
            alo[mt] = *(const short8*)(ap + 8);
        }
#pragma unroll
        for (int nt = 0; nt < 4; ++nt) {
            const short* wp = Wf + (((size_t)kt * MT + ntbase + nt) * 64 + lane) * 16;
            short8 bhi = *(const short8*)wp;
            short8 blo = *(const short8*)(wp + 8);
#pragma unroll
            for (int mt = 0; mt < 4; ++mt) {
                acc[mt][nt] = __builtin_amdgcn_mfma_f32_16x16x32_bf16(ahi[mt], bhi,
                                                                      acc[mt][nt], 0, 0, 0);
                acc[mt][nt] = __builtin_amdgcn_mfma_f32_16x16x32_bf16(ahi[mt], blo,
                                                                      acc[mt][nt], 0, 0, 0);
                acc[mt][nt] = __builtin_amdgcn_mfma_f32_16x16x32_bf16(alo[mt], bhi,
                                                                      acc[mt][nt], 0, 0, 0);
            }
        }
    }
#pragma unroll
    for (int nt = 0; nt < 4; ++nt) {
        int col = bn + nt * 16 + l16;
        float bv = bias ? bias[col] : 0.0f;
#pragma unroll
        for (int mt = 0; mt < 4; ++mt) {
#pragma unroll
            for (int r = 0; r < 4; ++r) {
                int row = bm + mt * 16 + q * 4 + r;
                if (row < N) {
                    float v = acc[mt][nt][r] + bv;
                    if constexpr (BF16OUT)
                        ((unsigned short*)Hout)[(size_t)row * M + col] = f2bf_rne(v);
                    else
                        ((float*)Hout)[(size_t)row * M + col] = v;
                }
            }
        }
    }
}

// ---------------- gather aggregation (CSR by dst, bf16 input, f32 out) ----------

template <int C>
__global__ __launch_bounds__(64) void gather_agg_bf16_kernel(
        const unsigned short* __restrict__ Hb, const float* __restrict__ dinv,
        const float* __restrict__ bias, const int* __restrict__ row_start,
        const int* __restrict__ csr_src, float* __restrict__ AGG, int n) {
    constexpr int V = C / 64;  // 2 or 4 channels per lane
    constexpr int U = V / 2;   // packed uints per lane
    int i = blockIdx.x;
    if (i >= n) return;
    int lane = threadIdx.x;
    float di = dinv[i];
    float w0 = di * di;
    const unsigned int* base = (const unsigned int*)Hb;
    float acc[V];
    {
        const unsigned int* hrow = base + ((size_t)i * C >> 1) + lane * U;
#pragma unroll
        for (int t = 0; t < U; ++t) {
            unsigned int u = hrow[t];
            float f0 = __uint_as_float(u << 16);
            float f1 = __uint_as_float(u & 0xFFFF0000u);
            acc[2 * t] = (bias ? bias[lane * V + 2 * t] : 0.0f) + f0 * w0;
            acc[2 * t + 1] = (bias ? bias[lane * V + 2 * t + 1] : 0.0f) + f1 * w0;
        }
    }
    int e0 = row_start[i], e1 = row_start[i + 1];
    for (int e = e0; e < e1; ++e) {
        int s = csr_src[e];
        float w = dinv[s] * di;
        const unsigned int* srow = base + ((size_t)s * C >> 1) + lane * U;
#pragma unroll
        for (int t = 0; t < U; ++t) {
            unsigned int u = srow[t];
            acc[2 * t] += __uint_as_float(u << 16) * w;
            acc[2 * t + 1] += __uint_as_float(u & 0xFFFF0000u) * w;
        }
    }
    float* orow = AGG + (size_t)i * C + lane * V;
    if constexpr (V == 4)
        *(float4*)orow = make_float4(acc[0], acc[1], acc[2], acc[3]);
    else
        *(float2*)orow = make_float2(acc[0], acc[1]);
}

// ---------------- batch norm stats ----------------

__global__ void zero_kernel(float* p, int n) {
    int i = blockIdx.x * blockDim.x + threadIdx.x;
    if (i < n) p[i] = 0.0f;
}

__global__ void bn_stats_kernel(const float* __restrict__ A, float* __restrict__ sums,
                                float* __restrict__ sumsq, int n, int C) {
    int c = threadIdx.x;
    int rpb = (n + gridDim.x - 1) / gridDim.x;
    int r0 = blockIdx.x * rpb;
    int r1 = min(n, r0 + rpb);
    float s = 0.0f, s2 = 0.0f;
    for (int r = r0; r < r1; ++r) {
        float v = A[(size_t)r * C + c];
        s += v;
        s2 += v * v;
    }
    atomicAdd(&sums[c], s);
    atomicAdd(&sumsq[c], s2);
}

__global__ void bn_finalize_kernel(const float* __restrict__ sums, const float* __restrict__ sumsq,
                                   const float* __restrict__ gamma, const float* __restrict__ beta,
                                   float* __restrict__ scale, float* __restrict__ shift,
                                   int n, int C) {
    int c = threadIdx.x;
    if (c >= C) return;
    float inv_n = 1.0f / (float)n;
    float mu = sums[c] * inv_n;
    float var = sumsq[c] * inv_n - mu * mu;
    float rs = rsqrtf(var + EPS);
    float sc = gamma[c] * rs;
    scale[c] = sc;
    shift[c] = beta[c] - mu * sc;
}

// ---------------- pooling (sorted-segment, no atomics) ----------------

__global__ void graph_bounds_kernel(const int* __restrict__ batch, int* __restrict__ gstart,
                                    int n, int G) {
    int g = blockIdx.x * blockDim.x + threadIdx.x;
    if (g > G) return;
    int lo = 0, hi = n;
    while (lo < hi) {
        int mid = (lo + hi) >> 1;
        if (batch[mid] < g) lo = mid + 1; else hi = mid;
    }
    gstart[g] = lo;
}

__global__ __launch_bounds__(256) void pool_seg_kernel(
        const float* __restrict__ A, const float* __restrict__ scale,
        const float* __restrict__ shift, const int* __restrict__ gstart,
        float* __restrict__ out) {
    __shared__ float partial[256];
    int g = blockIdx.x;
    int tid = threadIdx.x;
    int c = tid & 127;
    int part = tid >> 7;
    int r0 = gstart[g], r1 = gstart[g + 1];
    float sc = scale[c], sh = shift[c];
    float s = 0.0f;
    for (int r = r0 + part; r < r1; r += 2) {
        float v = A[(size_t)r * 128 + c];
        s += fmaxf(v * sc + sh, 0.0f);
    }
    partial[tid] = s;
    __syncthreads();
    if (part == 0) {
        float tot = s + partial[c + 128];
        float cnt = (float)(r1 - r0);
        out[g * 128 + c] = tot / fmaxf(cnt, 1.0f);
    }
}

// ---------------- host-side helpers ----------------

static void run_bn_stats(hipStream_t stream, const float* A, const float* gamma,
                         const float* beta, int Cout, float* sums, float* sumsq,
                         float* scale, float* shift) {
    hipLaunchKernelGGL(zero_kernel, dim3(2), dim3(256), 0, stream, sums, 512);
    hipLaunchKernelGGL(bn_stats_kernel, dim3(256), dim3(Cout), 0, stream, A, sums, sumsq,
                       N_NODES, Cout);
    hipLaunchKernelGGL(bn_finalize_kernel, dim3(1), dim3(Cout), 0, stream, sums, sumsq, gamma,
                       beta, scale, shift, N_NODES, Cout);
}

extern "C" void kernel_launch(void* const* d_in, const int* in_sizes, int n_in,
                              void* d_out, int out_size, void* d_ws, size_t ws_size,
                              hipStream_t stream) {
    const float* x     = (const float*)d_in[0];
    const int*   ei    = (const int*)d_in[1];
    const int*   batch = (const int*)d_in[2];
    const float* W1 = (const float*)d_in[3];
    const float* b1 = (const float*)d_in[4];
    const float* W2 = (const float*)d_in[5];
    const float* b2 = (const float*)d_in[6];
    const float* W3 = (const float*)d_in[7];
    const float* b3 = (const float*)d_in[8];
    const float* g1 = (const float*)d_in[9];
    const float* be1 = (const float*)d_in[10];
    const float* g2 = (const float*)d_in[11];
    const float* be2 = (const float*)d_in[12];
    const float* g3 = (const float*)d_in[13];
    const float* be3 = (const float*)d_in[14];
    float* out = (float*)d_out;

    const int* src = ei;
    const int* dstv = ei + N_EDGES;

    size_t off = 0;
    auto allocb = [&](size_t nbytes) {
        char* p = (char*)d_ws + off;
        off += (nbytes + 255) & ~(size_t)255;
        return p;
    };
    int*   deg_int   = (int*)allocb(N_NODES * 4);
    int*   row_start = (int*)allocb((N_NODES + 1) * 4);
    int*   cursor    = (int*)allocb(N_NODES * 4);
    int*   csr_src   = (int*)allocb(N_EDGES * 4);
    int*   gstart    = (int*)allocb((NUM_GRAPHS + 1) * 4);
    float* dinv      = (float*)allocb(N_NODES * 4);
    float* sums      = (float*)allocb(512 * 4);
    float* sumsq     = sums + 256;
    float* scale     = (float*)allocb(256 * 4);
    float* shift     = (float*)allocb(256 * 4);
    short* W1f       = (short*)allocb((size_t)128 * 256 * 4);
    short* W2f       = (short*)allocb((size_t)256 * 256 * 4);
    short* W3f       = (short*)allocb((size_t)256 * 128 * 4);
    unsigned short* Hbf = (unsigned short*)allocb((size_t)N_NODES * 256 * 2);  // bf16 buffer
    float* bufA      = (float*)allocb((size_t)N_NODES * 256 * 4);
    float* bufB      = (float*)allocb((size_t)N_NODES * 256 * 4);
    unsigned short* xbf = Hbf;  // x-bf16 aliases Hbf (dead until layer-2 GEMM)
    (void)ws_size; (void)n_in; (void)in_sizes; (void)out_size;

    int nb = (N_NODES + 255) / 256;

    // ---- degree, dinv, CSR (by dst), graph bounds, W packing, x->bf16 ----
    hipLaunchKernelGGL(zero_int_kernel, dim3(nb), dim3(256), 0, stream, deg_int, N_NODES);
    hipLaunchKernelGGL(count_deg_kernel, dim3(2048), dim3(256), 0, stream, dstv, deg_int, N_EDGES);
    hipLaunchKernelGGL(dinv_kernel, dim3(nb), dim3(256), 0, stream, deg_int, dinv, N_NODES);
    hipLaunchKernelGGL(scan_kernel, dim3(1), dim3(1024), 0, stream, deg_int, row_start, N_NODES);
    hipLaunchKernelGGL(copy_int_kernel, dim3(nb), dim3(256), 0, stream, row_start, cursor, N_NODES);
    hipLaunchKernelGGL(fill_csr_kernel, dim3(2048), dim3(256), 0, stream, src, dstv, cursor,
                       csr_src, N_EDGES);
    hipLaunchKernelGGL(graph_bounds_kernel, dim3(1), dim3(NUM_GRAPHS + 1), 0, stream, batch,
                       gstart, N_NODES, NUM_GRAPHS);
    hipLaunchKernelGGL(wpack_kernel, dim3(16), dim3(256), 0, stream, W1, W1f, 128, 256);
    hipLaunchKernelGGL(wpack_kernel, dim3(32), dim3(256), 0, stream, W2, W2f, 256, 256);
    hipLaunchKernelGGL(wpack_kernel, dim3(16), dim3(256), 0, stream, W3, W3f, 256, 128);
    int n4 = N_NODES * 128 / 4;
    hipLaunchKernelGGL(f2bf4_kernel, dim3((n4 + 255) / 256), dim3(256), 0, stream, x, xbf, n4);

    int gx = (N_NODES + 127) / 128;  // 391

    // ---- layer 1: gather(xbf) -> bufA; pack -> bufB; gemm(+b1) -> bufA (f32); stats ----
    hipLaunchKernelGGL((gather_agg_bf16_kernel<128>), dim3(N_NODES), dim3(64), 0, stream, xbf,
                       dinv, (const float*)nullptr, row_start, csr_src, bufA, N_NODES);
    hipLaunchKernelGGL(apack_kernel, dim3(NT_ROWS * 4 / 4), dim3(256), 0, stream, bufA,
                       (const float*)nullptr, (const float*)nullptr, (short*)bufB, 128);
    hipLaunchKernelGGL((gemm_mfma_kernel<4, false>), dim3(gx, 2), dim3(256), 0, stream,
                       (short*)bufB, W1f, b1, bufA, N_NODES, 256);
    run_bn_stats(stream, bufA, g1, be1, 256, sums, sumsq, scale, shift);

    // ---- layer 2: pack(BN1+relu) -> bufB; gemm -> Hbf (bf16); gather(+b2) -> bufA; stats ----
    hipLaunchKernelGGL(apack_kernel, dim3(NT_ROWS * 8 / 4), dim3(256), 0, stream, bufA, scale,
                       shift, (short*)bufB, 256);
    hipLaunchKernelGGL((gemm_mfma_kernel<8, true>), dim3(gx, 2), dim3(256), 0, stream,
                       (short*)bufB, W2f, (const float*)nullptr, Hbf, N_NODES, 256);
    hipLaunchKernelGGL((gather_agg_bf16_kernel<256>), dim3(N_NODES), dim3(64), 0, stream, Hbf,
                       dinv, b2, row_start, csr_src, bufA, N_NODES);
    run_bn_stats(stream, bufA, g2, be2, 256, sums, sumsq, scale, shift);

    // ---- layer 3: pack(BN2+relu) -> bufB; gemm -> Hbf (bf16); gather(+b3) -> bufA; stats ----
    hipLaunchKernelGGL(apack_kernel, dim3(NT_ROWS * 8 / 4), dim3(256), 0, stream, bufA, scale,
                       shift, (short*)bufB, 256);
    hipLaunchKernelGGL((gemm_mfma_kernel<8, true>), dim3(gx, 1), dim3(256), 0, stream,
                       (short*)bufB, W3f, (const float*)nullptr, Hbf, N_NODES, 128);
    hipLaunchKernelGGL((gather_agg_bf16_kernel<128>), dim3(N_NODES), dim3(64), 0, stream, Hbf,
                       dinv, b3, row_start, csr_src, bufA, N_NODES);
    run_bn_stats(stream, bufA, g3, be3, 128, sums, sumsq, scale, shift);

    // ---- pool: segmented mean with BN3 apply+relu fused ----
    hipLaunchKernelGGL(pool_seg_kernel, dim3(NUM_GRAPHS), dim3(256), 0, stream, bufA, scale,
                       shift, gstart, out);
}

// Round 6
// 732.235 us; speedup vs baseline: 3.6314x; 1.1085x over previous
//
#include <hip/hip_runtime.h>

#define N_NODES 50000
#define N_EDGES 800000
#define NUM_GRAPHS 128
#define EPS 1e-5f
#define NT_ROWS (N_NODES / 16)   // 3125 row tiles (exact)
#define SCAN_BLOCKS 196          // ceil(50000/256)

typedef __attribute__((ext_vector_type(8))) short short8;
typedef __attribute__((ext_vector_type(4))) float floatx4;
typedef __attribute__((ext_vector_type(4))) unsigned short ushort4v;

__device__ __forceinline__ unsigned short f2bf_rne(float f) {
    unsigned int u = __float_as_uint(f);
    u += 0x7FFF + ((u >> 16) & 1);
    return (unsigned short)(u >> 16);
}
__device__ __forceinline__ float bf2f(unsigned short h) {
    return __uint_as_float(((unsigned int)h) << 16);
}

// ---------------- degree / CSR build ----------------

__global__ void zero_int_kernel(int* p, int n) {
    int i = blockIdx.x * blockDim.x + threadIdx.x;
    if (i < n) p[i] = 0;
}

__global__ void count_deg_kernel(const int* __restrict__ dst, int* deg, int E) {
    int i = blockIdx.x * blockDim.x + threadIdx.x;
    int stride = gridDim.x * blockDim.x;
    for (; i < E; i += stride) atomicAdd(&deg[dst[i]], 1);
}

__global__ void dinv_kernel(const int* __restrict__ deg, float* dinv, int n) {
    int i = blockIdx.x * blockDim.x + threadIdx.x;
    if (i < n) dinv[i] = rsqrtf((float)(deg[i] + 1));
}

// phase 1: per-block sums of 256-element chunks
__global__ __launch_bounds__(256) void scan_p1_kernel(const int* __restrict__ deg,
                                                      int* __restrict__ partial, int n) {
    __shared__ int red[256];
    int tid = threadIdx.x;
    int i = blockIdx.x * 256 + tid;
    red[tid] = (i < n) ? deg[i] : 0;
    __syncthreads();
#pragma unroll
    for (int s = 128; s > 0; s >>= 1) {
        if (tid < s) red[tid] += red[tid + s];
        __syncthreads();
    }
    if (tid == 0) partial[blockIdx.x] = red[0];
}

// phase 2: exclusive scan of the block partials (nb <= 256); also row_start[n] = E
__global__ __launch_bounds__(256) void scan_p2_kernel(const int* __restrict__ partial,
                                                      int* __restrict__ block_off,
                                                      int* __restrict__ row_start,
                                                      int nb, int n, int E) {
    __shared__ int s[256];
    int tid = threadIdx.x;
    int v = (tid < nb) ? partial[tid] : 0;
    s[tid] = v;
    __syncthreads();
#pragma unroll
    for (int off = 1; off < 256; off <<= 1) {
        int t = (tid >= off) ? s[tid - off] : 0;
        __syncthreads();
        s[tid] += t;
        __syncthreads();
    }
    if (tid < nb) block_off[tid] = s[tid] - v;  // exclusive
    if (tid == 0) row_start[n] = E;
}

// phase 3: per-block exclusive scan + block offset -> row_start & cursor
__global__ __launch_bounds__(256) void scan_p3_kernel(const int* __restrict__ deg,
                                                      const int* __restrict__ block_off,
                                                      int* __restrict__ row_start,
                                                      int* __restrict__ cursor, int n) {
    __shared__ int s[256];
    int tid = threadIdx.x;
    int i = blockIdx.x * 256 + tid;
    int v = (i < n) ? deg[i] : 0;
    s[tid] = v;
    __syncthreads();
#pragma unroll
    for (int off = 1; off < 256; off <<= 1) {
        int t = (tid >= off) ? s[tid - off] : 0;
        __syncthreads();
        s[tid] += t;
        __syncthreads();
    }
    if (i < n) {
        int r = block_off[blockIdx.x] + s[tid] - v;  // exclusive prefix
        row_start[i] = r;
        cursor[i] = r;
    }
}

__global__ void fill_csr_kernel(const int* __restrict__ src, const int* __restrict__ dst,
                                int* __restrict__ cursor, int* __restrict__ csr_src, int E) {
    int i = blockIdx.x * blockDim.x + threadIdx.x;
    int stride = gridDim.x * blockDim.x;
    for (; i < E; i += stride) {
        int p = atomicAdd(&cursor[dst[i]], 1);
        csr_src[p] = src[i];
    }
}

// ---------------- f32 -> bf16 bulk convert (4 elems/thread) ----------------

__global__ void f2bf4_kernel(const float* __restrict__ in, unsigned short* __restrict__ out,
                             int n4) {
    int i = blockIdx.x * blockDim.x + threadIdx.x;
    if (i >= n4) return;
    float4 v = ((const float4*)in)[i];
    ushort4v o = {f2bf_rne(v.x), f2bf_rne(v.y), f2bf_rne(v.z), f2bf_rne(v.w)};
    ((ushort4v*)out)[i] = o;
}

// ---------------- operand packing (f32 -> bf16 hi/lo, MFMA fragment order) -------

__global__ void wpack_kernel(const float* __restrict__ W, short* __restrict__ Wf,
                             int K, int M) {
    int t = blockIdx.x * blockDim.x + threadIdx.x;
    int KT = K >> 5, MT = M >> 4;
    if (t >= KT * MT * 64) return;
    int lane = t & 63, chunk = t >> 6;
    int kt = chunk / MT, nt = chunk % MT;
    int q = lane >> 4, m = lane & 15;
    int n = nt * 16 + m;
    short* op = Wf + (size_t)t * 16;
#pragma unroll
    for (int j = 0; j < 8; ++j) {
        float w = W[(size_t)(kt * 32 + q * 8 + j) * M + n];
        unsigned short hi = f2bf_rne(w);
        unsigned short lo = f2bf_rne(w - bf2f(hi));
        op[j] = (short)hi;
        op[8 + j] = (short)lo;
    }
}

// A[N][K] f32 -> Af[rt][kt][lane][8hi|8lo]; optional fused BN apply + relu.
__global__ __launch_bounds__(256) void apack_kernel(
        const float* __restrict__ A, const float* __restrict__ scale,
        const float* __restrict__ shift, short* __restrict__ Af, int K) {
    int KT = K >> 5;
    int gw = blockIdx.x * 4 + (threadIdx.x >> 6);
    if (gw >= NT_ROWS * KT) return;
    int lane = threadIdx.x & 63;
    int rt = gw / KT, kt = gw % KT;
    int m = lane & 15, q = lane >> 4;
    int row = rt * 16 + m;
    int k0 = kt * 32 + q * 8;
    const float* ap = A + (size_t)row * K + k0;
    float v[8];
    *(float4*)(v) = *(const float4*)(ap);
    *(float4*)(v + 4) = *(const float4*)(ap + 4);
    if (scale) {
        float sc[8], sh[8];
        *(float4*)(sc) = *(const float4*)(scale + k0);
        *(float4*)(sc + 4) = *(const float4*)(scale + k0 + 4);
        *(float4*)(sh) = *(const float4*)(shift + k0);
        *(float4*)(sh + 4) = *(const float4*)(shift + k0 + 4);
#pragma unroll
        for (int j = 0; j < 8; ++j) v[j] = fmaxf(v[j] * sc[j] + sh[j], 0.0f);
    }
    short hi[8], lo[8];
#pragma unroll
    for (int j = 0; j < 8; ++j) {
        unsigned short h = f2bf_rne(v[j]);
        hi[j] = (short)h;
        lo[j] = (short)f2bf_rne(v[j] - bf2f(h));
    }
    short* op = Af + ((size_t)gw * 64 + lane) * 16;
    *(short8*)op = *(short8*)hi;
    *(short8*)(op + 8) = *(short8*)lo;
}

// ---------------- MFMA GEMM: H[N,M] = A[N,K] @ W[K,M] (+ optional bias) ----------

template <int KT, bool BF16OUT>
__global__ __launch_bounds__(256) void gemm_mfma_kernel(
        const short* __restrict__ Af, const short* __restrict__ Wf,
        const float* __restrict__ bias, void* __restrict__ Hout, int N, int M) {
    const int MT = M >> 4;
    int wave = threadIdx.x >> 6, lane = threadIdx.x & 63;
    int wr = wave >> 1, wc = wave & 1;
    int bm = blockIdx.x * 128 + wr * 64;
    int bn = blockIdx.y * 128 + wc * 64;
    int q = lane >> 4, l16 = lane & 15;
    int rtbase = bm >> 4;
    int ntbase = bn >> 4;
    floatx4 acc[4][4] = {};
    for (int kt = 0; kt < KT; ++kt) {
        short8 ahi[4], alo[4];
#pragma unroll
        for (int mt = 0; mt < 4; ++mt) {
            int rt = rtbase + mt;
            if (rt > NT_ROWS - 1) rt = NT_ROWS - 1;
            const short* ap = Af + (((size_t)rt * KT + kt) * 64 + lane) * 16;
            ahi[mt] = *(const short8*)ap;
            alo[mt] = *(const short8*)(ap + 8);
        }
#pragma unroll
        for (int nt = 0; nt < 4; ++nt) {
            const short* wp = Wf + (((size_t)kt * MT + ntbase + nt) * 64 + lane) * 16;
            short8 bhi = *(const short8*)wp;
            short8 blo = *(const short8*)(wp + 8);
#pragma unroll
            for (int mt = 0; mt < 4; ++mt) {
                acc[mt][nt] = __builtin_amdgcn_mfma_f32_16x16x32_bf16(ahi[mt], bhi,
                                                                      acc[mt][nt], 0, 0, 0);
                acc[mt][nt] = __builtin_amdgcn_mfma_f32_16x16x32_bf16(ahi[mt], blo,
                                                                      acc[mt][nt], 0, 0, 0);
                acc[mt][nt] = __builtin_amdgcn_mfma_f32_16x16x32_bf16(alo[mt], bhi,
                                                                      acc[mt][nt], 0, 0, 0);
            }
        }
    }
#pragma unroll
    for (int nt = 0; nt < 4; ++nt) {
        int col = bn + nt * 16 + l16;
        float bv = bias ? bias[col] : 0.0f;
#pragma unroll
        for (int mt = 0; mt < 4; ++mt) {
#pragma unroll
            for (int r = 0; r < 4; ++r) {
                int row = bm + mt * 16 + q * 4 + r;
                if (row < N) {
                    float v = acc[mt][nt][r] + bv;
                    if constexpr (BF16OUT)
                        ((unsigned short*)Hout)[(size_t)row * M + col] = f2bf_rne(v);
                    else
                        ((float*)Hout)[(size_t)row * M + col] = v;
                }
            }
        }
    }
}

// ---------------- gather aggregation (CSR by dst, bf16 input, f32 out) ----------

template <int C>
__global__ __launch_bounds__(64) void gather_agg_bf16_kernel(
        const unsigned short* __restrict__ Hb, const float* __restrict__ dinv,
        const float* __restrict__ bias, const int* __restrict__ row_start,
        const int* __restrict__ csr_src, float* __restrict__ AGG, int n) {
    constexpr int V = C / 64;  // 2 or 4 channels per lane
    constexpr int U = V / 2;   // packed uints per lane
    int i = blockIdx.x;
    if (i >= n) return;
    int lane = threadIdx.x;
    float di = dinv[i];
    float w0 = di * di;
    const unsigned int* base = (const unsigned int*)Hb;
    float acc[V];
    {
        const unsigned int* hrow = base + ((size_t)i * C >> 1) + lane * U;
#pragma unroll
        for (int t = 0; t < U; ++t) {
            unsigned int u = hrow[t];
            float f0 = __uint_as_float(u << 16);
            float f1 = __uint_as_float(u & 0xFFFF0000u);
            acc[2 * t] = (bias ? bias[lane * V + 2 * t] : 0.0f) + f0 * w0;
            acc[2 * t + 1] = (bias ? bias[lane * V + 2 * t + 1] : 0.0f) + f1 * w0;
        }
    }
    int e0 = row_start[i], e1 = row_start[i + 1];
    for (int e = e0; e < e1; ++e) {
        int s = csr_src[e];
        float w = dinv[s] * di;
        const unsigned int* srow = base + ((size_t)s * C >> 1) + lane * U;
#pragma unroll
        for (int t = 0; t < U; ++t) {
            unsigned int u = srow[t];
            acc[2 * t] += __uint_as_float(u << 16) * w;
            acc[2 * t + 1] += __uint_as_float(u & 0xFFFF0000u) * w;
        }
    }
    float* orow = AGG + (size_t)i * C + lane * V;
    if constexpr (V == 4)
        *(float4*)orow = make_float4(acc[0], acc[1], acc[2], acc[3]);
    else
        *(float2*)orow = make_float2(acc[0], acc[1]);
}

// ---------------- batch norm stats ----------------

__global__ void zero_kernel(float* p, int n) {
    int i = blockIdx.x * blockDim.x + threadIdx.x;
    if (i < n) p[i] = 0.0f;
}

__global__ void bn_stats_kernel(const float* __restrict__ A, float* __restrict__ sums,
                                float* __restrict__ sumsq, int n, int C) {
    int c = threadIdx.x;
    int rpb = (n + gridDim.x - 1) / gridDim.x;
    int r0 = blockIdx.x * rpb;
    int r1 = min(n, r0 + rpb);
    float s = 0.0f, s2 = 0.0f;
    for (int r = r0; r < r1; ++r) {
        float v = A[(size_t)r * C + c];
        s += v;
        s2 += v * v;
    }
    atomicAdd(&sums[c], s);
    atomicAdd(&sumsq[c], s2);
}

__global__ void bn_finalize_kernel(const float* __restrict__ sums, const float* __restrict__ sumsq,
                                   const float* __restrict__ gamma, const float* __restrict__ beta,
                                   float* __restrict__ scale, float* __restrict__ shift,
                                   int n, int C) {
    int c = threadIdx.x;
    if (c >= C) return;
    float inv_n = 1.0f / (float)n;
    float mu = sums[c] * inv_n;
    float var = sumsq[c] * inv_n - mu * mu;
    float rs = rsqrtf(var + EPS);
    float sc = gamma[c] * rs;
    scale[c] = sc;
    shift[c] = beta[c] - mu * sc;
}

// ---------------- pooling (sorted-segment, no atomics) ----------------

__global__ void graph_bounds_kernel(const int* __restrict__ batch, int* __restrict__ gstart,
                                    int n, int G) {
    int g = blockIdx.x * blockDim.x + threadIdx.x;
    if (g > G) return;
    int lo = 0, hi = n;
    while (lo < hi) {
        int mid = (lo + hi) >> 1;
        if (batch[mid] < g) lo = mid + 1; else hi = mid;
    }
    gstart[g] = lo;
}

__global__ __launch_bounds__(256) void pool_seg_kernel(
        const float* __restrict__ A, const float* __restrict__ scale,
        const float* __restrict__ shift, const int* __restrict__ gstart,
        float* __restrict__ out) {
    __shared__ float partial[256];
    int g = blockIdx.x;
    int tid = threadIdx.x;
    int c = tid & 127;
    int part = tid >> 7;
    int r0 = gstart[g], r1 = gstart[g + 1];
    float sc = scale[c], sh = shift[c];
    float s = 0.0f;
    for (int r = r0 + part; r < r1; r += 2) {
        float v = A[(size_t)r * 128 + c];
        s += fmaxf(v * sc + sh, 0.0f);
    }
    partial[tid] = s;
    __syncthreads();
    if (part == 0) {
        float tot = s + partial[c + 128];
        float cnt = (float)(r1 - r0);
        out[g * 128 + c] = tot / fmaxf(cnt, 1.0f);
    }
}

// ---------------- host-side helpers ----------------

static void run_bn_stats(hipStream_t stream, const float* A, const float* gamma,
                         const float* beta, int Cout, float* sums, float* sumsq,
                         float* scale, float* shift) {
    hipLaunchKernelGGL(zero_kernel, dim3(2), dim3(256), 0, stream, sums, 512);
    hipLaunchKernelGGL(bn_stats_kernel, dim3(256), dim3(Cout), 0, stream, A, sums, sumsq,
                       N_NODES, Cout);
    hipLaunchKernelGGL(bn_finalize_kernel, dim3(1), dim3(Cout), 0, stream, sums, sumsq, gamma,
                       beta, scale, shift, N_NODES, Cout);
}

extern "C" void kernel_launch(void* const* d_in, const int* in_sizes, int n_in,
                              void* d_out, int out_size, void* d_ws, size_t ws_size,
                              hipStream_t stream) {
    const float* x     = (const float*)d_in[0];
    const int*   ei    = (const int*)d_in[1];
    const int*   batch = (const int*)d_in[2];
    const float* W1 = (const float*)d_in[3];
    const float* b1 = (const float*)d_in[4];
    const float* W2 = (const float*)d_in[5];
    const float* b2 = (const float*)d_in[6];
    const float* W3 = (const float*)d_in[7];
    const float* b3 = (const float*)d_in[8];
    const float* g1 = (const float*)d_in[9];
    const float* be1 = (const float*)d_in[10];
    const float* g2 = (const float*)d_in[11];
    const float* be2 = (const float*)d_in[12];
    const float* g3 = (const float*)d_in[13];
    const float* be3 = (const float*)d_in[14];
    float* out = (float*)d_out;

    const int* src = ei;
    const int* dstv = ei + N_EDGES;

    size_t off = 0;
    auto allocb = [&](size_t nbytes) {
        char* p = (char*)d_ws + off;
        off += (nbytes + 255) & ~(size_t)255;
        return p;
    };
    int*   deg_int   = (int*)allocb(N_NODES * 4);
    int*   row_start = (int*)allocb((N_NODES + 1) * 4);
    int*   cursor    = (int*)allocb(N_NODES * 4);
    int*   csr_src   = (int*)allocb(N_EDGES * 4);
    int*   gstart    = (int*)allocb((NUM_GRAPHS + 1) * 4);
    int*   spartial  = (int*)allocb(SCAN_BLOCKS * 4);
    int*   sboff     = (int*)allocb(SCAN_BLOCKS * 4);
    float* dinv      = (float*)allocb(N_NODES * 4);
    float* sums      = (float*)allocb(512 * 4);
    float* sumsq     = sums + 256;
    float* scale     = (float*)allocb(256 * 4);
    float* shift     = (float*)allocb(256 * 4);
    short* W1f       = (short*)allocb((size_t)128 * 256 * 4);
    short* W2f       = (short*)allocb((size_t)256 * 256 * 4);
    short* W3f       = (short*)allocb((size_t)256 * 128 * 4);
    unsigned short* Hbf = (unsigned short*)allocb((size_t)N_NODES * 256 * 2);  // bf16 buffer
    float* bufA      = (float*)allocb((size_t)N_NODES * 256 * 4);
    float* bufB      = (float*)allocb((size_t)N_NODES * 256 * 4);
    unsigned short* xbf = Hbf;  // x-bf16 aliases Hbf (dead until layer-2 GEMM)
    (void)ws_size; (void)n_in; (void)in_sizes; (void)out_size;

    int nb = (N_NODES + 255) / 256;

    // ---- degree, dinv, CSR (by dst), graph bounds, W packing, x->bf16 ----
    hipLaunchKernelGGL(zero_int_kernel, dim3(nb), dim3(256), 0, stream, deg_int, N_NODES);
    hipLaunchKernelGGL(count_deg_kernel, dim3(2048), dim3(256), 0, stream, dstv, deg_int, N_EDGES);
    hipLaunchKernelGGL(dinv_kernel, dim3(nb), dim3(256), 0, stream, deg_int, dinv, N_NODES);
    hipLaunchKernelGGL(scan_p1_kernel, dim3(SCAN_BLOCKS), dim3(256), 0, stream, deg_int,
                       spartial, N_NODES);
    hipLaunchKernelGGL(scan_p2_kernel, dim3(1), dim3(256), 0, stream, spartial, sboff,
                       row_start, SCAN_BLOCKS, N_NODES, N_EDGES);
    hipLaunchKernelGGL(scan_p3_kernel, dim3(SCAN_BLOCKS), dim3(256), 0, stream, deg_int, sboff,
                       row_start, cursor, N_NODES);
    hipLaunchKernelGGL(fill_csr_kernel, dim3(2048), dim3(256), 0, stream, src, dstv, cursor,
                       csr_src, N_EDGES);
    hipLaunchKernelGGL(graph_bounds_kernel, dim3(1), dim3(NUM_GRAPHS + 1), 0, stream, batch,
                       gstart, N_NODES, NUM_GRAPHS);
    hipLaunchKernelGGL(wpack_kernel, dim3(16), dim3(256), 0, stream, W1, W1f, 128, 256);
    hipLaunchKernelGGL(wpack_kernel, dim3(32), dim3(256), 0, stream, W2, W2f, 256, 256);
    hipLaunchKernelGGL(wpack_kernel, dim3(16), dim3(256), 0, stream, W3, W3f, 256, 128);
    int n4 = N_NODES * 128 / 4;
    hipLaunchKernelGGL(f2bf4_kernel, dim3((n4 + 255) / 256), dim3(256), 0, stream, x, xbf, n4);

    int gx = (N_NODES + 127) / 128;  // 391

    // ---- layer 1: gather(xbf) -> bufA; pack -> bufB; gemm(+b1) -> bufA (f32); stats ----
    hipLaunchKernelGGL((gather_agg_bf16_kernel<128>), dim3(N_NODES), dim3(64), 0, stream, xbf,
                       dinv, (const float*)nullptr, row_start, csr_src, bufA, N_NODES);
    hipLaunchKernelGGL(apack_kernel, dim3(NT_ROWS * 4 / 4), dim3(256), 0, stream, bufA,
                       (const float*)nullptr, (const float*)nullptr, (short*)bufB, 128);
    hipLaunchKernelGGL((gemm_mfma_kernel<4, false>), dim3(gx, 2), dim3(256), 0, stream,
                       (short*)bufB, W1f, b1, bufA, N_NODES, 256);
    run_bn_stats(stream, bufA, g1, be1, 256, sums, sumsq, scale, shift);

    // ---- layer 2: pack(BN1+relu) -> bufB; gemm -> Hbf (bf16); gather(+b2) -> bufA; stats ----
    hipLaunchKernelGGL(apack_kernel, dim3(NT_ROWS * 8 / 4), dim3(256), 0, stream, bufA, scale,
                       shift, (short*)bufB, 256);
    hipLaunchKernelGGL((gemm_mfma_kernel<8, true>), dim3(gx, 2), dim3(256), 0, stream,
                       (short*)bufB, W2f, (const float*)nullptr, Hbf, N_NODES, 256);
    hipLaunchKernelGGL((gather_agg_bf16_kernel<256>), dim3(N_NODES), dim3(64), 0, stream, Hbf,
                       dinv, b2, row_start, csr_src, bufA, N_NODES);
    run_bn_stats(stream, bufA, g2, be2, 256, sums, sumsq, scale, shift);

    // ---- layer 3: pack(BN2+relu) -> bufB; gemm -> Hbf (bf16); gather(+b3) -> bufA; stats ----
    hipLaunchKernelGGL(apack_kernel, dim3(NT_ROWS * 8 / 4), dim3(256), 0, stream, bufA, scale,
                       shift, (short*)bufB, 256);
    hipLaunchKernelGGL((gemm_mfma_kernel<8, true>), dim3(gx, 1), dim3(256), 0, stream,
                       (short*)bufB, W3f, (const float*)nullptr, Hbf, N_NODES, 128);
    hipLaunchKernelGGL((gather_agg_bf16_kernel<128>), dim3(N_NODES), dim3(64), 0, stream, Hbf,
                       dinv, b3, row_start, csr_src, bufA, N_NODES);
    run_bn_stats(stream, bufA, g3, be3, 128, sums, sumsq, scale, shift);

    // ---- pool: segmented mean with BN3 apply+relu fused ----
    hipLaunchKernelGGL(pool_seg_kernel, dim3(NUM_GRAPHS), dim3(256), 0, stream, bufA, scale,
                       shift, gstart, out);
}

// Round 7
// 674.877 us; speedup vs baseline: 3.9401x; 1.0850x over previous
//
#include <hip/hip_runtime.h>

#define N_NODES 50000
#define N_EDGES 800000
#define NUM_GRAPHS 128
#define EPS 1e-5f
#define SCAN_BLOCKS 196          // ceil(50000/256)

typedef __attribute__((ext_vector_type(8))) short short8;
typedef __attribute__((ext_vector_type(4))) float floatx4;
typedef __attribute__((ext_vector_type(4))) unsigned short ushort4v;

__device__ __forceinline__ unsigned short f2bf_rne(float f) {
    unsigned int u = __float_as_uint(f);
    u += 0x7FFF + ((u >> 16) & 1);
    return (unsigned short)(u >> 16);
}
__device__ __forceinline__ float bf2f(unsigned short h) {
    return __uint_as_float(((unsigned int)h) << 16);
}
__device__ __forceinline__ float bflo(unsigned int u) { return __uint_as_float(u << 16); }
__device__ __forceinline__ float bfhi(unsigned int u) {
    return __uint_as_float(u & 0xFFFF0000u);
}

// ---------------- degree / CSR build ----------------

__global__ void zero_int_kernel(int* p, int n) {
    int i = blockIdx.x * blockDim.x + threadIdx.x;
    if (i < n) p[i] = 0;
}

__global__ void count_deg_kernel(const int* __restrict__ dst, int* deg, int E) {
    int i = blockIdx.x * blockDim.x + threadIdx.x;
    int stride = gridDim.x * blockDim.x;
    for (; i < E; i += stride) atomicAdd(&deg[dst[i]], 1);
}

__global__ void dinv_kernel(const int* __restrict__ deg, float* dinv, int n) {
    int i = blockIdx.x * blockDim.x + threadIdx.x;
    if (i < n) dinv[i] = rsqrtf((float)(deg[i] + 1));
}

__global__ __launch_bounds__(256) void scan_p1_kernel(const int* __restrict__ deg,
                                                      int* __restrict__ partial, int n) {
    __shared__ int red[256];
    int tid = threadIdx.x;
    int i = blockIdx.x * 256 + tid;
    red[tid] = (i < n) ? deg[i] : 0;
    __syncthreads();
#pragma unroll
    for (int s = 128; s > 0; s >>= 1) {
        if (tid < s) red[tid] += red[tid + s];
        __syncthreads();
    }
    if (tid == 0) partial[blockIdx.x] = red[0];
}

__global__ __launch_bounds__(256) void scan_p2_kernel(const int* __restrict__ partial,
                                                      int* __restrict__ block_off,
                                                      int* __restrict__ row_start,
                                                      int nb, int n, int E) {
    __shared__ int s[256];
    int tid = threadIdx.x;
    int v = (tid < nb) ? partial[tid] : 0;
    s[tid] = v;
    __syncthreads();
#pragma unroll
    for (int off = 1; off < 256; off <<= 1) {
        int t = (tid >= off) ? s[tid - off] : 0;
        __syncthreads();
        s[tid] += t;
        __syncthreads();
    }
    if (tid < nb) block_off[tid] = s[tid] - v;
    if (tid == 0) row_start[n] = E;
}

__global__ __launch_bounds__(256) void scan_p3_kernel(const int* __restrict__ deg,
                                                      const int* __restrict__ block_off,
                                                      int* __restrict__ row_start,
                                                      int* __restrict__ cursor, int n) {
    __shared__ int s[256];
    int tid = threadIdx.x;
    int i = blockIdx.x * 256 + tid;
    int v = (i < n) ? deg[i] : 0;
    s[tid] = v;
    __syncthreads();
#pragma unroll
    for (int off = 1; off < 256; off <<= 1) {
        int t = (tid >= off) ? s[tid - off] : 0;
        __syncthreads();
        s[tid] += t;
        __syncthreads();
    }
    if (i < n) {
        int r = block_off[blockIdx.x] + s[tid] - v;
        row_start[i] = r;
        cursor[i] = r;
    }
}

__global__ void fill_csr_kernel(const int* __restrict__ src, const int* __restrict__ dst,
                                int* __restrict__ cursor, int* __restrict__ csr_src, int E) {
    int i = blockIdx.x * blockDim.x + threadIdx.x;
    int stride = gridDim.x * blockDim.x;
    for (; i < E; i += stride) {
        int p = atomicAdd(&cursor[dst[i]], 1);
        csr_src[p] = src[i];
    }
}

// ---------------- f32 -> bf16 bulk convert ----------------

__global__ void f2bf4_kernel(const float* __restrict__ in, unsigned short* __restrict__ out,
                             int n4) {
    int i = blockIdx.x * blockDim.x + threadIdx.x;
    if (i >= n4) return;
    float4 v = ((const float4*)in)[i];
    ushort4v o = {f2bf_rne(v.x), f2bf_rne(v.y), f2bf_rne(v.z), f2bf_rne(v.w)};
    ((ushort4v*)out)[i] = o;
}

// ---------------- BN apply + relu, f32 -> bf16 row-major ----------------
// C must satisfy (C/4) power-of-two mask arithmetic; used with C=256 -> c4mask=63.

__global__ void bnapply_kernel(const float* __restrict__ A, const float* __restrict__ scale,
                               const float* __restrict__ shift, unsigned int* __restrict__ out,
                               int total4, int c4mask) {
    int i = blockIdx.x * blockDim.x + threadIdx.x;
    if (i >= total4) return;
    int cg = i & c4mask;
    float4 v = ((const float4*)A)[i];
    float4 sc = ((const float4*)scale)[cg];
    float4 sh = ((const float4*)shift)[cg];
    float r0 = fmaxf(v.x * sc.x + sh.x, 0.0f);
    float r1 = fmaxf(v.y * sc.y + sh.y, 0.0f);
    float r2 = fmaxf(v.z * sc.z + sh.z, 0.0f);
    float r3 = fmaxf(v.w * sc.w + sh.w, 0.0f);
    uint2 o;
    o.x = (unsigned int)f2bf_rne(r0) | ((unsigned int)f2bf_rne(r1) << 16);
    o.y = (unsigned int)f2bf_rne(r2) | ((unsigned int)f2bf_rne(r3) << 16);
    ((uint2*)out)[i] = o;
}

// ---------------- W packing (f32 -> bf16 hi/lo, MFMA fragment order) -------

__global__ void wpack_kernel(const float* __restrict__ W, short* __restrict__ Wf,
                             int K, int M) {
    int t = blockIdx.x * blockDim.x + threadIdx.x;
    int KT = K >> 5, MT = M >> 4;
    if (t >= KT * MT * 64) return;
    int lane = t & 63, chunk = t >> 6;
    int kt = chunk / MT, nt = chunk % MT;
    int q = lane >> 4, m = lane & 15;
    int n = nt * 16 + m;
    short* op = Wf + (size_t)t * 16;
#pragma unroll
    for (int j = 0; j < 8; ++j) {
        float w = W[(size_t)(kt * 32 + q * 8 + j) * M + n];
        unsigned short hi = f2bf_rne(w);
        unsigned short lo = f2bf_rne(w - bf2f(hi));
        op[j] = (short)hi;
        op[8 + j] = (short)lo;
    }
}

// ---------------- MFMA GEMM: H[N,M] = A[N,K] @ W[K,M] (+ optional bias) ----------
// A is plain row-major bf16; W is hi/lo fragment-packed (2 MFMAs per k-step pair).
// block = 4 waves in 2x2, block tile 128x128, wave tile 64x64, no LDS.

template <int KT, bool BF16OUT>
__global__ __launch_bounds__(256) void gemm_mfma_kernel(
        const unsigned short* __restrict__ Abf, const short* __restrict__ Wf,
        const float* __restrict__ bias, void* __restrict__ Hout, int N, int M) {
    const int MT = M >> 4;
    const int K = KT * 32;
    int wave = threadIdx.x >> 6, lane = threadIdx.x & 63;
    int wr = wave >> 1, wc = wave & 1;
    int bm = blockIdx.x * 128 + wr * 64;
    int bn = blockIdx.y * 128 + wc * 64;
    int q = lane >> 4, l16 = lane & 15;
    int ntbase = bn >> 4;
    floatx4 acc[4][4] = {};
    for (int kt = 0; kt < KT; ++kt) {
        short8 a[4];
#pragma unroll
        for (int mt = 0; mt < 4; ++mt) {
            int row = bm + mt * 16 + l16;
            if (row > N_NODES - 1) row = N_NODES - 1;  // clamp; stores guarded
            a[mt] = *(const short8*)(Abf + (size_t)row * K + kt * 32 + q * 8);
        }
#pragma unroll
        for (int nt = 0; nt < 4; ++nt) {
            const short* wp = Wf + (((size_t)kt * MT + ntbase + nt) * 64 + lane) * 16;
            short8 bhi = *(const short8*)wp;
            short8 blo = *(const short8*)(wp + 8);
#pragma unroll
            for (int mt = 0; mt < 4; ++mt) {
                acc[mt][nt] = __builtin_amdgcn_mfma_f32_16x16x32_bf16(a[mt], bhi,
                                                                      acc[mt][nt], 0, 0, 0);
                acc[mt][nt] = __builtin_amdgcn_mfma_f32_16x16x32_bf16(a[mt], blo,
                                                                      acc[mt][nt], 0, 0, 0);
            }
        }
    }
#pragma unroll
    for (int nt = 0; nt < 4; ++nt) {
        int col = bn + nt * 16 + l16;
        float bv = bias ? bias[col] : 0.0f;
#pragma unroll
        for (int mt = 0; mt < 4; ++mt) {
#pragma unroll
            for (int r = 0; r < 4; ++r) {
                int row = bm + mt * 16 + q * 4 + r;
                if (row < N) {
                    float v = acc[mt][nt][r] + bv;
                    if constexpr (BF16OUT)
                        ((unsigned short*)Hout)[(size_t)row * M + col] = f2bf_rne(v);
                    else
                        ((float*)Hout)[(size_t)row * M + col] = v;
                }
            }
        }
    }
}

// ---------------- gather aggregation (CSR by dst, bf16 in, f32 or bf16 out) ------
// 4x-unrolled edge loop for memory-level parallelism.

template <int C, bool BF16OUT>
__global__ __launch_bounds__(64) void gather_agg_kernel(
        const unsigned short* __restrict__ Hb, const float* __restrict__ dinv,
        const float* __restrict__ bias, const int* __restrict__ row_start,
        const int* __restrict__ csr_src, void* __restrict__ AGG, int n) {
    constexpr int V = C / 64;  // channels per lane (2 or 4)
    constexpr int U = V / 2;   // packed uints per lane
    int i = blockIdx.x;
    if (i >= n) return;
    int lane = threadIdx.x;
    float di = dinv[i];
    float w0 = di * di;
    const unsigned int* base = (const unsigned int*)Hb;
    float acc[V];
    {
        const unsigned int* hrow = base + ((size_t)i * C >> 1) + lane * U;
#pragma unroll
        for (int t = 0; t < U; ++t) {
            unsigned int u = hrow[t];
            acc[2 * t] = (bias ? bias[lane * V + 2 * t] : 0.0f) + bflo(u) * w0;
            acc[2 * t + 1] = (bias ? bias[lane * V + 2 * t + 1] : 0.0f) + bfhi(u) * w0;
        }
    }
    int e0 = row_start[i], e1 = row_start[i + 1];
    int e = e0;
    for (; e + 4 <= e1; e += 4) {
        int s0 = csr_src[e + 0], s1 = csr_src[e + 1];
        int s2 = csr_src[e + 2], s3 = csr_src[e + 3];
        float wa = dinv[s0] * di, wb = dinv[s1] * di;
        float wc = dinv[s2] * di, wd = dinv[s3] * di;
        unsigned int ua[U], ub[U], uc[U], ud[U];
        const unsigned int* pa = base + ((size_t)s0 * C >> 1) + lane * U;
        const unsigned int* pb = base + ((size_t)s1 * C >> 1) + lane * U;
        const unsigned int* pc = base + ((size_t)s2 * C >> 1) + lane * U;
        const unsigned int* pd = base + ((size_t)s3 * C >> 1) + lane * U;
#pragma unroll
        for (int t = 0; t < U; ++t) ua[t] = pa[t];
#pragma unroll
        for (int t = 0; t < U; ++t) ub[t] = pb[t];
#pragma unroll
        for (int t = 0; t < U; ++t) uc[t] = pc[t];
#pragma unroll
        for (int t = 0; t < U; ++t) ud[t] = pd[t];
#pragma unroll
        for (int t = 0; t < U; ++t) {
            acc[2 * t] += bflo(ua[t]) * wa + bflo(ub[t]) * wb + bflo(uc[t]) * wc +
                          bflo(ud[t]) * wd;
            acc[2 * t + 1] += bfhi(ua[t]) * wa + bfhi(ub[t]) * wb + bfhi(uc[t]) * wc +
                              bfhi(ud[t]) * wd;
        }
    }
    for (; e < e1; ++e) {
        int s = csr_src[e];
        float w = dinv[s] * di;
        const unsigned int* srow = base + ((size_t)s * C >> 1) + lane * U;
#pragma unroll
        for (int t = 0; t < U; ++t) {
            unsigned int u = srow[t];
            acc[2 * t] += bflo(u) * w;
            acc[2 * t + 1] += bfhi(u) * w;
        }
    }
    if constexpr (BF16OUT) {
        unsigned int* orow = (unsigned int*)AGG + ((size_t)i * C >> 1) + lane * U;
#pragma unroll
        for (int t = 0; t < U; ++t)
            orow[t] = (unsigned int)f2bf_rne(acc[2 * t]) |
                      ((unsigned int)f2bf_rne(acc[2 * t + 1]) << 16);
    } else {
        float* orow = (float*)AGG + (size_t)i * C + lane * V;
        if constexpr (V == 4)
            *(float4*)orow = make_float4(acc[0], acc[1], acc[2], acc[3]);
        else
            *(float2*)orow = make_float2(acc[0], acc[1]);
    }
}

// ---------------- batch norm stats ----------------

__global__ void zero_kernel(float* p, int n) {
    int i = blockIdx.x * blockDim.x + threadIdx.x;
    if (i < n) p[i] = 0.0f;
}

__global__ void bn_stats_kernel(const float* __restrict__ A, float* __restrict__ sums,
                                float* __restrict__ sumsq, int n, int C) {
    int c = threadIdx.x;
    int rpb = (n + gridDim.x - 1) / gridDim.x;
    int r0 = blockIdx.x * rpb;
    int r1 = min(n, r0 + rpb);
    float s = 0.0f, s2 = 0.0f;
    for (int r = r0; r < r1; ++r) {
        float v = A[(size_t)r * C + c];
        s += v;
        s2 += v * v;
    }
    atomicAdd(&sums[c], s);
    atomicAdd(&sumsq[c], s2);
}

__global__ void bn_finalize_kernel(const float* __restrict__ sums, const float* __restrict__ sumsq,
                                   const float* __restrict__ gamma, const float* __restrict__ beta,
                                   float* __restrict__ scale, float* __restrict__ shift,
                                   int n, int C) {
    int c = threadIdx.x;
    if (c >= C) return;
    float inv_n = 1.0f / (float)n;
    float mu = sums[c] * inv_n;
    float var = sumsq[c] * inv_n - mu * mu;
    float rs = rsqrtf(var + EPS);
    float sc = gamma[c] * rs;
    scale[c] = sc;
    shift[c] = beta[c] - mu * sc;
}

// ---------------- pooling (sorted-segment, no atomics) ----------------

__global__ void graph_bounds_kernel(const int* __restrict__ batch, int* __restrict__ gstart,
                                    int n, int G) {
    int g = blockIdx.x * blockDim.x + threadIdx.x;
    if (g > G) return;
    int lo = 0, hi = n;
    while (lo < hi) {
        int mid = (lo + hi) >> 1;
        if (batch[mid] < g) lo = mid + 1; else hi = mid;
    }
    gstart[g] = lo;
}

__global__ __launch_bounds__(256) void pool_seg_kernel(
        const float* __restrict__ A, const float* __restrict__ scale,
        const float* __restrict__ shift, const int* __restrict__ gstart,
        float* __restrict__ out) {
    __shared__ float partial[256];
    int g = blockIdx.x;
    int tid = threadIdx.x;
    int c = tid & 127;
    int part = tid >> 7;
    int r0 = gstart[g], r1 = gstart[g + 1];
    float sc = scale[c], sh = shift[c];
    float s = 0.0f;
    for (int r = r0 + part; r < r1; r += 2) {
        float v = A[(size_t)r * 128 + c];
        s += fmaxf(v * sc + sh, 0.0f);
    }
    partial[tid] = s;
    __syncthreads();
    if (part == 0) {
        float tot = s + partial[c + 128];
        float cnt = (float)(r1 - r0);
        out[g * 128 + c] = tot / fmaxf(cnt, 1.0f);
    }
}

// ---------------- host-side helpers ----------------

static void run_bn_stats(hipStream_t stream, const float* A, const float* gamma,
                         const float* beta, int Cout, float* sums, float* sumsq,
                         float* scale, float* shift) {
    hipLaunchKernelGGL(zero_kernel, dim3(2), dim3(256), 0, stream, sums, 512);
    hipLaunchKernelGGL(bn_stats_kernel, dim3(256), dim3(Cout), 0, stream, A, sums, sumsq,
                       N_NODES, Cout);
    hipLaunchKernelGGL(bn_finalize_kernel, dim3(1), dim3(Cout), 0, stream, sums, sumsq, gamma,
                       beta, scale, shift, N_NODES, Cout);
}

extern "C" void kernel_launch(void* const* d_in, const int* in_sizes, int n_in,
                              void* d_out, int out_size, void* d_ws, size_t ws_size,
                              hipStream_t stream) {
    const float* x     = (const float*)d_in[0];
    const int*   ei    = (const int*)d_in[1];
    const int*   batch = (const int*)d_in[2];
    const float* W1 = (const float*)d_in[3];
    const float* b1 = (const float*)d_in[4];
    const float* W2 = (const float*)d_in[5];
    const float* b2 = (const float*)d_in[6];
    const float* W3 = (const float*)d_in[7];
    const float* b3 = (const float*)d_in[8];
    const float* g1 = (const float*)d_in[9];
    const float* be1 = (const float*)d_in[10];
    const float* g2 = (const float*)d_in[11];
    const float* be2 = (const float*)d_in[12];
    const float* g3 = (const float*)d_in[13];
    const float* be3 = (const float*)d_in[14];
    float* out = (float*)d_out;

    const int* src = ei;
    const int* dstv = ei + N_EDGES;

    size_t off = 0;
    auto allocb = [&](size_t nbytes) {
        char* p = (char*)d_ws + off;
        off += (nbytes + 255) & ~(size_t)255;
        return p;
    };
    int*   deg_int   = (int*)allocb(N_NODES * 4);
    int*   row_start = (int*)allocb((N_NODES + 1) * 4);
    int*   cursor    = (int*)allocb(N_NODES * 4);
    int*   csr_src   = (int*)allocb(N_EDGES * 4);
    int*   gstart    = (int*)allocb((NUM_GRAPHS + 1) * 4);
    int*   spartial  = (int*)allocb(SCAN_BLOCKS * 4);
    int*   sboff     = (int*)allocb(SCAN_BLOCKS * 4);
    float* dinv      = (float*)allocb(N_NODES * 4);
    float* sums      = (float*)allocb(512 * 4);
    float* sumsq     = sums + 256;
    float* scale     = (float*)allocb(256 * 4);
    float* shift     = (float*)allocb(256 * 4);
    short* W1f       = (short*)allocb((size_t)128 * 256 * 4);
    short* W2f       = (short*)allocb((size_t)256 * 256 * 4);
    short* W3f       = (short*)allocb((size_t)256 * 128 * 4);
    unsigned short* Hbf = (unsigned short*)allocb((size_t)N_NODES * 256 * 2);  // bf16 H
    float* bufA      = (float*)allocb((size_t)N_NODES * 256 * 4);  // f32 AGG / GEMM out
    float* bufB      = (float*)allocb((size_t)N_NODES * 256 * 4);  // bf16 A staging
    unsigned short* xbf = Hbf;            // x-bf16 aliases Hbf (dead until layer-2 GEMM)
    unsigned short* Abf = (unsigned short*)bufB;  // row-major bf16 activations
    (void)ws_size; (void)n_in; (void)in_sizes; (void)out_size;

    int nb = (N_NODES + 255) / 256;

    // ---- degree, dinv, CSR (by dst), graph bounds, W packing, x->bf16 ----
    hipLaunchKernelGGL(zero_int_kernel, dim3(nb), dim3(256), 0, stream, deg_int, N_NODES);
    hipLaunchKernelGGL(count_deg_kernel, dim3(2048), dim3(256), 0, stream, dstv, deg_int, N_EDGES);
    hipLaunchKernelGGL(dinv_kernel, dim3(nb), dim3(256), 0, stream, deg_int, dinv, N_NODES);
    hipLaunchKernelGGL(scan_p1_kernel, dim3(SCAN_BLOCKS), dim3(256), 0, stream, deg_int,
                       spartial, N_NODES);
    hipLaunchKernelGGL(scan_p2_kernel, dim3(1), dim3(256), 0, stream, spartial, sboff,
                       row_start, SCAN_BLOCKS, N_NODES, N_EDGES);
    hipLaunchKernelGGL(scan_p3_kernel, dim3(SCAN_BLOCKS), dim3(256), 0, stream, deg_int, sboff,
                       row_start, cursor, N_NODES);
    hipLaunchKernelGGL(fill_csr_kernel, dim3(2048), dim3(256), 0, stream, src, dstv, cursor,
                       csr_src, N_EDGES);
    hipLaunchKernelGGL(graph_bounds_kernel, dim3(1), dim3(NUM_GRAPHS + 1), 0, stream, batch,
                       gstart, N_NODES, NUM_GRAPHS);
    hipLaunchKernelGGL(wpack_kernel, dim3(16), dim3(256), 0, stream, W1, W1f, 128, 256);
    hipLaunchKernelGGL(wpack_kernel, dim3(32), dim3(256), 0, stream, W2, W2f, 256, 256);
    hipLaunchKernelGGL(wpack_kernel, dim3(16), dim3(256), 0, stream, W3, W3f, 256, 128);
    int n4 = N_NODES * 128 / 4;
    hipLaunchKernelGGL(f2bf4_kernel, dim3((n4 + 255) / 256), dim3(256), 0, stream, x, xbf, n4);

    int gx = (N_NODES + 127) / 128;  // 391
    int t4_256 = N_NODES * 256 / 4;

    // ---- layer 1: gather(xbf) -> Abf (bf16); gemm(+b1) -> bufA (f32); stats ----
    hipLaunchKernelGGL((gather_agg_kernel<128, true>), dim3(N_NODES), dim3(64), 0, stream, xbf,
                       dinv, (const float*)nullptr, row_start, csr_src, Abf, N_NODES);
    hipLaunchKernelGGL((gemm_mfma_kernel<4, false>), dim3(gx, 2), dim3(256), 0, stream, Abf,
                       W1f, b1, bufA, N_NODES, 256);
    run_bn_stats(stream, bufA, g1, be1, 256, sums, sumsq, scale, shift);

    // ---- layer 2: apply BN1+relu -> Abf; gemm -> Hbf; gather(+b2) -> bufA; stats ----
    hipLaunchKernelGGL(bnapply_kernel, dim3((t4_256 + 255) / 256), dim3(256), 0, stream, bufA,
                       scale, shift, (unsigned int*)Abf, t4_256, 63);
    hipLaunchKernelGGL((gemm_mfma_kernel<8, true>), dim3(gx, 2), dim3(256), 0, stream, Abf,
                       W2f, (const float*)nullptr, Hbf, N_NODES, 256);
    hipLaunchKernelGGL((gather_agg_kernel<256, false>), dim3(N_NODES), dim3(64), 0, stream, Hbf,
                       dinv, b2, row_start, csr_src, bufA, N_NODES);
    run_bn_stats(stream, bufA, g2, be2, 256, sums, sumsq, scale, shift);

    // ---- layer 3: apply BN2+relu -> Abf; gemm -> Hbf; gather(+b3) -> bufA; stats ----
    hipLaunchKernelGGL(bnapply_kernel, dim3((t4_256 + 255) / 256), dim3(256), 0, stream, bufA,
                       scale, shift, (unsigned int*)Abf, t4_256, 63);
    hipLaunchKernelGGL((gemm_mfma_kernel<8, true>), dim3(gx, 1), dim3(256), 0, stream, Abf,
                       W3f, (const float*)nullptr, Hbf, N_NODES, 128);
    hipLaunchKernelGGL((gather_agg_kernel<128, false>), dim3(N_NODES), dim3(64), 0, stream, Hbf,
                       dinv, b3, row_start, csr_src, bufA, N_NODES);
    run_bn_stats(stream, bufA, g3, be3, 128, sums, sumsq, scale, shift);

    // ---- pool: segmented mean with BN3 apply+relu fused ----
    hipLaunchKernelGGL(pool_seg_kernel, dim3(NUM_GRAPHS), dim3(256), 0, stream, bufA, scale,
                       shift, gstart, out);
}

// Round 8
// 653.649 us; speedup vs baseline: 4.0680x; 1.0325x over previous
//
#include <hip/hip_runtime.h>

#define N_NODES 50000
#define N_EDGES 800000
#define NUM_GRAPHS 128
#define EPS 1e-5f
#define SCAN_BLOCKS 196          // ceil(50000/256)
#define NPAD 50048               // 391 * 128 (row-tile padded node count)

typedef __attribute__((ext_vector_type(8))) short short8;
typedef __attribute__((ext_vector_type(4))) float floatx4;
typedef __attribute__((ext_vector_type(4))) unsigned short ushort4v;

__device__ __forceinline__ unsigned short f2bf_rne(float f) {
    unsigned int u = __float_as_uint(f);
    u += 0x7FFF + ((u >> 16) & 1);
    return (unsigned short)(u >> 16);
}
__device__ __forceinline__ float bf2f(unsigned short h) {
    return __uint_as_float(((unsigned int)h) << 16);
}
__device__ __forceinline__ float bflo(unsigned int u) { return __uint_as_float(u << 16); }
__device__ __forceinline__ float bfhi(unsigned int u) {
    return __uint_as_float(u & 0xFFFF0000u);
}

// async global->LDS, 16B per lane (CK-style addrspace casts)
__device__ __forceinline__ void gload16(const void* g, void* l) {
#if __has_builtin(__builtin_amdgcn_global_load_lds)
    __builtin_amdgcn_global_load_lds(
        reinterpret_cast<const __attribute__((address_space(1))) unsigned int*>(
            reinterpret_cast<unsigned long long>(g)),
        reinterpret_cast<__attribute__((address_space(3))) unsigned int*>(
            reinterpret_cast<unsigned long long>(l)),
        16, 0, 0);
#else
    *(uint4*)l = *(const uint4*)g;
#endif
}

// ---------------- degree / CSR build ----------------

__global__ void zero_int_kernel(int* p, int n) {
    int i = blockIdx.x * blockDim.x + threadIdx.x;
    if (i < n) p[i] = 0;
}

__global__ void count_deg_kernel(const int* __restrict__ dst, int* deg, int E) {
    int i = blockIdx.x * blockDim.x + threadIdx.x;
    int stride = gridDim.x * blockDim.x;
    for (; i < E; i += stride) atomicAdd(&deg[dst[i]], 1);
}

__global__ void dinv_kernel(const int* __restrict__ deg, float* dinv, int n) {
    int i = blockIdx.x * blockDim.x + threadIdx.x;
    if (i < n) dinv[i] = rsqrtf((float)(deg[i] + 1));
}

__global__ __launch_bounds__(256) void scan_p1_kernel(const int* __restrict__ deg,
                                                      int* __restrict__ partial, int n) {
    __shared__ int red[256];
    int tid = threadIdx.x;
    int i = blockIdx.x * 256 + tid;
    red[tid] = (i < n) ? deg[i] : 0;
    __syncthreads();
#pragma unroll
    for (int s = 128; s > 0; s >>= 1) {
        if (tid < s) red[tid] += red[tid + s];
        __syncthreads();
    }
    if (tid == 0) partial[blockIdx.x] = red[0];
}

__global__ __launch_bounds__(256) void scan_p2_kernel(const int* __restrict__ partial,
                                                      int* __restrict__ block_off,
                                                      int* __restrict__ row_start,
                                                      int nb, int n, int E) {
    __shared__ int s[256];
    int tid = threadIdx.x;
    int v = (tid < nb) ? partial[tid] : 0;
    s[tid] = v;
    __syncthreads();
#pragma unroll
    for (int off = 1; off < 256; off <<= 1) {
        int t = (tid >= off) ? s[tid - off] : 0;
        __syncthreads();
        s[tid] += t;
        __syncthreads();
    }
    if (tid < nb) block_off[tid] = s[tid] - v;
    if (tid == 0) row_start[n] = E;
}

__global__ __launch_bounds__(256) void scan_p3_kernel(const int* __restrict__ deg,
                                                      const int* __restrict__ block_off,
                                                      int* __restrict__ row_start,
                                                      int* __restrict__ cursor, int n) {
    __shared__ int s[256];
    int tid = threadIdx.x;
    int i = blockIdx.x * 256 + tid;
    int v = (i < n) ? deg[i] : 0;
    s[tid] = v;
    __syncthreads();
#pragma unroll
    for (int off = 1; off < 256; off <<= 1) {
        int t = (tid >= off) ? s[tid - off] : 0;
        __syncthreads();
        s[tid] += t;
        __syncthreads();
    }
    if (i < n) {
        int r = block_off[blockIdx.x] + s[tid] - v;
        row_start[i] = r;
        cursor[i] = r;
    }
}

__global__ void fill_csr_kernel(const int* __restrict__ src, const int* __restrict__ dst,
                                int* __restrict__ cursor, int* __restrict__ csr_src, int E) {
    int i = blockIdx.x * blockDim.x + threadIdx.x;
    int stride = gridDim.x * blockDim.x;
    for (; i < E; i += stride) {
        int p = atomicAdd(&cursor[dst[i]], 1);
        csr_src[p] = src[i];
    }
}

// ---------------- f32 -> bf16 bulk convert ----------------

__global__ void f2bf4_kernel(const float* __restrict__ in, unsigned short* __restrict__ out,
                             int n4) {
    int i = blockIdx.x * blockDim.x + threadIdx.x;
    if (i >= n4) return;
    float4 v = ((const float4*)in)[i];
    ushort4v o = {f2bf_rne(v.x), f2bf_rne(v.y), f2bf_rne(v.z), f2bf_rne(v.w)};
    ((ushort4v*)out)[i] = o;
}

// ---------------- BN apply + relu, f32 row-major -> bf16 panel-major -------------
// C == 256. Panel layout: Ap[p][NPAD][32], p = channel>>5.

__global__ void bnapply_panel_kernel(const float* __restrict__ A, const float* __restrict__ scale,
                                     const float* __restrict__ shift,
                                     unsigned short* __restrict__ Ap, int n) {
    int i = blockIdx.x * blockDim.x + threadIdx.x;  // over n*64 groups of 4 cols
    if (i >= n * 64) return;
    int row = i >> 6, cg = i & 63;
    int c0 = cg * 4;
    float4 v = ((const float4*)A)[i];
    float4 sc = ((const float4*)scale)[cg];
    float4 sh = ((const float4*)shift)[cg];
    float r0 = fmaxf(v.x * sc.x + sh.x, 0.0f);
    float r1 = fmaxf(v.y * sc.y + sh.y, 0.0f);
    float r2 = fmaxf(v.z * sc.z + sh.z, 0.0f);
    float r3 = fmaxf(v.w * sc.w + sh.w, 0.0f);
    uint2 o;
    o.x = (unsigned int)f2bf_rne(r0) | ((unsigned int)f2bf_rne(r1) << 16);
    o.y = (unsigned int)f2bf_rne(r2) | ((unsigned int)f2bf_rne(r3) << 16);
    int p = c0 >> 5, wc = c0 & 31;
    *(uint2*)(Ap + ((size_t)p * NPAD + row) * 32 + wc) = o;
}

// ---------------- W packing: f32 -> bf16 hi/lo, staging-friendly fragment order ---
// Wf[kt][nt][h(0=hi,1=lo)][lane][8]  (shorts). Per (kt, 8-nt window): 16 KB contiguous.

__global__ void wpack_kernel(const float* __restrict__ W, short* __restrict__ Wf,
                             int K, int M) {
    int t = blockIdx.x * blockDim.x + threadIdx.x;
    int KT = K >> 5, MT = M >> 4;
    if (t >= KT * MT * 64) return;
    int lane = t & 63, chunk = t >> 6;
    int kt = chunk / MT, nt = chunk % MT;
    int q = lane >> 4, m = lane & 15;
    int n = nt * 16 + m;
    short* ophi = Wf + ((size_t)(kt * MT + nt) * 2 + 0) * 512 + lane * 8;
    short* oplo = Wf + ((size_t)(kt * MT + nt) * 2 + 1) * 512 + lane * 8;
#pragma unroll
    for (int j = 0; j < 8; ++j) {
        float w = W[(size_t)(kt * 32 + q * 8 + j) * M + n];
        unsigned short hi = f2bf_rne(w);
        unsigned short lo = f2bf_rne(w - bf2f(hi));
        ophi[j] = (short)hi;
        oplo[j] = (short)lo;
    }
}

// ---------------- LDS-staged MFMA GEMM: H[N,M] = A[N,K] @ W[K,M] (+bias) ---------
// A panel-major bf16 (Ap[kt][NPAD][32]); W hi/lo packed. Block tile 128x128,
// 4 waves 2x2, wave tile 64x64. Per kt: async-stage 8KB A + 16KB W, ds_read frags.

template <int KT, bool BF16OUT>
__global__ __launch_bounds__(256) void gemm_lds_kernel(
        const unsigned short* __restrict__ Ap, const short* __restrict__ Wf,
        const float* __restrict__ bias, void* __restrict__ Hout, int N, int M) {
    const int MT = M >> 4;
    __shared__ unsigned short sA[128 * 32];   // 8 KB
    __shared__ short sW[8 * 2 * 512];         // 16 KB
    int tid = threadIdx.x;
    int wave = tid >> 6, lane = tid & 63;
    int wr = wave >> 1, wc = wave & 1;
    int bm = blockIdx.x * 128;
    int bn = blockIdx.y * 128;
    int ntbb = bn >> 4;
    int q = lane >> 4, l16 = lane & 15;
    floatx4 acc[4][4] = {};
    for (int kt = 0; kt < KT; ++kt) {
        __syncthreads();  // protect previous iteration's LDS reads
        {
            const char* ab = (const char*)(Ap + ((size_t)kt * NPAD + bm) * 32);
            const char* wb = (const char*)(Wf + (size_t)(kt * MT + ntbb) * 1024);
            char* sa = (char*)sA;
            char* sw = (char*)sW;
            gload16(ab + tid * 16, sa + tid * 16);
            gload16(ab + (256 + tid) * 16, sa + (256 + tid) * 16);
#pragma unroll
            for (int i = 0; i < 4; ++i)
                gload16(wb + (i * 256 + tid) * 16, sw + (i * 256 + tid) * 16);
        }
        __syncthreads();  // staging complete (vmcnt drained by barrier)
        short8 a[4], wh[4], wl[4];
#pragma unroll
        for (int mt = 0; mt < 4; ++mt)
            a[mt] = *(const short8*)&sA[(wr * 64 + mt * 16 + l16) * 32 + q * 8];
#pragma unroll
        for (int nt = 0; nt < 4; ++nt) {
            wh[nt] = *(const short8*)&sW[((wc * 4 + nt) * 2 + 0) * 512 + lane * 8];
            wl[nt] = *(const short8*)&sW[((wc * 4 + nt) * 2 + 1) * 512 + lane * 8];
        }
#pragma unroll
        for (int nt = 0; nt < 4; ++nt)
#pragma unroll
            for (int mt = 0; mt < 4; ++mt) {
                acc[mt][nt] = __builtin_amdgcn_mfma_f32_16x16x32_bf16(a[mt], wh[nt],
                                                                      acc[mt][nt], 0, 0, 0);
                acc[mt][nt] = __builtin_amdgcn_mfma_f32_16x16x32_bf16(a[mt], wl[nt],
                                                                      acc[mt][nt], 0, 0, 0);
            }
    }
#pragma unroll
    for (int nt = 0; nt < 4; ++nt) {
        int col = bn + wc * 64 + nt * 16 + l16;
        float bv = bias ? bias[col] : 0.0f;
#pragma unroll
        for (int mt = 0; mt < 4; ++mt) {
#pragma unroll
            for (int r = 0; r < 4; ++r) {
                int row = bm + wr * 64 + mt * 16 + q * 4 + r;
                if (row < N) {
                    float v = acc[mt][nt][r] + bv;
                    if constexpr (BF16OUT)
                        ((unsigned short*)Hout)[(size_t)row * M + col] = f2bf_rne(v);
                    else
                        ((float*)Hout)[(size_t)row * M + col] = v;
                }
            }
        }
    }
}

// ---------------- gather aggregation (CSR by dst, bf16 in) ----------------------
// OUTMODE: 0 = f32 row-major, 1 = bf16 panel-major (GEMM A operand).
// 4x-unrolled edge loop for memory-level parallelism.

template <int C, int OUTMODE>
__global__ __launch_bounds__(64) void gather_agg_kernel(
        const unsigned short* __restrict__ Hb, const float* __restrict__ dinv,
        const float* __restrict__ bias, const int* __restrict__ row_start,
        const int* __restrict__ csr_src, void* __restrict__ AGG, int n) {
    constexpr int V = C / 64;  // channels per lane (2 or 4)
    constexpr int U = V / 2;   // packed uints per lane
    int i = blockIdx.x;
    if (i >= n) return;
    int lane = threadIdx.x;
    float di = dinv[i];
    float w0 = di * di;
    const unsigned int* base = (const unsigned int*)Hb;
    float acc[V];
    {
        const unsigned int* hrow = base + ((size_t)i * C >> 1) + lane * U;
#pragma unroll
        for (int t = 0; t < U; ++t) {
            unsigned int u = hrow[t];
            acc[2 * t] = (bias ? bias[lane * V + 2 * t] : 0.0f) + bflo(u) * w0;
            acc[2 * t + 1] = (bias ? bias[lane * V + 2 * t + 1] : 0.0f) + bfhi(u) * w0;
        }
    }
    int e0 = row_start[i], e1 = row_start[i + 1];
    int e = e0;
    for (; e + 4 <= e1; e += 4) {
        int s0 = csr_src[e + 0], s1 = csr_src[e + 1];
        int s2 = csr_src[e + 2], s3 = csr_src[e + 3];
        float wa = dinv[s0] * di, wb = dinv[s1] * di;
        float wc = dinv[s2] * di, wd = dinv[s3] * di;
        unsigned int ua[U], ub[U], uc[U], ud[U];
        const unsigned int* pa = base + ((size_t)s0 * C >> 1) + lane * U;
        const unsigned int* pb = base + ((size_t)s1 * C >> 1) + lane * U;
        const unsigned int* pc = base + ((size_t)s2 * C >> 1) + lane * U;
        const unsigned int* pd = base + ((size_t)s3 * C >> 1) + lane * U;
#pragma unroll
        for (int t = 0; t < U; ++t) ua[t] = pa[t];
#pragma unroll
        for (int t = 0; t < U; ++t) ub[t] = pb[t];
#pragma unroll
        for (int t = 0; t < U; ++t) uc[t] = pc[t];
#pragma unroll
        for (int t = 0; t < U; ++t) ud[t] = pd[t];
#pragma unroll
        for (int t = 0; t < U; ++t) {
            acc[2 * t] += bflo(ua[t]) * wa + bflo(ub[t]) * wb + bflo(uc[t]) * wc +
                          bflo(ud[t]) * wd;
            acc[2 * t + 1] += bfhi(ua[t]) * wa + bfhi(ub[t]) * wb + bfhi(uc[t]) * wc +
                              bfhi(ud[t]) * wd;
        }
    }
    for (; e < e1; ++e) {
        int s = csr_src[e];
        float w = dinv[s] * di;
        const unsigned int* srow = base + ((size_t)s * C >> 1) + lane * U;
#pragma unroll
        for (int t = 0; t < U; ++t) {
            unsigned int u = srow[t];
            acc[2 * t] += bflo(u) * w;
            acc[2 * t + 1] += bfhi(u) * w;
        }
    }
    if constexpr (OUTMODE == 1) {
        // panel-major bf16: channel c -> panel c>>5, col c&31
#pragma unroll
        for (int t = 0; t < U; ++t) {
            int c = lane * V + 2 * t;
            unsigned int o = (unsigned int)f2bf_rne(acc[2 * t]) |
                             ((unsigned int)f2bf_rne(acc[2 * t + 1]) << 16);
            *(unsigned int*)((unsigned short*)AGG + ((size_t)(c >> 5) * NPAD + i) * 32 +
                             (c & 31)) = o;
        }
    } else {
        float* orow = (float*)AGG + (size_t)i * C + lane * V;
        if constexpr (V == 4)
            *(float4*)orow = make_float4(acc[0], acc[1], acc[2], acc[3]);
        else
            *(float2*)orow = make_float2(acc[0], acc[1]);
    }
}

// ---------------- batch norm stats ----------------

__global__ void zero_kernel(float* p, int n) {
    int i = blockIdx.x * blockDim.x + threadIdx.x;
    if (i < n) p[i] = 0.0f;
}

__global__ void bn_stats_kernel(const float* __restrict__ A, float* __restrict__ sums,
                                float* __restrict__ sumsq, int n, int C) {
    int c = threadIdx.x;
    int rpb = (n + gridDim.x - 1) / gridDim.x;
    int r0 = blockIdx.x * rpb;
    int r1 = min(n, r0 + rpb);
    float s = 0.0f, s2 = 0.0f;
    for (int r = r0; r < r1; ++r) {
        float v = A[(size_t)r * C + c];
        s += v;
        s2 += v * v;
    }
    atomicAdd(&sums[c], s);
    atomicAdd(&sumsq[c], s2);
}

__global__ void bn_finalize_kernel(const float* __restrict__ sums, const float* __restrict__ sumsq,
                                   const float* __restrict__ gamma, const float* __restrict__ beta,
                                   float* __restrict__ scale, float* __restrict__ shift,
                                   int n, int C) {
    int c = threadIdx.x;
    if (c >= C) return;
    float inv_n = 1.0f / (float)n;
    float mu = sums[c] * inv_n;
    float var = sumsq[c] * inv_n - mu * mu;
    float rs = rsqrtf(var + EPS);
    float sc = gamma[c] * rs;
    scale[c] = sc;
    shift[c] = beta[c] - mu * sc;
}

// ---------------- pooling (sorted-segment, no atomics) ----------------

__global__ void graph_bounds_kernel(const int* __restrict__ batch, int* __restrict__ gstart,
                                    int n, int G) {
    int g = blockIdx.x * blockDim.x + threadIdx.x;
    if (g > G) return;
    int lo = 0, hi = n;
    while (lo < hi) {
        int mid = (lo + hi) >> 1;
        if (batch[mid] < g) lo = mid + 1; else hi = mid;
    }
    gstart[g] = lo;
}

__global__ __launch_bounds__(256) void pool_seg_kernel(
        const float* __restrict__ A, const float* __restrict__ scale,
        const float* __restrict__ shift, const int* __restrict__ gstart,
        float* __restrict__ out) {
    __shared__ float partial[256];
    int g = blockIdx.x;
    int tid = threadIdx.x;
    int c = tid & 127;
    int part = tid >> 7;
    int r0 = gstart[g], r1 = gstart[g + 1];
    float sc = scale[c], sh = shift[c];
    float s = 0.0f;
    for (int r = r0 + part; r < r1; r += 2) {
        float v = A[(size_t)r * 128 + c];
        s += fmaxf(v * sc + sh, 0.0f);
    }
    partial[tid] = s;
    __syncthreads();
    if (part == 0) {
        float tot = s + partial[c + 128];
        float cnt = (float)(r1 - r0);
        out[g * 128 + c] = tot / fmaxf(cnt, 1.0f);
    }
}

// ---------------- host-side helpers ----------------

static void run_bn_stats(hipStream_t stream, const float* A, const float* gamma,
                         const float* beta, int Cout, float* sums, float* sumsq,
                         float* scale, float* shift) {
    hipLaunchKernelGGL(zero_kernel, dim3(2), dim3(256), 0, stream, sums, 512);
    hipLaunchKernelGGL(bn_stats_kernel, dim3(256), dim3(Cout), 0, stream, A, sums, sumsq,
                       N_NODES, Cout);
    hipLaunchKernelGGL(bn_finalize_kernel, dim3(1), dim3(Cout), 0, stream, sums, sumsq, gamma,
                       beta, scale, shift, N_NODES, Cout);
}

extern "C" void kernel_launch(void* const* d_in, const int* in_sizes, int n_in,
                              void* d_out, int out_size, void* d_ws, size_t ws_size,
                              hipStream_t stream) {
    const float* x     = (const float*)d_in[0];
    const int*   ei    = (const int*)d_in[1];
    const int*   batch = (const int*)d_in[2];
    const float* W1 = (const float*)d_in[3];
    const float* b1 = (const float*)d_in[4];
    const float* W2 = (const float*)d_in[5];
    const float* b2 = (const float*)d_in[6];
    const float* W3 = (const float*)d_in[7];
    const float* b3 = (const float*)d_in[8];
    const float* g1 = (const float*)d_in[9];
    const float* be1 = (const float*)d_in[10];
    const float* g2 = (const float*)d_in[11];
    const float* be2 = (const float*)d_in[12];
    const float* g3 = (const float*)d_in[13];
    const float* be3 = (const float*)d_in[14];
    float* out = (float*)d_out;

    const int* src = ei;
    const int* dstv = ei + N_EDGES;

    size_t off = 0;
    auto allocb = [&](size_t nbytes) {
        char* p = (char*)d_ws + off;
        off += (nbytes + 255) & ~(size_t)255;
        return p;
    };
    int*   deg_int   = (int*)allocb(N_NODES * 4);
    int*   row_start = (int*)allocb((N_NODES + 1) * 4);
    int*   cursor    = (int*)allocb(N_NODES * 4);
    int*   csr_src   = (int*)allocb(N_EDGES * 4);
    int*   gstart    = (int*)allocb((NUM_GRAPHS + 1) * 4);
    int*   spartial  = (int*)allocb(SCAN_BLOCKS * 4);
    int*   sboff     = (int*)allocb(SCAN_BLOCKS * 4);
    float* dinv      = (float*)allocb(N_NODES * 4);
    float* sums      = (float*)allocb(512 * 4);
    float* sumsq     = sums + 256;
    float* scale     = (float*)allocb(256 * 4);
    float* shift     = (float*)allocb(256 * 4);
    short* W1f       = (short*)allocb((size_t)128 * 256 * 4);
    short* W2f       = (short*)allocb((size_t)256 * 256 * 4);
    short* W3f       = (short*)allocb((size_t)256 * 128 * 4);
    unsigned short* Hbf = (unsigned short*)allocb((size_t)N_NODES * 256 * 2);  // bf16 H
    float* bufA      = (float*)allocb((size_t)N_NODES * 256 * 4);   // f32 AGG / GEMM out
    float* bufB      = (float*)allocb((size_t)NPAD * 256 * 4);      // panel-major bf16 A
    unsigned short* xbf = Hbf;            // x-bf16 aliases Hbf (dead until layer-2 GEMM)
    unsigned short* Ap  = (unsigned short*)bufB;  // panel-major bf16 activations
    (void)ws_size; (void)n_in; (void)in_sizes; (void)out_size;

    int nb = (N_NODES + 255) / 256;

    // ---- degree, dinv, CSR (by dst), graph bounds, W packing, x->bf16 ----
    hipLaunchKernelGGL(zero_int_kernel, dim3(nb), dim3(256), 0, stream, deg_int, N_NODES);
    hipLaunchKernelGGL(count_deg_kernel, dim3(2048), dim3(256), 0, stream, dstv, deg_int, N_EDGES);
    hipLaunchKernelGGL(dinv_kernel, dim3(nb), dim3(256), 0, stream, deg_int, dinv, N_NODES);
    hipLaunchKernelGGL(scan_p1_kernel, dim3(SCAN_BLOCKS), dim3(256), 0, stream, deg_int,
                       spartial, N_NODES);
    hipLaunchKernelGGL(scan_p2_kernel, dim3(1), dim3(256), 0, stream, spartial, sboff,
                       row_start, SCAN_BLOCKS, N_NODES, N_EDGES);
    hipLaunchKernelGGL(scan_p3_kernel, dim3(SCAN_BLOCKS), dim3(256), 0, stream, deg_int, sboff,
                       row_start, cursor, N_NODES);
    hipLaunchKernelGGL(fill_csr_kernel, dim3(2048), dim3(256), 0, stream, src, dstv, cursor,
                       csr_src, N_EDGES);
    hipLaunchKernelGGL(graph_bounds_kernel, dim3(1), dim3(NUM_GRAPHS + 1), 0, stream, batch,
                       gstart, N_NODES, NUM_GRAPHS);
    hipLaunchKernelGGL(wpack_kernel, dim3(16), dim3(256), 0, stream, W1, W1f, 128, 256);
    hipLaunchKernelGGL(wpack_kernel, dim3(32), dim3(256), 0, stream, W2, W2f, 256, 256);
    hipLaunchKernelGGL(wpack_kernel, dim3(16), dim3(256), 0, stream, W3, W3f, 256, 128);
    int n4 = N_NODES * 128 / 4;
    hipLaunchKernelGGL(f2bf4_kernel, dim3((n4 + 255) / 256), dim3(256), 0, stream, x, xbf, n4);

    int gx = NPAD / 128;  // 391
    int nba = (N_NODES * 64 + 255) / 256;

    // ---- layer 1: gather(xbf) -> Ap (panel bf16); gemm(+b1) -> bufA (f32); stats ----
    hipLaunchKernelGGL((gather_agg_kernel<128, 1>), dim3(N_NODES), dim3(64), 0, stream, xbf,
                       dinv, (const float*)nullptr, row_start, csr_src, Ap, N_NODES);
    hipLaunchKernelGGL((gemm_lds_kernel<4, false>), dim3(gx, 2), dim3(256), 0, stream, Ap,
                       W1f, b1, bufA, N_NODES, 256);
    run_bn_stats(stream, bufA, g1, be1, 256, sums, sumsq, scale, shift);

    // ---- layer 2: BN1+relu -> Ap; gemm -> Hbf; gather(+b2) -> bufA; stats ----
    hipLaunchKernelGGL(bnapply_panel_kernel, dim3(nba), dim3(256), 0, stream, bufA, scale,
                       shift, Ap, N_NODES);
    hipLaunchKernelGGL((gemm_lds_kernel<8, true>), dim3(gx, 2), dim3(256), 0, stream, Ap,
                       W2f, (const float*)nullptr, Hbf, N_NODES, 256);
    hipLaunchKernelGGL((gather_agg_kernel<256, 0>), dim3(N_NODES), dim3(64), 0, stream, Hbf,
                       dinv, b2, row_start, csr_src, bufA, N_NODES);
    run_bn_stats(stream, bufA, g2, be2, 256, sums, sumsq, scale, shift);

    // ---- layer 3: BN2+relu -> Ap; gemm -> Hbf; gather(+b3) -> bufA; stats ----
    hipLaunchKernelGGL(bnapply_panel_kernel, dim3(nba), dim3(256), 0, stream, bufA, scale,
                       shift, Ap, N_NODES);
    hipLaunchKernelGGL((gemm_lds_kernel<8, true>), dim3(gx, 1), dim3(256), 0, stream, Ap,
                       W3f, (const float*)nullptr, Hbf, N_NODES, 128);
    hipLaunchKernelGGL((gather_agg_kernel<128, 0>), dim3(N_NODES), dim3(64), 0, stream, Hbf,
                       dinv, b3, row_start, csr_src, bufA, N_NODES);
    run_bn_stats(stream, bufA, g3, be3, 128, sums, sumsq, scale, shift);

    // ---- pool: segmented mean with BN3 apply+relu fused ----
    hipLaunchKernelGGL(pool_seg_kernel, dim3(NUM_GRAPHS), dim3(256), 0, stream, bufA, scale,
                       shift, gstart, out);
}

// Round 9
// 593.662 us; speedup vs baseline: 4.4791x; 1.1010x over previous
//
#include <hip/hip_runtime.h>

#define N_NODES 50000
#define N_EDGES 800000
#define NUM_GRAPHS 128
#define EPS 1e-5f
#define SCAN_BLOCKS 196          // ceil(50000/256)
#define NPAD 50048               // 391 * 128 (row-tile padded node count)
#define POOL_SPLITS 8

typedef __attribute__((ext_vector_type(8))) short short8;
typedef __attribute__((ext_vector_type(4))) float floatx4;
typedef __attribute__((ext_vector_type(4))) unsigned short ushort4v;

__device__ __forceinline__ unsigned short f2bf_rne(float f) {
    unsigned int u = __float_as_uint(f);
    u += 0x7FFF + ((u >> 16) & 1);
    return (unsigned short)(u >> 16);
}
__device__ __forceinline__ float bf2f(unsigned short h) {
    return __uint_as_float(((unsigned int)h) << 16);
}
__device__ __forceinline__ float bflo(unsigned int u) { return __uint_as_float(u << 16); }
__device__ __forceinline__ float bfhi(unsigned int u) {
    return __uint_as_float(u & 0xFFFF0000u);
}

// async global->LDS, 16B per lane
__device__ __forceinline__ void gload16(const void* g, void* l) {
#if __has_builtin(__builtin_amdgcn_global_load_lds)
    __builtin_amdgcn_global_load_lds(
        reinterpret_cast<const __attribute__((address_space(1))) unsigned int*>(
            reinterpret_cast<unsigned long long>(g)),
        reinterpret_cast<__attribute__((address_space(3))) unsigned int*>(
            reinterpret_cast<unsigned long long>(l)),
        16, 0, 0);
#else
    *(uint4*)l = *(const uint4*)g;
#endif
}

// ---------------- degree / CSR build ----------------

__global__ void zero_int_kernel(int* p, int n) {
    int i = blockIdx.x * blockDim.x + threadIdx.x;
    if (i < n) p[i] = 0;
}

__global__ void count_deg_kernel(const int* __restrict__ dst, int* deg, int E) {
    int i = blockIdx.x * blockDim.x + threadIdx.x;
    int stride = gridDim.x * blockDim.x;
    for (; i < E; i += stride) atomicAdd(&deg[dst[i]], 1);
}

__global__ void dinv_kernel(const int* __restrict__ deg, float* dinv, int n) {
    int i = blockIdx.x * blockDim.x + threadIdx.x;
    if (i < n) dinv[i] = rsqrtf((float)(deg[i] + 1));
}

__global__ __launch_bounds__(256) void scan_p1_kernel(const int* __restrict__ deg,
                                                      int* __restrict__ partial, int n) {
    __shared__ int red[256];
    int tid = threadIdx.x;
    int i = blockIdx.x * 256 + tid;
    red[tid] = (i < n) ? deg[i] : 0;
    __syncthreads();
#pragma unroll
    for (int s = 128; s > 0; s >>= 1) {
        if (tid < s) red[tid] += red[tid + s];
        __syncthreads();
    }
    if (tid == 0) partial[blockIdx.x] = red[0];
}

__global__ __launch_bounds__(256) void scan_p2_kernel(const int* __restrict__ partial,
                                                      int* __restrict__ block_off,
                                                      int* __restrict__ row_start,
                                                      int nb, int n, int E) {
    __shared__ int s[256];
    int tid = threadIdx.x;
    int v = (tid < nb) ? partial[tid] : 0;
    s[tid] = v;
    __syncthreads();
#pragma unroll
    for (int off = 1; off < 256; off <<= 1) {
        int t = (tid >= off) ? s[tid - off] : 0;
        __syncthreads();
        s[tid] += t;
        __syncthreads();
    }
    if (tid < nb) block_off[tid] = s[tid] - v;
    if (tid == 0) row_start[n] = E;
}

__global__ __launch_bounds__(256) void scan_p3_kernel(const int* __restrict__ deg,
                                                      const int* __restrict__ block_off,
                                                      int* __restrict__ row_start,
                                                      int* __restrict__ cursor, int n) {
    __shared__ int s[256];
    int tid = threadIdx.x;
    int i = blockIdx.x * 256 + tid;
    int v = (i < n) ? deg[i] : 0;
    s[tid] = v;
    __syncthreads();
#pragma unroll
    for (int off = 1; off < 256; off <<= 1) {
        int t = (tid >= off) ? s[tid - off] : 0;
        __syncthreads();
        s[tid] += t;
        __syncthreads();
    }
    if (i < n) {
        int r = block_off[blockIdx.x] + s[tid] - v;
        row_start[i] = r;
        cursor[i] = r;
    }
}

__global__ void fill_csr_kernel(const int* __restrict__ src, const int* __restrict__ dst,
                                int* __restrict__ cursor, int* __restrict__ csr_src, int E) {
    int i = blockIdx.x * blockDim.x + threadIdx.x;
    int stride = gridDim.x * blockDim.x;
    for (; i < E; i += stride) {
        int p = atomicAdd(&cursor[dst[i]], 1);
        csr_src[p] = src[i];
    }
}

// ---------------- f32 -> bf16 bulk convert ----------------

__global__ void f2bf4_kernel(const float* __restrict__ in, unsigned short* __restrict__ out,
                             int n4) {
    int i = blockIdx.x * blockDim.x + threadIdx.x;
    if (i >= n4) return;
    float4 v = ((const float4*)in)[i];
    ushort4v o = {f2bf_rne(v.x), f2bf_rne(v.y), f2bf_rne(v.z), f2bf_rne(v.w)};
    ((ushort4v*)out)[i] = o;
}

// ---------------- BN apply + relu, f32 row-major -> bf16 panel-major -------------

__global__ void bnapply_panel_kernel(const float* __restrict__ A, const float* __restrict__ scale,
                                     const float* __restrict__ shift,
                                     unsigned short* __restrict__ Ap, int n) {
    int i = blockIdx.x * blockDim.x + threadIdx.x;  // over n*64 groups of 4 cols
    if (i >= n * 64) return;
    int row = i >> 6, cg = i & 63;
    int c0 = cg * 4;
    float4 v = ((const float4*)A)[i];
    float4 sc = ((const float4*)scale)[cg];
    float4 sh = ((const float4*)shift)[cg];
    float r0 = fmaxf(v.x * sc.x + sh.x, 0.0f);
    float r1 = fmaxf(v.y * sc.y + sh.y, 0.0f);
    float r2 = fmaxf(v.z * sc.z + sh.z, 0.0f);
    float r3 = fmaxf(v.w * sc.w + sh.w, 0.0f);
    uint2 o;
    o.x = (unsigned int)f2bf_rne(r0) | ((unsigned int)f2bf_rne(r1) << 16);
    o.y = (unsigned int)f2bf_rne(r2) | ((unsigned int)f2bf_rne(r3) << 16);
    int p = c0 >> 5, wc = c0 & 31;
    *(uint2*)(Ap + ((size_t)p * NPAD + row) * 32 + wc) = o;
}

// ---------------- W packing: f32 -> bf16 hi/lo, staging-friendly fragment order ---

__global__ void wpack_kernel(const float* __restrict__ W, short* __restrict__ Wf,
                             int K, int M) {
    int t = blockIdx.x * blockDim.x + threadIdx.x;
    int KT = K >> 5, MT = M >> 4;
    if (t >= KT * MT * 64) return;
    int lane = t & 63, chunk = t >> 6;
    int kt = chunk / MT, nt = chunk % MT;
    int q = lane >> 4, m = lane & 15;
    int n = nt * 16 + m;
    short* ophi = Wf + ((size_t)(kt * MT + nt) * 2 + 0) * 512 + lane * 8;
    short* oplo = Wf + ((size_t)(kt * MT + nt) * 2 + 1) * 512 + lane * 8;
#pragma unroll
    for (int j = 0; j < 8; ++j) {
        float w = W[(size_t)(kt * 32 + q * 8 + j) * M + n];
        unsigned short hi = f2bf_rne(w);
        unsigned short lo = f2bf_rne(w - bf2f(hi));
        ophi[j] = (short)hi;
        oplo[j] = (short)lo;
    }
}

// ---------------- LDS-staged MFMA GEMM ----------------

template <int KT, bool BF16OUT>
__global__ __launch_bounds__(256) void gemm_lds_kernel(
        const unsigned short* __restrict__ Ap, const short* __restrict__ Wf,
        const float* __restrict__ bias, void* __restrict__ Hout, int N, int M) {
    const int MT = M >> 4;
    __shared__ unsigned short sA[128 * 32];   // 8 KB
    __shared__ short sW[8 * 2 * 512];         // 16 KB
    int tid = threadIdx.x;
    int wave = tid >> 6, lane = tid & 63;
    int wr = wave >> 1, wc = wave & 1;
    int bm = blockIdx.x * 128;
    int bn = blockIdx.y * 128;
    int ntbb = bn >> 4;
    int q = lane >> 4, l16 = lane & 15;
    floatx4 acc[4][4] = {};
    for (int kt = 0; kt < KT; ++kt) {
        __syncthreads();
        {
            const char* ab = (const char*)(Ap + ((size_t)kt * NPAD + bm) * 32);
            const char* wb = (const char*)(Wf + (size_t)(kt * MT + ntbb) * 1024);
            char* sa = (char*)sA;
            char* sw = (char*)sW;
            gload16(ab + tid * 16, sa + tid * 16);
            gload16(ab + (256 + tid) * 16, sa + (256 + tid) * 16);
#pragma unroll
            for (int i = 0; i < 4; ++i)
                gload16(wb + (i * 256 + tid) * 16, sw + (i * 256 + tid) * 16);
        }
        __syncthreads();
        short8 a[4], wh[4], wl[4];
#pragma unroll
        for (int mt = 0; mt < 4; ++mt)
            a[mt] = *(const short8*)&sA[(wr * 64 + mt * 16 + l16) * 32 + q * 8];
#pragma unroll
        for (int nt = 0; nt < 4; ++nt) {
            wh[nt] = *(const short8*)&sW[((wc * 4 + nt) * 2 + 0) * 512 + lane * 8];
            wl[nt] = *(const short8*)&sW[((wc * 4 + nt) * 2 + 1) * 512 + lane * 8];
        }
#pragma unroll
        for (int nt = 0; nt < 4; ++nt)
#pragma unroll
            for (int mt = 0; mt < 4; ++mt) {
                acc[mt][nt] = __builtin_amdgcn_mfma_f32_16x16x32_bf16(a[mt], wh[nt],
                                                                      acc[mt][nt], 0, 0, 0);
                acc[mt][nt] = __builtin_amdgcn_mfma_f32_16x16x32_bf16(a[mt], wl[nt],
                                                                      acc[mt][nt], 0, 0, 0);
            }
    }
#pragma unroll
    for (int nt = 0; nt < 4; ++nt) {
        int col = bn + wc * 64 + nt * 16 + l16;
        float bv = bias ? bias[col] : 0.0f;
#pragma unroll
        for (int mt = 0; mt < 4; ++mt) {
#pragma unroll
            for (int r = 0; r < 4; ++r) {
                int row = bm + wr * 64 + mt * 16 + q * 4 + r;
                if (row < N) {
                    float v = acc[mt][nt][r] + bv;
                    if constexpr (BF16OUT)
                        ((unsigned short*)Hout)[(size_t)row * M + col] = f2bf_rne(v);
                    else
                        ((float*)Hout)[(size_t)row * M + col] = v;
                }
            }
        }
    }
}

// ---------------- gather aggregation (CSR by dst, bf16 in) ----------------------
// OUTMODE: 0 = f32 row-major, 1 = bf16 panel-major. 8x/4x-unrolled edge loop.

template <int C, int OUTMODE>
__global__ __launch_bounds__(64) void gather_agg_kernel(
        const unsigned short* __restrict__ Hb, const float* __restrict__ dinv,
        const float* __restrict__ bias, const int* __restrict__ row_start,
        const int* __restrict__ csr_src, void* __restrict__ AGG, int n) {
    constexpr int V = C / 64;  // channels per lane (2 or 4)
    constexpr int U = V / 2;   // packed uints per lane
    int i = blockIdx.x;
    if (i >= n) return;
    int lane = threadIdx.x;
    float di = dinv[i];
    float w0 = di * di;
    const unsigned int* base = (const unsigned int*)Hb;
    float acc[V];
    {
        const unsigned int* hrow = base + ((size_t)i * C >> 1) + lane * U;
#pragma unroll
        for (int t = 0; t < U; ++t) {
            unsigned int u = hrow[t];
            acc[2 * t] = (bias ? bias[lane * V + 2 * t] : 0.0f) + bflo(u) * w0;
            acc[2 * t + 1] = (bias ? bias[lane * V + 2 * t + 1] : 0.0f) + bfhi(u) * w0;
        }
    }
    int e0 = row_start[i], e1 = row_start[i + 1];
    int e = e0;
    for (; e + 8 <= e1; e += 8) {
        int s[8];
#pragma unroll
        for (int j = 0; j < 8; ++j) s[j] = csr_src[e + j];
        float w[8];
#pragma unroll
        for (int j = 0; j < 8; ++j) w[j] = dinv[s[j]] * di;
        unsigned int u[8][U];
#pragma unroll
        for (int j = 0; j < 8; ++j) {
            const unsigned int* p = base + ((size_t)s[j] * C >> 1) + lane * U;
#pragma unroll
            for (int t = 0; t < U; ++t) u[j][t] = p[t];
        }
#pragma unroll
        for (int t = 0; t < U; ++t) {
#pragma unroll
            for (int j = 0; j < 8; ++j) {
                acc[2 * t] += bflo(u[j][t]) * w[j];
                acc[2 * t + 1] += bfhi(u[j][t]) * w[j];
            }
        }
    }
    for (; e + 4 <= e1; e += 4) {
        int s[4];
#pragma unroll
        for (int j = 0; j < 4; ++j) s[j] = csr_src[e + j];
        float w[4];
#pragma unroll
        for (int j = 0; j < 4; ++j) w[j] = dinv[s[j]] * di;
        unsigned int u[4][U];
#pragma unroll
        for (int j = 0; j < 4; ++j) {
            const unsigned int* p = base + ((size_t)s[j] * C >> 1) + lane * U;
#pragma unroll
            for (int t = 0; t < U; ++t) u[j][t] = p[t];
        }
#pragma unroll
        for (int t = 0; t < U; ++t) {
#pragma unroll
            for (int j = 0; j < 4; ++j) {
                acc[2 * t] += bflo(u[j][t]) * w[j];
                acc[2 * t + 1] += bfhi(u[j][t]) * w[j];
            }
        }
    }
    for (; e < e1; ++e) {
        int s = csr_src[e];
        float w = dinv[s] * di;
        const unsigned int* srow = base + ((size_t)s * C >> 1) + lane * U;
#pragma unroll
        for (int t = 0; t < U; ++t) {
            unsigned int uu = srow[t];
            acc[2 * t] += bflo(uu) * w;
            acc[2 * t + 1] += bfhi(uu) * w;
        }
    }
    if constexpr (OUTMODE == 1) {
#pragma unroll
        for (int t = 0; t < U; ++t) {
            int c = lane * V + 2 * t;
            unsigned int o = (unsigned int)f2bf_rne(acc[2 * t]) |
                             ((unsigned int)f2bf_rne(acc[2 * t + 1]) << 16);
            *(unsigned int*)((unsigned short*)AGG + ((size_t)(c >> 5) * NPAD + i) * 32 +
                             (c & 31)) = o;
        }
    } else {
        float* orow = (float*)AGG + (size_t)i * C + lane * V;
        if constexpr (V == 4)
            *(float4*)orow = make_float4(acc[0], acc[1], acc[2], acc[3]);
        else
            *(float2*)orow = make_float2(acc[0], acc[1]);
    }
}

// ---------------- batch norm stats ----------------

__global__ void zero_kernel(float* p, int n) {
    int i = blockIdx.x * blockDim.x + threadIdx.x;
    if (i < n) p[i] = 0.0f;
}

__global__ void bn_stats_kernel(const float* __restrict__ A, float* __restrict__ sums,
                                float* __restrict__ sumsq, int n, int C) {
    int c = threadIdx.x;
    int rpb = (n + gridDim.x - 1) / gridDim.x;
    int r0 = blockIdx.x * rpb;
    int r1 = min(n, r0 + rpb);
    float s = 0.0f, s2 = 0.0f;
    for (int r = r0; r < r1; ++r) {
        float v = A[(size_t)r * C + c];
        s += v;
        s2 += v * v;
    }
    atomicAdd(&sums[c], s);
    atomicAdd(&sumsq[c], s2);
}

__global__ void bn_finalize_kernel(const float* __restrict__ sums, const float* __restrict__ sumsq,
                                   const float* __restrict__ gamma, const float* __restrict__ beta,
                                   float* __restrict__ scale, float* __restrict__ shift,
                                   int n, int C) {
    int c = threadIdx.x;
    if (c >= C) return;
    float inv_n = 1.0f / (float)n;
    float mu = sums[c] * inv_n;
    float var = sumsq[c] * inv_n - mu * mu;
    float rs = rsqrtf(var + EPS);
    float sc = gamma[c] * rs;
    scale[c] = sc;
    shift[c] = beta[c] - mu * sc;
}

// ---------------- pooling (sorted-segment, parallel, BN3+relu fused) -------------

__global__ void graph_bounds_kernel(const int* __restrict__ batch, int* __restrict__ gstart,
                                    int n, int G) {
    int g = blockIdx.x * blockDim.x + threadIdx.x;
    if (g > G) return;
    int lo = 0, hi = n;
    while (lo < hi) {
        int mid = (lo + hi) >> 1;
        if (batch[mid] < g) lo = mid + 1; else hi = mid;
    }
    gstart[g] = lo;
}

// grid (G, POOL_SPLITS) x 128 threads; partial sums -> atomic accumulate
__global__ __launch_bounds__(128) void pool_part_kernel(
        const float* __restrict__ A, const float* __restrict__ scale,
        const float* __restrict__ shift, const int* __restrict__ gstart,
        float* __restrict__ outacc) {
    int g = blockIdx.x;
    int split = blockIdx.y;
    int c = threadIdx.x;
    int r0 = gstart[g], r1 = gstart[g + 1];
    float sc = scale[c], sh = shift[c];
    float s = 0.0f;
    for (int r = r0 + split; r < r1; r += POOL_SPLITS) {
        float v = A[(size_t)r * 128 + c];
        s += fmaxf(v * sc + sh, 0.0f);
    }
    atomicAdd(&outacc[g * 128 + c], s);
}

__global__ void pool_fin_kernel(const float* __restrict__ outacc,
                                const int* __restrict__ gstart, float* __restrict__ out) {
    int idx = blockIdx.x * blockDim.x + threadIdx.x;
    if (idx >= NUM_GRAPHS * 128) return;
    int g = idx >> 7;
    float cnt = (float)(gstart[g + 1] - gstart[g]);
    out[idx] = outacc[idx] / fmaxf(cnt, 1.0f);
}

// ---------------- host-side helpers ----------------

static void run_bn_stats(hipStream_t stream, const float* A, const float* gamma,
                         const float* beta, int Cout, float* sums, float* sumsq,
                         float* scale, float* shift) {
    hipLaunchKernelGGL(zero_kernel, dim3(2), dim3(256), 0, stream, sums, 512);
    hipLaunchKernelGGL(bn_stats_kernel, dim3(1024), dim3(Cout), 0, stream, A, sums, sumsq,
                       N_NODES, Cout);
    hipLaunchKernelGGL(bn_finalize_kernel, dim3(1), dim3(Cout), 0, stream, sums, sumsq, gamma,
                       beta, scale, shift, N_NODES, Cout);
}

extern "C" void kernel_launch(void* const* d_in, const int* in_sizes, int n_in,
                              void* d_out, int out_size, void* d_ws, size_t ws_size,
                              hipStream_t stream) {
    const float* x     = (const float*)d_in[0];
    const int*   ei    = (const int*)d_in[1];
    const int*   batch = (const int*)d_in[2];
    const float* W1 = (const float*)d_in[3];
    const float* b1 = (const float*)d_in[4];
    const float* W2 = (const float*)d_in[5];
    const float* b2 = (const float*)d_in[6];
    const float* W3 = (const float*)d_in[7];
    const float* b3 = (const float*)d_in[8];
    const float* g1 = (const float*)d_in[9];
    const float* be1 = (const float*)d_in[10];
    const float* g2 = (const float*)d_in[11];
    const float* be2 = (const float*)d_in[12];
    const float* g3 = (const float*)d_in[13];
    const float* be3 = (const float*)d_in[14];
    float* out = (float*)d_out;

    const int* src = ei;
    const int* dstv = ei + N_EDGES;

    size_t off = 0;
    auto allocb = [&](size_t nbytes) {
        char* p = (char*)d_ws + off;
        off += (nbytes + 255) & ~(size_t)255;
        return p;
    };
    int*   deg_int   = (int*)allocb(N_NODES * 4);
    int*   row_start = (int*)allocb((N_NODES + 1) * 4);
    int*   cursor    = (int*)allocb(N_NODES * 4);
    int*   csr_src   = (int*)allocb(N_EDGES * 4);
    int*   gstart    = (int*)allocb((NUM_GRAPHS + 1) * 4);
    int*   spartial  = (int*)allocb(SCAN_BLOCKS * 4);
    int*   sboff     = (int*)allocb(SCAN_BLOCKS * 4);
    float* dinv      = (float*)allocb(N_NODES * 4);
    float* sums      = (float*)allocb(512 * 4);
    float* sumsq     = sums + 256;
    float* scale     = (float*)allocb(256 * 4);
    float* shift     = (float*)allocb(256 * 4);
    float* outacc    = (float*)allocb(NUM_GRAPHS * 128 * 4);
    short* W1f       = (short*)allocb((size_t)128 * 256 * 4);
    short* W2f       = (short*)allocb((size_t)256 * 256 * 4);
    short* W3f       = (short*)allocb((size_t)256 * 128 * 4);
    unsigned short* Hbf = (unsigned short*)allocb((size_t)N_NODES * 256 * 2);  // bf16 H
    float* bufA      = (float*)allocb((size_t)N_NODES * 256 * 4);   // f32 AGG / GEMM out
    float* bufB      = (float*)allocb((size_t)NPAD * 256 * 4);      // panel-major bf16 A
    unsigned short* xbf = Hbf;            // x-bf16 aliases Hbf (dead until layer-2 GEMM)
    unsigned short* Ap  = (unsigned short*)bufB;  // panel-major bf16 activations
    (void)ws_size; (void)n_in; (void)in_sizes; (void)out_size;

    int nb = (N_NODES + 255) / 256;

    // ---- degree, dinv, CSR (by dst), graph bounds, W packing, x->bf16 ----
    hipLaunchKernelGGL(zero_int_kernel, dim3(nb), dim3(256), 0, stream, deg_int, N_NODES);
    hipLaunchKernelGGL(count_deg_kernel, dim3(2048), dim3(256), 0, stream, dstv, deg_int, N_EDGES);
    hipLaunchKernelGGL(dinv_kernel, dim3(nb), dim3(256), 0, stream, deg_int, dinv, N_NODES);
    hipLaunchKernelGGL(scan_p1_kernel, dim3(SCAN_BLOCKS), dim3(256), 0, stream, deg_int,
                       spartial, N_NODES);
    hipLaunchKernelGGL(scan_p2_kernel, dim3(1), dim3(256), 0, stream, spartial, sboff,
                       row_start, SCAN_BLOCKS, N_NODES, N_EDGES);
    hipLaunchKernelGGL(scan_p3_kernel, dim3(SCAN_BLOCKS), dim3(256), 0, stream, deg_int, sboff,
                       row_start, cursor, N_NODES);
    hipLaunchKernelGGL(fill_csr_kernel, dim3(2048), dim3(256), 0, stream, src, dstv, cursor,
                       csr_src, N_EDGES);
    hipLaunchKernelGGL(graph_bounds_kernel, dim3(1), dim3(NUM_GRAPHS + 1), 0, stream, batch,
                       gstart, N_NODES, NUM_GRAPHS);
    hipLaunchKernelGGL(zero_kernel, dim3((NUM_GRAPHS * 128 + 255) / 256), dim3(256), 0, stream,
                       outacc, NUM_GRAPHS * 128);
    hipLaunchKernelGGL(wpack_kernel, dim3(16), dim3(256), 0, stream, W1, W1f, 128, 256);
    hipLaunchKernelGGL(wpack_kernel, dim3(32), dim3(256), 0, stream, W2, W2f, 256, 256);
    hipLaunchKernelGGL(wpack_kernel, dim3(16), dim3(256), 0, stream, W3, W3f, 256, 128);
    int n4 = N_NODES * 128 / 4;
    hipLaunchKernelGGL(f2bf4_kernel, dim3((n4 + 255) / 256), dim3(256), 0, stream, x, xbf, n4);

    int gx = NPAD / 128;  // 391
    int nba = (N_NODES * 64 + 255) / 256;

    // ---- layer 1: gather(xbf) -> Ap (panel bf16); gemm(+b1) -> bufA (f32); stats ----
    hipLaunchKernelGGL((gather_agg_kernel<128, 1>), dim3(N_NODES), dim3(64), 0, stream, xbf,
                       dinv, (const float*)nullptr, row_start, csr_src, Ap, N_NODES);
    hipLaunchKernelGGL((gemm_lds_kernel<4, false>), dim3(gx, 2), dim3(256), 0, stream, Ap,
                       W1f, b1, bufA, N_NODES, 256);
    run_bn_stats(stream, bufA, g1, be1, 256, sums, sumsq, scale, shift);

    // ---- layer 2: BN1+relu -> Ap; gemm -> Hbf; gather(+b2) -> bufA; stats ----
    hipLaunchKernelGGL(bnapply_panel_kernel, dim3(nba), dim3(256), 0, stream, bufA, scale,
                       shift, Ap, N_NODES);
    hipLaunchKernelGGL((gemm_lds_kernel<8, true>), dim3(gx, 2), dim3(256), 0, stream, Ap,
                       W2f, (const float*)nullptr, Hbf, N_NODES, 256);
    hipLaunchKernelGGL((gather_agg_kernel<256, 0>), dim3(N_NODES), dim3(64), 0, stream, Hbf,
                       dinv, b2, row_start, csr_src, bufA, N_NODES);
    run_bn_stats(stream, bufA, g2, be2, 256, sums, sumsq, scale, shift);

    // ---- layer 3: BN2+relu -> Ap; gemm -> Hbf; gather(+b3) -> bufA; stats ----
    hipLaunchKernelGGL(bnapply_panel_kernel, dim3(nba), dim3(256), 0, stream, bufA, scale,
                       shift, Ap, N_NODES);
    hipLaunchKernelGGL((gemm_lds_kernel<8, true>), dim3(gx, 1), dim3(256), 0, stream, Ap,
                       W3f, (const float*)nullptr, Hbf, N_NODES, 128);
    hipLaunchKernelGGL((gather_agg_kernel<128, 0>), dim3(N_NODES), dim3(64), 0, stream, Hbf,
                       dinv, b3, row_start, csr_src, bufA, N_NODES);
    run_bn_stats(stream, bufA, g3, be3, 128, sums, sumsq, scale, shift);

    // ---- pool: parallel segmented mean with BN3 apply+relu fused ----
    hipLaunchKernelGGL(pool_part_kernel, dim3(NUM_GRAPHS, POOL_SPLITS), dim3(128), 0, stream,
                       bufA, scale, shift, gstart, outacc);
    hipLaunchKernelGGL(pool_fin_kernel, dim3((NUM_GRAPHS * 128 + 255) / 256), dim3(256), 0,
                       stream, outacc, gstart, out);
}

// Round 10
// 531.661 us; speedup vs baseline: 5.0014x; 1.1166x over previous
//
#include <hip/hip_runtime.h>

#define N_NODES 50000
#define N_EDGES 800000
#define NUM_GRAPHS 128
#define EPS 1e-5f
#define SCAN_BLOCKS 196          // ceil(50000/256)
#define NPAD 50048               // 391 * 128 (row-tile padded node count)
#define POOL_SPLITS 8
#define INV_N (1.0f / 50000.0f)

typedef __attribute__((ext_vector_type(8))) short short8;
typedef __attribute__((ext_vector_type(4))) float floatx4;
typedef __attribute__((ext_vector_type(4))) unsigned short ushort4v;

__device__ __forceinline__ unsigned short f2bf_rne(float f) {
    unsigned int u = __float_as_uint(f);
    u += 0x7FFF + ((u >> 16) & 1);
    return (unsigned short)(u >> 16);
}
__device__ __forceinline__ float bf2f(unsigned short h) {
    return __uint_as_float(((unsigned int)h) << 16);
}
__device__ __forceinline__ float bflo(unsigned int u) { return __uint_as_float(u << 16); }
__device__ __forceinline__ float bfhi(unsigned int u) {
    return __uint_as_float(u & 0xFFFF0000u);
}

// async global->LDS, 16B per lane
__device__ __forceinline__ void gload16(const void* g, void* l) {
#if __has_builtin(__builtin_amdgcn_global_load_lds)
    __builtin_amdgcn_global_load_lds(
        reinterpret_cast<const __attribute__((address_space(1))) unsigned int*>(
            reinterpret_cast<unsigned long long>(g)),
        reinterpret_cast<__attribute__((address_space(3))) unsigned int*>(
            reinterpret_cast<unsigned long long>(l)),
        16, 0, 0);
#else
    *(uint4*)l = *(const uint4*)g;
#endif
}

// ---------------- degree / CSR build (rank-based, no cursor atomics in fill) -----

__global__ void zero_int_kernel(int* p, int n) {
    int i = blockIdx.x * blockDim.x + threadIdx.x;
    if (i < n) p[i] = 0;
}

__global__ void count_deg_rank_kernel(const int* __restrict__ dst, int* deg,
                                      int* __restrict__ rank, int E) {
    int i = blockIdx.x * blockDim.x + threadIdx.x;
    int stride = gridDim.x * blockDim.x;
    for (; i < E; i += stride) rank[i] = atomicAdd(&deg[dst[i]], 1);
}

__global__ __launch_bounds__(256) void scan_p1_kernel(const int* __restrict__ deg,
                                                      int* __restrict__ partial, int n) {
    __shared__ int red[256];
    int tid = threadIdx.x;
    int i = blockIdx.x * 256 + tid;
    red[tid] = (i < n) ? deg[i] : 0;
    __syncthreads();
#pragma unroll
    for (int s = 128; s > 0; s >>= 1) {
        if (tid < s) red[tid] += red[tid + s];
        __syncthreads();
    }
    if (tid == 0) partial[blockIdx.x] = red[0];
}

__global__ __launch_bounds__(256) void scan_p2_kernel(const int* __restrict__ partial,
                                                      int* __restrict__ block_off,
                                                      int* __restrict__ row_start,
                                                      int nb, int n, int E) {
    __shared__ int s[256];
    int tid = threadIdx.x;
    int v = (tid < nb) ? partial[tid] : 0;
    s[tid] = v;
    __syncthreads();
#pragma unroll
    for (int off = 1; off < 256; off <<= 1) {
        int t = (tid >= off) ? s[tid - off] : 0;
        __syncthreads();
        s[tid] += t;
        __syncthreads();
    }
    if (tid < nb) block_off[tid] = s[tid] - v;
    if (tid == 0) row_start[n] = E;
}

// exclusive scan -> row_start; also dinv = rsqrt(deg+1) (fused)
__global__ __launch_bounds__(256) void scan_p3_kernel(const int* __restrict__ deg,
                                                      const int* __restrict__ block_off,
                                                      int* __restrict__ row_start,
                                                      float* __restrict__ dinv, int n) {
    __shared__ int s[256];
    int tid = threadIdx.x;
    int i = blockIdx.x * 256 + tid;
    int v = (i < n) ? deg[i] : 0;
    s[tid] = v;
    __syncthreads();
#pragma unroll
    for (int off = 1; off < 256; off <<= 1) {
        int t = (tid >= off) ? s[tid - off] : 0;
        __syncthreads();
        s[tid] += t;
        __syncthreads();
    }
    if (i < n) {
        row_start[i] = block_off[blockIdx.x] + s[tid] - v;
        dinv[i] = rsqrtf((float)(v + 1));
    }
}

__global__ void fill_csr_kernel(const int* __restrict__ src, const int* __restrict__ dst,
                                const int* __restrict__ rank, const int* __restrict__ row_start,
                                int* __restrict__ csr_src, int E) {
    int i = blockIdx.x * blockDim.x + threadIdx.x;
    int stride = gridDim.x * blockDim.x;
    for (; i < E; i += stride) csr_src[row_start[dst[i]] + rank[i]] = src[i];
}

// ---------------- f32 -> bf16 bulk convert ----------------

__global__ void f2bf4_kernel(const float* __restrict__ in, unsigned short* __restrict__ out,
                             int n4) {
    int i = blockIdx.x * blockDim.x + threadIdx.x;
    if (i >= n4) return;
    float4 v = ((const float4*)in)[i];
    ushort4v o = {f2bf_rne(v.x), f2bf_rne(v.y), f2bf_rne(v.z), f2bf_rne(v.w)};
    ((ushort4v*)out)[i] = o;
}

// ---------------- BN finalize (inline helper) ----------------

__device__ __forceinline__ void bn_coeff(const float* __restrict__ sums,
                                         const float* __restrict__ sumsq,
                                         const float* __restrict__ gamma,
                                         const float* __restrict__ beta, int c,
                                         float& sc, float& sh) {
    float mu = sums[c] * INV_N;
    float var = sumsq[c] * INV_N - mu * mu;
    float rs = rsqrtf(var + EPS);
    sc = gamma[c] * rs;
    sh = beta[c] - mu * sc;
}

// ---------------- BN apply + relu: bf16 row-major -> bf16 panel-major -------------
// scale/shift computed inline from sums/sumsq/gamma/beta (finalize fused).

__global__ void bnapply_panel_kernel(const unsigned short* __restrict__ A,
                                     const float* __restrict__ sums,
                                     const float* __restrict__ sumsq,
                                     const float* __restrict__ gamma,
                                     const float* __restrict__ beta,
                                     unsigned short* __restrict__ Ap, int n) {
    int i = blockIdx.x * blockDim.x + threadIdx.x;  // over n*64 groups of 4 cols
    if (i >= n * 64) return;
    int row = i >> 6, cg = i & 63;
    int c0 = cg * 4;
    uint2 in = *(const uint2*)(A + (size_t)row * 256 + c0);
    float v0 = bflo(in.x), v1 = bfhi(in.x), v2 = bflo(in.y), v3 = bfhi(in.y);
    float sc0, sh0, sc1, sh1, sc2, sh2, sc3, sh3;
    bn_coeff(sums, sumsq, gamma, beta, c0 + 0, sc0, sh0);
    bn_coeff(sums, sumsq, gamma, beta, c0 + 1, sc1, sh1);
    bn_coeff(sums, sumsq, gamma, beta, c0 + 2, sc2, sh2);
    bn_coeff(sums, sumsq, gamma, beta, c0 + 3, sc3, sh3);
    float r0 = fmaxf(v0 * sc0 + sh0, 0.0f);
    float r1 = fmaxf(v1 * sc1 + sh1, 0.0f);
    float r2 = fmaxf(v2 * sc2 + sh2, 0.0f);
    float r3 = fmaxf(v3 * sc3 + sh3, 0.0f);
    uint2 o;
    o.x = (unsigned int)f2bf_rne(r0) | ((unsigned int)f2bf_rne(r1) << 16);
    o.y = (unsigned int)f2bf_rne(r2) | ((unsigned int)f2bf_rne(r3) << 16);
    int p = c0 >> 5, wc = c0 & 31;
    *(uint2*)(Ap + ((size_t)p * NPAD + row) * 32 + wc) = o;
}

// ---------------- W packing: f32 -> bf16 hi/lo, one fused dispatch ---------------

__device__ __forceinline__ void wpack_one(const float* __restrict__ W, short* __restrict__ Wf,
                                          int K, int M, int t) {
    int KT = K >> 5, MT = M >> 4;
    if (t >= KT * MT * 64) return;
    int lane = t & 63, chunk = t >> 6;
    int kt = chunk / MT, nt = chunk % MT;
    int q = lane >> 4, m = lane & 15;
    int n = nt * 16 + m;
    short* ophi = Wf + ((size_t)(kt * MT + nt) * 2 + 0) * 512 + lane * 8;
    short* oplo = Wf + ((size_t)(kt * MT + nt) * 2 + 1) * 512 + lane * 8;
#pragma unroll
    for (int j = 0; j < 8; ++j) {
        float w = W[(size_t)(kt * 32 + q * 8 + j) * M + n];
        unsigned short hi = f2bf_rne(w);
        unsigned short lo = f2bf_rne(w - bf2f(hi));
        ophi[j] = (short)hi;
        oplo[j] = (short)lo;
    }
}

__global__ __launch_bounds__(256) void wpack_all_kernel(
        const float* __restrict__ W1, const float* __restrict__ W2,
        const float* __restrict__ W3, short* W1f, short* W2f, short* W3f) {
    int b = blockIdx.x;
    if (b < 16) wpack_one(W1, W1f, 128, 256, b * 256 + threadIdx.x);
    else if (b < 48) wpack_one(W2, W2f, 256, 256, (b - 16) * 256 + threadIdx.x);
    else wpack_one(W3, W3f, 256, 128, (b - 48) * 256 + threadIdx.x);
}

// ---------------- LDS-staged MFMA GEMM (bf16 out) ----------------

template <int KT>
__global__ __launch_bounds__(256) void gemm_lds_kernel(
        const unsigned short* __restrict__ Ap, const short* __restrict__ Wf,
        const float* __restrict__ bias, unsigned short* __restrict__ Hout, int N, int M) {
    const int MT = M >> 4;
    __shared__ unsigned short sA[128 * 32];   // 8 KB
    __shared__ short sW[8 * 2 * 512];         // 16 KB
    int tid = threadIdx.x;
    int wave = tid >> 6, lane = tid & 63;
    int wr = wave >> 1, wc = wave & 1;
    int bm = blockIdx.x * 128;
    int bn = blockIdx.y * 128;
    int ntbb = bn >> 4;
    int q = lane >> 4, l16 = lane & 15;
    floatx4 acc[4][4] = {};
    for (int kt = 0; kt < KT; ++kt) {
        __syncthreads();
        {
            const char* ab = (const char*)(Ap + ((size_t)kt * NPAD + bm) * 32);
            const char* wb = (const char*)(Wf + (size_t)(kt * MT + ntbb) * 1024);
            char* sa = (char*)sA;
            char* sw = (char*)sW;
            gload16(ab + tid * 16, sa + tid * 16);
            gload16(ab + (256 + tid) * 16, sa + (256 + tid) * 16);
#pragma unroll
            for (int i = 0; i < 4; ++i)
                gload16(wb + (i * 256 + tid) * 16, sw + (i * 256 + tid) * 16);
        }
        __syncthreads();
        short8 a[4], wh[4], wl[4];
#pragma unroll
        for (int mt = 0; mt < 4; ++mt)
            a[mt] = *(const short8*)&sA[(wr * 64 + mt * 16 + l16) * 32 + q * 8];
#pragma unroll
        for (int nt = 0; nt < 4; ++nt) {
            wh[nt] = *(const short8*)&sW[((wc * 4 + nt) * 2 + 0) * 512 + lane * 8];
            wl[nt] = *(const short8*)&sW[((wc * 4 + nt) * 2 + 1) * 512 + lane * 8];
        }
#pragma unroll
        for (int nt = 0; nt < 4; ++nt)
#pragma unroll
            for (int mt = 0; mt < 4; ++mt) {
                acc[mt][nt] = __builtin_amdgcn_mfma_f32_16x16x32_bf16(a[mt], wh[nt],
                                                                      acc[mt][nt], 0, 0, 0);
                acc[mt][nt] = __builtin_amdgcn_mfma_f32_16x16x32_bf16(a[mt], wl[nt],
                                                                      acc[mt][nt], 0, 0, 0);
            }
    }
#pragma unroll
    for (int nt = 0; nt < 4; ++nt) {
        int col = bn + wc * 64 + nt * 16 + l16;
        float bv = bias ? bias[col] : 0.0f;
#pragma unroll
        for (int mt = 0; mt < 4; ++mt) {
#pragma unroll
            for (int r = 0; r < 4; ++r) {
                int row = bm + wr * 64 + mt * 16 + q * 4 + r;
                if (row < N)
                    Hout[(size_t)row * M + col] = f2bf_rne(acc[mt][nt][r] + bv);
            }
        }
    }
}

// ---------------- gather aggregation (CSR by dst, bf16 in, bf16 out) -------------
// OUTMODE: 1 = bf16 panel-major (GEMM A operand), 2 = bf16 row-major.

template <int C, int OUTMODE>
__global__ __launch_bounds__(64) void gather_agg_kernel(
        const unsigned short* __restrict__ Hb, const float* __restrict__ dinv,
        const float* __restrict__ bias, const int* __restrict__ row_start,
        const int* __restrict__ csr_src, unsigned short* __restrict__ AGG, int n) {
    constexpr int V = C / 64;  // channels per lane (2 or 4)
    constexpr int U = V / 2;   // packed uints per lane
    int i = blockIdx.x;
    if (i >= n) return;
    int lane = threadIdx.x;
    float di = dinv[i];
    float w0 = di * di;
    const unsigned int* base = (const unsigned int*)Hb;
    float acc[V];
    {
        const unsigned int* hrow = base + ((size_t)i * C >> 1) + lane * U;
#pragma unroll
        for (int t = 0; t < U; ++t) {
            unsigned int u = hrow[t];
            acc[2 * t] = (bias ? bias[lane * V + 2 * t] : 0.0f) + bflo(u) * w0;
            acc[2 * t + 1] = (bias ? bias[lane * V + 2 * t + 1] : 0.0f) + bfhi(u) * w0;
        }
    }
    int e0 = row_start[i], e1 = row_start[i + 1];
    int e = e0;
    for (; e + 4 <= e1; e += 4) {
        int s[4];
#pragma unroll
        for (int j = 0; j < 4; ++j) s[j] = csr_src[e + j];
        float w[4];
#pragma unroll
        for (int j = 0; j < 4; ++j) w[j] = dinv[s[j]] * di;
        unsigned int u[4][U];
#pragma unroll
        for (int j = 0; j < 4; ++j) {
            const unsigned int* p = base + ((size_t)s[j] * C >> 1) + lane * U;
#pragma unroll
            for (int t = 0; t < U; ++t) u[j][t] = p[t];
        }
#pragma unroll
        for (int t = 0; t < U; ++t) {
#pragma unroll
            for (int j = 0; j < 4; ++j) {
                acc[2 * t] += bflo(u[j][t]) * w[j];
                acc[2 * t + 1] += bfhi(u[j][t]) * w[j];
            }
        }
    }
    for (; e < e1; ++e) {
        int s = csr_src[e];
        float w = dinv[s] * di;
        const unsigned int* srow = base + ((size_t)s * C >> 1) + lane * U;
#pragma unroll
        for (int t = 0; t < U; ++t) {
            unsigned int uu = srow[t];
            acc[2 * t] += bflo(uu) * w;
            acc[2 * t + 1] += bfhi(uu) * w;
        }
    }
    if constexpr (OUTMODE == 1) {
#pragma unroll
        for (int t = 0; t < U; ++t) {
            int c = lane * V + 2 * t;
            unsigned int o = (unsigned int)f2bf_rne(acc[2 * t]) |
                             ((unsigned int)f2bf_rne(acc[2 * t + 1]) << 16);
            *(unsigned int*)(AGG + ((size_t)(c >> 5) * NPAD + i) * 32 + (c & 31)) = o;
        }
    } else {
        unsigned int* orow = (unsigned int*)AGG + ((size_t)i * C >> 1) + lane * U;
#pragma unroll
        for (int t = 0; t < U; ++t)
            orow[t] = (unsigned int)f2bf_rne(acc[2 * t]) |
                      ((unsigned int)f2bf_rne(acc[2 * t + 1]) << 16);
    }
}

// ---------------- batch norm stats (bf16 input) ----------------

__global__ void zero_kernel(float* p, int n) {
    int i = blockIdx.x * blockDim.x + threadIdx.x;
    if (i < n) p[i] = 0.0f;
}

__global__ void bn_stats_kernel(const unsigned short* __restrict__ A, float* __restrict__ sums,
                                float* __restrict__ sumsq, int n, int C) {
    int c = threadIdx.x;
    int rpb = (n + gridDim.x - 1) / gridDim.x;
    int r0 = blockIdx.x * rpb;
    int r1 = min(n, r0 + rpb);
    float s = 0.0f, s2 = 0.0f;
    for (int r = r0; r < r1; ++r) {
        float v = bf2f(A[(size_t)r * C + c]);
        s += v;
        s2 += v * v;
    }
    atomicAdd(&sums[c], s);
    atomicAdd(&sumsq[c], s2);
}

// ---------------- pooling (sorted-segment, parallel, BN3+relu fused) -------------

__global__ void graph_bounds_kernel(const int* __restrict__ batch, int* __restrict__ gstart,
                                    int n, int G) {
    int g = blockIdx.x * blockDim.x + threadIdx.x;
    if (g > G) return;
    int lo = 0, hi = n;
    while (lo < hi) {
        int mid = (lo + hi) >> 1;
        if (batch[mid] < g) lo = mid + 1; else hi = mid;
    }
    gstart[g] = lo;
}

__global__ __launch_bounds__(128) void pool_part_kernel(
        const unsigned short* __restrict__ A, const float* __restrict__ sums,
        const float* __restrict__ sumsq, const float* __restrict__ gamma,
        const float* __restrict__ beta, const int* __restrict__ gstart,
        float* __restrict__ outacc) {
    int g = blockIdx.x;
    int split = blockIdx.y;
    int c = threadIdx.x;
    int r0 = gstart[g], r1 = gstart[g + 1];
    float sc, sh;
    bn_coeff(sums, sumsq, gamma, beta, c, sc, sh);
    float s = 0.0f;
    for (int r = r0 + split; r < r1; r += POOL_SPLITS) {
        float v = bf2f(A[(size_t)r * 128 + c]);
        s += fmaxf(v * sc + sh, 0.0f);
    }
    atomicAdd(&outacc[g * 128 + c], s);
}

__global__ void pool_fin_kernel(const float* __restrict__ outacc,
                                const int* __restrict__ gstart, float* __restrict__ out) {
    int idx = blockIdx.x * blockDim.x + threadIdx.x;
    if (idx >= NUM_GRAPHS * 128) return;
    int g = idx >> 7;
    float cnt = (float)(gstart[g + 1] - gstart[g]);
    out[idx] = outacc[idx] / fmaxf(cnt, 1.0f);
}

// ---------------- host driver ----------------

extern "C" void kernel_launch(void* const* d_in, const int* in_sizes, int n_in,
                              void* d_out, int out_size, void* d_ws, size_t ws_size,
                              hipStream_t stream) {
    const float* x     = (const float*)d_in[0];
    const int*   ei    = (const int*)d_in[1];
    const int*   batch = (const int*)d_in[2];
    const float* W1 = (const float*)d_in[3];
    const float* b1 = (const float*)d_in[4];
    const float* W2 = (const float*)d_in[5];
    const float* b2 = (const float*)d_in[6];
    const float* W3 = (const float*)d_in[7];
    const float* b3 = (const float*)d_in[8];
    const float* g1 = (const float*)d_in[9];
    const float* be1 = (const float*)d_in[10];
    const float* g2 = (const float*)d_in[11];
    const float* be2 = (const float*)d_in[12];
    const float* g3 = (const float*)d_in[13];
    const float* be3 = (const float*)d_in[14];
    float* out = (float*)d_out;

    const int* src = ei;
    const int* dstv = ei + N_EDGES;

    size_t off = 0;
    auto allocb = [&](size_t nbytes) {
        char* p = (char*)d_ws + off;
        off += (nbytes + 255) & ~(size_t)255;
        return p;
    };
    int*   deg_int   = (int*)allocb(N_NODES * 4);
    int*   row_start = (int*)allocb((N_NODES + 1) * 4);
    int*   rank      = (int*)allocb(N_EDGES * 4);
    int*   csr_src   = (int*)allocb(N_EDGES * 4);
    int*   gstart    = (int*)allocb((NUM_GRAPHS + 1) * 4);
    int*   spartial  = (int*)allocb(SCAN_BLOCKS * 4);
    int*   sboff     = (int*)allocb(SCAN_BLOCKS * 4);
    float* dinv      = (float*)allocb(N_NODES * 4);
    float* sums_all  = (float*)allocb(3 * 512 * 4);  // [layer][sums256|sumsq256]
    float* outacc    = (float*)allocb(NUM_GRAPHS * 128 * 4);
    short* W1f       = (short*)allocb((size_t)128 * 256 * 4);
    short* W2f       = (short*)allocb((size_t)256 * 256 * 4);
    short* W3f       = (short*)allocb((size_t)256 * 128 * 4);
    unsigned short* Hbf  = (unsigned short*)allocb((size_t)N_NODES * 256 * 2);  // GEMM out
    unsigned short* bufA = (unsigned short*)allocb((size_t)N_NODES * 256 * 2);  // AGG/H1
    unsigned short* Ap   = (unsigned short*)allocb((size_t)NPAD * 256 * 2);     // panels
    unsigned short* xbf  = Hbf;  // x-bf16 aliases Hbf (dead until layer-2 GEMM)
    (void)ws_size; (void)n_in; (void)in_sizes; (void)out_size;

    float* s1 = sums_all, *sq1 = sums_all + 256;
    float* s2 = sums_all + 512, *sq2 = sums_all + 768;
    float* s3 = sums_all + 1024, *sq3 = sums_all + 1280;

    int nb = (N_NODES + 255) / 256;

    // ---- prologue: degree+rank, scan(+dinv), CSR fill, bounds, zeros, wpack, x->bf16 ----
    hipLaunchKernelGGL(zero_int_kernel, dim3(nb), dim3(256), 0, stream, deg_int, N_NODES);
    hipLaunchKernelGGL(count_deg_rank_kernel, dim3(2048), dim3(256), 0, stream, dstv, deg_int,
                       rank, N_EDGES);
    hipLaunchKernelGGL(scan_p1_kernel, dim3(SCAN_BLOCKS), dim3(256), 0, stream, deg_int,
                       spartial, N_NODES);
    hipLaunchKernelGGL(scan_p2_kernel, dim3(1), dim3(256), 0, stream, spartial, sboff,
                       row_start, SCAN_BLOCKS, N_NODES, N_EDGES);
    hipLaunchKernelGGL(scan_p3_kernel, dim3(SCAN_BLOCKS), dim3(256), 0, stream, deg_int, sboff,
                       row_start, dinv, N_NODES);
    hipLaunchKernelGGL(fill_csr_kernel, dim3(2048), dim3(256), 0, stream, src, dstv, rank,
                       row_start, csr_src, N_EDGES);
    hipLaunchKernelGGL(graph_bounds_kernel, dim3(1), dim3(NUM_GRAPHS + 1), 0, stream, batch,
                       gstart, N_NODES, NUM_GRAPHS);
    hipLaunchKernelGGL(zero_kernel, dim3((3 * 512 + NUM_GRAPHS * 128 + 255) / 256), dim3(256),
                       0, stream, sums_all, 3 * 512 + NUM_GRAPHS * 128);
    hipLaunchKernelGGL(wpack_all_kernel, dim3(64), dim3(256), 0, stream, W1, W2, W3, W1f, W2f,
                       W3f);
    int n4 = N_NODES * 128 / 4;
    hipLaunchKernelGGL(f2bf4_kernel, dim3((n4 + 255) / 256), dim3(256), 0, stream, x, xbf, n4);

    int gx = NPAD / 128;  // 391
    int nba = (N_NODES * 64 + 255) / 256;

    // ---- layer 1: gather(xbf) -> Ap; gemm(+b1) -> bufA (bf16); stats1 ----
    hipLaunchKernelGGL((gather_agg_kernel<128, 1>), dim3(N_NODES), dim3(64), 0, stream, xbf,
                       dinv, (const float*)nullptr, row_start, csr_src, Ap, N_NODES);
    hipLaunchKernelGGL((gemm_lds_kernel<4>), dim3(gx, 2), dim3(256), 0, stream, Ap, W1f, b1,
                       bufA, N_NODES, 256);
    hipLaunchKernelGGL(bn_stats_kernel, dim3(1024), dim3(256), 0, stream, bufA, s1, sq1,
                       N_NODES, 256);

    // ---- layer 2: BN1+relu -> Ap; gemm -> Hbf; gather(+b2) -> bufA; stats2 ----
    hipLaunchKernelGGL(bnapply_panel_kernel, dim3(nba), dim3(256), 0, stream, bufA, s1, sq1,
                       g1, be1, Ap, N_NODES);
    hipLaunchKernelGGL((gemm_lds_kernel<8>), dim3(gx, 2), dim3(256), 0, stream, Ap, W2f,
                       (const float*)nullptr, Hbf, N_NODES, 256);
    hipLaunchKernelGGL((gather_agg_kernel<256, 2>), dim3(N_NODES), dim3(64), 0, stream, Hbf,
                       dinv, b2, row_start, csr_src, bufA, N_NODES);
    hipLaunchKernelGGL(bn_stats_kernel, dim3(1024), dim3(256), 0, stream, bufA, s2, sq2,
                       N_NODES, 256);

    // ---- layer 3: BN2+relu -> Ap; gemm -> Hbf; gather(+b3) -> bufA; stats3 ----
    hipLaunchKernelGGL(bnapply_panel_kernel, dim3(nba), dim3(256), 0, stream, bufA, s2, sq2,
                       g2, be2, Ap, N_NODES);
    hipLaunchKernelGGL((gemm_lds_kernel<8>), dim3(gx, 1), dim3(256), 0, stream, Ap, W3f,
                       (const float*)nullptr, Hbf, N_NODES, 128);
    hipLaunchKernelGGL((gather_agg_kernel<128, 2>), dim3(N_NODES), dim3(64), 0, stream, Hbf,
                       dinv, b3, row_start, csr_src, bufA, N_NODES);
    hipLaunchKernelGGL(bn_stats_kernel, dim3(1024), dim3(128), 0, stream, bufA, s3, sq3,
                       N_NODES, 128);

    // ---- pool: parallel segmented mean with BN3 apply+relu fused ----
    hipLaunchKernelGGL(pool_part_kernel, dim3(NUM_GRAPHS, POOL_SPLITS), dim3(128), 0, stream,
                       bufA, s3, sq3, g3, be3, gstart, outacc);
    hipLaunchKernelGGL(pool_fin_kernel, dim3((NUM_GRAPHS * 128 + 255) / 256), dim3(256), 0,
                       stream, outacc, gstart, out);
}

// Round 11
// 525.117 us; speedup vs baseline: 5.0638x; 1.0125x over previous
//
#include <hip/hip_runtime.h>

#define N_NODES 50000
#define N_EDGES 800000
#define NUM_GRAPHS 128
#define EPS 1e-5f
#define SCAN_BLOCKS 196          // ceil(50000/256)
#define NPAD 50048               // 391 * 128 (row-tile padded node count)
#define POOL_SPLITS 16
#define INV_N (1.0f / 50000.0f)

typedef __attribute__((ext_vector_type(8))) short short8;
typedef __attribute__((ext_vector_type(4))) float floatx4;
typedef __attribute__((ext_vector_type(4))) unsigned short ushort4v;

__device__ __forceinline__ unsigned short f2bf_rne(float f) {
    unsigned int u = __float_as_uint(f);
    u += 0x7FFF + ((u >> 16) & 1);
    return (unsigned short)(u >> 16);
}
__device__ __forceinline__ float bf2f(unsigned short h) {
    return __uint_as_float(((unsigned int)h) << 16);
}
__device__ __forceinline__ float bflo(unsigned int u) { return __uint_as_float(u << 16); }
__device__ __forceinline__ float bfhi(unsigned int u) {
    return __uint_as_float(u & 0xFFFF0000u);
}

// async global->LDS, 16B per lane
__device__ __forceinline__ void gload16(const void* g, void* l) {
#if __has_builtin(__builtin_amdgcn_global_load_lds)
    __builtin_amdgcn_global_load_lds(
        reinterpret_cast<const __attribute__((address_space(1))) unsigned int*>(
            reinterpret_cast<unsigned long long>(g)),
        reinterpret_cast<__attribute__((address_space(3))) unsigned int*>(
            reinterpret_cast<unsigned long long>(l)),
        16, 0, 0);
#else
    *(uint4*)l = *(const uint4*)g;
#endif
}

// ---------------- fused zero (deg ints + stats/pool floats) ----------------

__global__ void zero_all_kernel(int* deg, float* f, int nInt, int nF) {
    int i = blockIdx.x * blockDim.x + threadIdx.x;
    if (i < nInt) deg[i] = 0;
    if (i < nF) f[i] = 0.0f;
}

// ---------------- degree / CSR build (rank-based) ----------------

__global__ void count_deg_rank_kernel(const int* __restrict__ dst, int* deg,
                                      int* __restrict__ rank, int E) {
    int i = blockIdx.x * blockDim.x + threadIdx.x;
    int stride = gridDim.x * blockDim.x;
    for (; i < E; i += stride) rank[i] = atomicAdd(&deg[dst[i]], 1);
}

__global__ __launch_bounds__(256) void scan_p1_kernel(const int* __restrict__ deg,
                                                      int* __restrict__ partial, int n) {
    __shared__ int red[256];
    int tid = threadIdx.x;
    int i = blockIdx.x * 256 + tid;
    red[tid] = (i < n) ? deg[i] : 0;
    __syncthreads();
#pragma unroll
    for (int s = 128; s > 0; s >>= 1) {
        if (tid < s) red[tid] += red[tid + s];
        __syncthreads();
    }
    if (tid == 0) partial[blockIdx.x] = red[0];
}

// block 0: exclusive scan of block partials; block 1: graph bounds (fused)
__global__ __launch_bounds__(256) void scan_p2_bounds_kernel(
        const int* __restrict__ partial, int* __restrict__ block_off,
        int* __restrict__ row_start, const int* __restrict__ batch,
        int* __restrict__ gstart, int nb, int n, int E) {
    if (blockIdx.x == 1) {
        int g = threadIdx.x;
        if (g > NUM_GRAPHS) return;
        int lo = 0, hi = n;
        while (lo < hi) {
            int mid = (lo + hi) >> 1;
            if (batch[mid] < g) lo = mid + 1; else hi = mid;
        }
        gstart[g] = lo;
        return;
    }
    __shared__ int s[256];
    int tid = threadIdx.x;
    int v = (tid < nb) ? partial[tid] : 0;
    s[tid] = v;
    __syncthreads();
#pragma unroll
    for (int off = 1; off < 256; off <<= 1) {
        int t = (tid >= off) ? s[tid - off] : 0;
        __syncthreads();
        s[tid] += t;
        __syncthreads();
    }
    if (tid < nb) block_off[tid] = s[tid] - v;
    if (tid == 0) row_start[n] = E;
}

// exclusive scan -> row_start; also dinv = rsqrt(deg+1) (fused)
__global__ __launch_bounds__(256) void scan_p3_kernel(const int* __restrict__ deg,
                                                      const int* __restrict__ block_off,
                                                      int* __restrict__ row_start,
                                                      float* __restrict__ dinv, int n) {
    __shared__ int s[256];
    int tid = threadIdx.x;
    int i = blockIdx.x * 256 + tid;
    int v = (i < n) ? deg[i] : 0;
    s[tid] = v;
    __syncthreads();
#pragma unroll
    for (int off = 1; off < 256; off <<= 1) {
        int t = (tid >= off) ? s[tid - off] : 0;
        __syncthreads();
        s[tid] += t;
        __syncthreads();
    }
    if (i < n) {
        row_start[i] = block_off[blockIdx.x] + s[tid] - v;
        dinv[i] = rsqrtf((float)(v + 1));
    }
}

__global__ void fill_csr_kernel(const int* __restrict__ src, const int* __restrict__ dst,
                                const int* __restrict__ rank, const int* __restrict__ row_start,
                                int* __restrict__ csr_src, int E) {
    int i = blockIdx.x * blockDim.x + threadIdx.x;
    int stride = gridDim.x * blockDim.x;
    for (; i < E; i += stride) csr_src[row_start[dst[i]] + rank[i]] = src[i];
}

// ---------------- f32 -> bf16 bulk convert ----------------

__global__ void f2bf4_kernel(const float* __restrict__ in, unsigned short* __restrict__ out,
                             int n4) {
    int i = blockIdx.x * blockDim.x + threadIdx.x;
    if (i >= n4) return;
    float4 v = ((const float4*)in)[i];
    ushort4v o = {f2bf_rne(v.x), f2bf_rne(v.y), f2bf_rne(v.z), f2bf_rne(v.w)};
    ((ushort4v*)out)[i] = o;
}

// ---------------- BN finalize (inline helper) ----------------

__device__ __forceinline__ void bn_coeff(const float* __restrict__ sums,
                                         const float* __restrict__ sumsq,
                                         const float* __restrict__ gamma,
                                         const float* __restrict__ beta, int c,
                                         float& sc, float& sh) {
    float mu = sums[c] * INV_N;
    float var = sumsq[c] * INV_N - mu * mu;
    float rs = rsqrtf(var + EPS);
    sc = gamma[c] * rs;
    sh = beta[c] - mu * sc;
}

// ---------------- BN apply + relu: bf16 row-major -> bf16 panel-major -------------

__global__ void bnapply_panel_kernel(const unsigned short* __restrict__ A,
                                     const float* __restrict__ sums,
                                     const float* __restrict__ sumsq,
                                     const float* __restrict__ gamma,
                                     const float* __restrict__ beta,
                                     unsigned short* __restrict__ Ap, int n) {
    int i = blockIdx.x * blockDim.x + threadIdx.x;  // over n*64 groups of 4 cols
    if (i >= n * 64) return;
    int row = i >> 6, cg = i & 63;
    int c0 = cg * 4;
    uint2 in = *(const uint2*)(A + (size_t)row * 256 + c0);
    float v0 = bflo(in.x), v1 = bfhi(in.x), v2 = bflo(in.y), v3 = bfhi(in.y);
    float sc0, sh0, sc1, sh1, sc2, sh2, sc3, sh3;
    bn_coeff(sums, sumsq, gamma, beta, c0 + 0, sc0, sh0);
    bn_coeff(sums, sumsq, gamma, beta, c0 + 1, sc1, sh1);
    bn_coeff(sums, sumsq, gamma, beta, c0 + 2, sc2, sh2);
    bn_coeff(sums, sumsq, gamma, beta, c0 + 3, sc3, sh3);
    float r0 = fmaxf(v0 * sc0 + sh0, 0.0f);
    float r1 = fmaxf(v1 * sc1 + sh1, 0.0f);
    float r2 = fmaxf(v2 * sc2 + sh2, 0.0f);
    float r3 = fmaxf(v3 * sc3 + sh3, 0.0f);
    uint2 o;
    o.x = (unsigned int)f2bf_rne(r0) | ((unsigned int)f2bf_rne(r1) << 16);
    o.y = (unsigned int)f2bf_rne(r2) | ((unsigned int)f2bf_rne(r3) << 16);
    int p = c0 >> 5, wc = c0 & 31;
    *(uint2*)(Ap + ((size_t)p * NPAD + row) * 32 + wc) = o;
}

// ---------------- W packing: f32 -> bf16 hi/lo, one fused dispatch ---------------

__device__ __forceinline__ void wpack_one(const float* __restrict__ W, short* __restrict__ Wf,
                                          int K, int M, int t) {
    int KT = K >> 5, MT = M >> 4;
    if (t >= KT * MT * 64) return;
    int lane = t & 63, chunk = t >> 6;
    int kt = chunk / MT, nt = chunk % MT;
    int q = lane >> 4, m = lane & 15;
    int n = nt * 16 + m;
    short* ophi = Wf + ((size_t)(kt * MT + nt) * 2 + 0) * 512 + lane * 8;
    short* oplo = Wf + ((size_t)(kt * MT + nt) * 2 + 1) * 512 + lane * 8;
#pragma unroll
    for (int j = 0; j < 8; ++j) {
        float w = W[(size_t)(kt * 32 + q * 8 + j) * M + n];
        unsigned short hi = f2bf_rne(w);
        unsigned short lo = f2bf_rne(w - bf2f(hi));
        ophi[j] = (short)hi;
        oplo[j] = (short)lo;
    }
}

__global__ __launch_bounds__(256) void wpack_all_kernel(
        const float* __restrict__ W1, const float* __restrict__ W2,
        const float* __restrict__ W3, short* W1f, short* W2f, short* W3f) {
    int b = blockIdx.x;
    if (b < 16) wpack_one(W1, W1f, 128, 256, b * 256 + threadIdx.x);
    else if (b < 48) wpack_one(W2, W2f, 256, 256, (b - 16) * 256 + threadIdx.x);
    else wpack_one(W3, W3f, 256, 128, (b - 48) * 256 + threadIdx.x);
}

// ---------------- double-buffered LDS MFMA GEMM (bf16 out) ----------------

template <int KT>
__global__ __launch_bounds__(256) void gemm_lds_kernel(
        const unsigned short* __restrict__ Ap, const short* __restrict__ Wf,
        const float* __restrict__ bias, unsigned short* __restrict__ Hout, int N, int M) {
    const int MT = M >> 4;
    __shared__ unsigned short sA[2][128 * 32];   // 2 x 8 KB
    __shared__ short sW[2][8 * 2 * 512];         // 2 x 16 KB
    int tid = threadIdx.x;
    int wave = tid >> 6, lane = tid & 63;
    int wr = wave >> 1, wc = wave & 1;
    int bm = blockIdx.x * 128;
    int bn = blockIdx.y * 128;
    int ntbb = bn >> 4;
    int q = lane >> 4, l16 = lane & 15;
    floatx4 acc[4][4] = {};

    auto stage = [&](int kt, int p) {
        const char* ab = (const char*)(Ap + ((size_t)kt * NPAD + bm) * 32);
        const char* wb = (const char*)(Wf + (size_t)(kt * MT + ntbb) * 1024);
        char* sa = (char*)sA[p];
        char* sw = (char*)sW[p];
        gload16(ab + tid * 16, sa + tid * 16);
        gload16(ab + (256 + tid) * 16, sa + (256 + tid) * 16);
#pragma unroll
        for (int i = 0; i < 4; ++i)
            gload16(wb + (i * 256 + tid) * 16, sw + (i * 256 + tid) * 16);
    };

    stage(0, 0);
    int p = 0;
    for (int kt = 0; kt < KT; ++kt) {
        __syncthreads();  // drains stage(kt); protects buffer p^1 from overwrite
        if (kt + 1 < KT) stage(kt + 1, p ^ 1);  // overlap with compute below
        short8 a[4], wh[4], wl[4];
#pragma unroll
        for (int mt = 0; mt < 4; ++mt)
            a[mt] = *(const short8*)&sA[p][(wr * 64 + mt * 16 + l16) * 32 + q * 8];
#pragma unroll
        for (int nt = 0; nt < 4; ++nt) {
            wh[nt] = *(const short8*)&sW[p][((wc * 4 + nt) * 2 + 0) * 512 + lane * 8];
            wl[nt] = *(const short8*)&sW[p][((wc * 4 + nt) * 2 + 1) * 512 + lane * 8];
        }
#pragma unroll
        for (int nt = 0; nt < 4; ++nt)
#pragma unroll
            for (int mt = 0; mt < 4; ++mt) {
                acc[mt][nt] = __builtin_amdgcn_mfma_f32_16x16x32_bf16(a[mt], wh[nt],
                                                                      acc[mt][nt], 0, 0, 0);
                acc[mt][nt] = __builtin_amdgcn_mfma_f32_16x16x32_bf16(a[mt], wl[nt],
                                                                      acc[mt][nt], 0, 0, 0);
            }
        p ^= 1;
    }
#pragma unroll
    for (int nt = 0; nt < 4; ++nt) {
        int col = bn + wc * 64 + nt * 16 + l16;
        float bv = bias ? bias[col] : 0.0f;
#pragma unroll
        for (int mt = 0; mt < 4; ++mt) {
#pragma unroll
            for (int r = 0; r < 4; ++r) {
                int row = bm + wr * 64 + mt * 16 + q * 4 + r;
                if (row < N)
                    Hout[(size_t)row * M + col] = f2bf_rne(acc[mt][nt][r] + bv);
            }
        }
    }
}

// ---------------- gather aggregation (CSR by dst, bf16 in, bf16 out) -------------
// OUTMODE: 1 = bf16 panel-major (GEMM A operand), 2 = bf16 row-major.

template <int C, int OUTMODE>
__global__ __launch_bounds__(64) void gather_agg_kernel(
        const unsigned short* __restrict__ Hb, const float* __restrict__ dinv,
        const float* __restrict__ bias, const int* __restrict__ row_start,
        const int* __restrict__ csr_src, unsigned short* __restrict__ AGG, int n) {
    constexpr int V = C / 64;  // channels per lane (2 or 4)
    constexpr int U = V / 2;   // packed uints per lane
    int i = blockIdx.x;
    if (i >= n) return;
    int lane = threadIdx.x;
    float di = dinv[i];
    float w0 = di * di;
    const unsigned int* base = (const unsigned int*)Hb;
    float acc[V];
    {
        const unsigned int* hrow = base + ((size_t)i * C >> 1) + lane * U;
#pragma unroll
        for (int t = 0; t < U; ++t) {
            unsigned int u = hrow[t];
            acc[2 * t] = (bias ? bias[lane * V + 2 * t] : 0.0f) + bflo(u) * w0;
            acc[2 * t + 1] = (bias ? bias[lane * V + 2 * t + 1] : 0.0f) + bfhi(u) * w0;
        }
    }
    int e0 = row_start[i], e1 = row_start[i + 1];
    int e = e0;
    for (; e + 4 <= e1; e += 4) {
        int s[4];
#pragma unroll
        for (int j = 0; j < 4; ++j) s[j] = csr_src[e + j];
        float w[4];
#pragma unroll
        for (int j = 0; j < 4; ++j) w[j] = dinv[s[j]] * di;
        unsigned int u[4][U];
#pragma unroll
        for (int j = 0; j < 4; ++j) {
            const unsigned int* p = base + ((size_t)s[j] * C >> 1) + lane * U;
#pragma unroll
            for (int t = 0; t < U; ++t) u[j][t] = p[t];
        }
#pragma unroll
        for (int t = 0; t < U; ++t) {
#pragma unroll
            for (int j = 0; j < 4; ++j) {
                acc[2 * t] += bflo(u[j][t]) * w[j];
                acc[2 * t + 1] += bfhi(u[j][t]) * w[j];
            }
        }
    }
    for (; e < e1; ++e) {
        int s = csr_src[e];
        float w = dinv[s] * di;
        const unsigned int* srow = base + ((size_t)s * C >> 1) + lane * U;
#pragma unroll
        for (int t = 0; t < U; ++t) {
            unsigned int uu = srow[t];
            acc[2 * t] += bflo(uu) * w;
            acc[2 * t + 1] += bfhi(uu) * w;
        }
    }
    if constexpr (OUTMODE == 1) {
#pragma unroll
        for (int t = 0; t < U; ++t) {
            int c = lane * V + 2 * t;
            unsigned int o = (unsigned int)f2bf_rne(acc[2 * t]) |
                             ((unsigned int)f2bf_rne(acc[2 * t + 1]) << 16);
            *(unsigned int*)(AGG + ((size_t)(c >> 5) * NPAD + i) * 32 + (c & 31)) = o;
        }
    } else {
        unsigned int* orow = (unsigned int*)AGG + ((size_t)i * C >> 1) + lane * U;
#pragma unroll
        for (int t = 0; t < U; ++t)
            orow[t] = (unsigned int)f2bf_rne(acc[2 * t]) |
                      ((unsigned int)f2bf_rne(acc[2 * t + 1]) << 16);
    }
}

// ---------------- batch norm stats (bf16 input) ----------------

__global__ void bn_stats_kernel(const unsigned short* __restrict__ A, float* __restrict__ sums,
                                float* __restrict__ sumsq, int n, int C) {
    int c = threadIdx.x;
    int rpb = (n + gridDim.x - 1) / gridDim.x;
    int r0 = blockIdx.x * rpb;
    int r1 = min(n, r0 + rpb);
    float s = 0.0f, s2 = 0.0f;
    for (int r = r0; r < r1; ++r) {
        float v = bf2f(A[(size_t)r * C + c]);
        s += v;
        s2 += v * v;
    }
    atomicAdd(&sums[c], s);
    atomicAdd(&sumsq[c], s2);
}

// ---------------- pooling (sorted-segment, parallel, BN3+relu fused) -------------

__global__ __launch_bounds__(128) void pool_part_kernel(
        const unsigned short* __restrict__ A, const float* __restrict__ sums,
        const float* __restrict__ sumsq, const float* __restrict__ gamma,
        const float* __restrict__ beta, const int* __restrict__ gstart,
        float* __restrict__ outacc) {
    int g = blockIdx.x;
    int split = blockIdx.y;
    int c = threadIdx.x;
    int r0 = gstart[g], r1 = gstart[g + 1];
    float sc, sh;
    bn_coeff(sums, sumsq, gamma, beta, c, sc, sh);
    float s = 0.0f;
    for (int r = r0 + split; r < r1; r += POOL_SPLITS) {
        float v = bf2f(A[(size_t)r * 128 + c]);
        s += fmaxf(v * sc + sh, 0.0f);
    }
    atomicAdd(&outacc[g * 128 + c], s);
}

__global__ void pool_fin_kernel(const float* __restrict__ outacc,
                                const int* __restrict__ gstart, float* __restrict__ out) {
    int idx = blockIdx.x * blockDim.x + threadIdx.x;
    if (idx >= NUM_GRAPHS * 128) return;
    int g = idx >> 7;
    float cnt = (float)(gstart[g + 1] - gstart[g]);
    out[idx] = outacc[idx] / fmaxf(cnt, 1.0f);
}

// ---------------- host driver ----------------

extern "C" void kernel_launch(void* const* d_in, const int* in_sizes, int n_in,
                              void* d_out, int out_size, void* d_ws, size_t ws_size,
                              hipStream_t stream) {
    const float* x     = (const float*)d_in[0];
    const int*   ei    = (const int*)d_in[1];
    const int*   batch = (const int*)d_in[2];
    const float* W1 = (const float*)d_in[3];
    const float* b1 = (const float*)d_in[4];
    const float* W2 = (const float*)d_in[5];
    const float* b2 = (const float*)d_in[6];
    const float* W3 = (const float*)d_in[7];
    const float* b3 = (const float*)d_in[8];
    const float* g1 = (const float*)d_in[9];
    const float* be1 = (const float*)d_in[10];
    const float* g2 = (const float*)d_in[11];
    const float* be2 = (const float*)d_in[12];
    const float* g3 = (const float*)d_in[13];
    const float* be3 = (const float*)d_in[14];
    float* out = (float*)d_out;

    const int* src = ei;
    const int* dstv = ei + N_EDGES;

    size_t off = 0;
    auto allocb = [&](size_t nbytes) {
        char* p = (char*)d_ws + off;
        off += (nbytes + 255) & ~(size_t)255;
        return p;
    };
    int*   deg_int   = (int*)allocb(N_NODES * 4);
    int*   row_start = (int*)allocb((N_NODES + 1) * 4);
    int*   rank      = (int*)allocb(N_EDGES * 4);
    int*   csr_src   = (int*)allocb(N_EDGES * 4);
    int*   gstart    = (int*)allocb((NUM_GRAPHS + 1) * 4);
    int*   spartial  = (int*)allocb(SCAN_BLOCKS * 4);
    int*   sboff     = (int*)allocb(SCAN_BLOCKS * 4);
    float* dinv      = (float*)allocb(N_NODES * 4);
    float* sums_all  = (float*)allocb((3 * 512 + NUM_GRAPHS * 128) * 4);  // stats + outacc
    float* outacc    = sums_all + 3 * 512;
    short* W1f       = (short*)allocb((size_t)128 * 256 * 4);
    short* W2f       = (short*)allocb((size_t)256 * 256 * 4);
    short* W3f       = (short*)allocb((size_t)256 * 128 * 4);
    unsigned short* Hbf  = (unsigned short*)allocb((size_t)N_NODES * 256 * 2);  // GEMM out
    unsigned short* bufA = (unsigned short*)allocb((size_t)N_NODES * 256 * 2);  // AGG/H1
    unsigned short* Ap   = (unsigned short*)allocb((size_t)NPAD * 256 * 2);     // panels
    unsigned short* xbf  = Hbf;  // x-bf16 aliases Hbf (dead until layer-2 GEMM)
    (void)ws_size; (void)n_in; (void)in_sizes; (void)out_size;

    float* s1 = sums_all, *sq1 = sums_all + 256;
    float* s2 = sums_all + 512, *sq2 = sums_all + 768;
    float* s3 = sums_all + 1024, *sq3 = sums_all + 1280;

    int nb = (N_NODES + 255) / 256;

    // ---- prologue ----
    hipLaunchKernelGGL(zero_all_kernel, dim3(nb), dim3(256), 0, stream, deg_int, sums_all,
                       N_NODES, 3 * 512 + NUM_GRAPHS * 128);
    hipLaunchKernelGGL(count_deg_rank_kernel, dim3(2048), dim3(256), 0, stream, dstv, deg_int,
                       rank, N_EDGES);
    hipLaunchKernelGGL(scan_p1_kernel, dim3(SCAN_BLOCKS), dim3(256), 0, stream, deg_int,
                       spartial, N_NODES);
    hipLaunchKernelGGL(scan_p2_bounds_kernel, dim3(2), dim3(256), 0, stream, spartial, sboff,
                       row_start, batch, gstart, SCAN_BLOCKS, N_NODES, N_EDGES);
    hipLaunchKernelGGL(scan_p3_kernel, dim3(SCAN_BLOCKS), dim3(256), 0, stream, deg_int, sboff,
                       row_start, dinv, N_NODES);
    hipLaunchKernelGGL(fill_csr_kernel, dim3(2048), dim3(256), 0, stream, src, dstv, rank,
                       row_start, csr_src, N_EDGES);
    hipLaunchKernelGGL(wpack_all_kernel, dim3(64), dim3(256), 0, stream, W1, W2, W3, W1f, W2f,
                       W3f);
    int n4 = N_NODES * 128 / 4;
    hipLaunchKernelGGL(f2bf4_kernel, dim3((n4 + 255) / 256), dim3(256), 0, stream, x, xbf, n4);

    int gx = NPAD / 128;  // 391
    int nba = (N_NODES * 64 + 255) / 256;

    // ---- layer 1: gather(xbf) -> Ap; gemm(+b1) -> bufA (bf16); stats1 ----
    hipLaunchKernelGGL((gather_agg_kernel<128, 1>), dim3(N_NODES), dim3(64), 0, stream, xbf,
                       dinv, (const float*)nullptr, row_start, csr_src, Ap, N_NODES);
    hipLaunchKernelGGL((gemm_lds_kernel<4>), dim3(gx, 2), dim3(256), 0, stream, Ap, W1f, b1,
                       bufA, N_NODES, 256);
    hipLaunchKernelGGL(bn_stats_kernel, dim3(1024), dim3(256), 0, stream, bufA, s1, sq1,
                       N_NODES, 256);

    // ---- layer 2: BN1+relu -> Ap; gemm -> Hbf; gather(+b2) -> bufA; stats2 ----
    hipLaunchKernelGGL(bnapply_panel_kernel, dim3(nba), dim3(256), 0, stream, bufA, s1, sq1,
                       g1, be1, Ap, N_NODES);
    hipLaunchKernelGGL((gemm_lds_kernel<8>), dim3(gx, 2), dim3(256), 0, stream, Ap, W2f,
                       (const float*)nullptr, Hbf, N_NODES, 256);
    hipLaunchKernelGGL((gather_agg_kernel<256, 2>), dim3(N_NODES), dim3(64), 0, stream, Hbf,
                       dinv, b2, row_start, csr_src, bufA, N_NODES);
    hipLaunchKernelGGL(bn_stats_kernel, dim3(1024), dim3(256), 0, stream, bufA, s2, sq2,
                       N_NODES, 256);

    // ---- layer 3: BN2+relu -> Ap; gemm -> Hbf; gather(+b3) -> bufA; stats3 ----
    hipLaunchKernelGGL(bnapply_panel_kernel, dim3(nba), dim3(256), 0, stream, bufA, s2, sq2,
                       g2, be2, Ap, N_NODES);
    hipLaunchKernelGGL((gemm_lds_kernel<8>), dim3(gx, 1), dim3(256), 0, stream, Ap, W3f,
                       (const float*)nullptr, Hbf, N_NODES, 128);
    hipLaunchKernelGGL((gather_agg_kernel<128, 2>), dim3(N_NODES), dim3(64), 0, stream, Hbf,
                       dinv, b3, row_start, csr_src, bufA, N_NODES);
    hipLaunchKernelGGL(bn_stats_kernel, dim3(1024), dim3(128), 0, stream, bufA, s3, sq3,
                       N_NODES, 128);

    // ---- pool: parallel segmented mean with BN3 apply+relu fused ----
    hipLaunchKernelGGL(pool_part_kernel, dim3(NUM_GRAPHS, POOL_SPLITS), dim3(128), 0, stream,
                       bufA, s3, sq3, g3, be3, gstart, outacc);
    hipLaunchKernelGGL(pool_fin_kernel, dim3((NUM_GRAPHS * 128 + 255) / 256), dim3(256), 0,
                       stream, outacc, gstart, out);
}